// Round 10
// baseline (418.727 us; speedup 1.0000x reference)
//
#include <hip/hip_runtime.h>
#include <stdint.h>

#define N_ANCH   106392
#define PRE_NMS  6000
#define POST_NMS 1000
#define POOL_CAP 8192
#define NMS_BLKS 94   // 94*64 = 6016 >= 6000
#define SUP_W    96   // padded words per suppression row

static __device__ const int    LV_H[5]      = {128, 64, 32, 16, 8};
static __device__ const int    LV_W[5]      = {208, 104, 52, 26, 13};
static __device__ const int    LV_STRIDE[5] = {4, 8, 16, 32, 64};
static __device__ const int    LV_PIX[5]    = {26624, 6656, 1664, 416, 104};
static __device__ const int    LV_TILE0[6]  = {0, 416, 520, 546, 553, 555};
static __device__ const int    LV_AOFF[6]   = {0, 79872, 99840, 104832, 106080, 106392};
static __device__ const int    GPOFF[6]     = {0, 26624, 33280, 34944, 35360, 35464};
// Base anchors computed with np.round (half-even) semantics, verified by hand.
static __device__ const double BASE_ANCH[5][3][4] = {
  {{-22.,-10.,25.,13.},   {-14.,-14.,17.,17.},    {-10.,-22.,13.,25.}},
  {{-40.,-20.,47.,27.},   {-28.,-28.,35.,35.},    {-20.,-44.,27.,51.}},
  {{-84.,-40.,99.,55.},   {-56.,-56.,71.,71.},    {-36.,-80.,51.,95.}},
  {{-164.,-72.,195.,103.},{-112.,-112.,143.,143.},{-76.,-168.,107.,199.}},
  {{-332.,-152.,395.,215.},{-224.,-224.,287.,287.},{-148.,-328.,211.,391.}}
};

// sortable mappings (monotone): bigger value -> bigger key
__device__ __forceinline__ uint32_t sort32f(float f) {
  uint32_t u = __float_as_uint(f);
  return ((int)u < 0) ? ~u : (u | 0x80000000u);
}
__device__ __forceinline__ uint64_t sort64(double d) {
  uint64_t u = (uint64_t)__double_as_longlong(d);
  return ((long long)u < 0) ? ~u : (u | 0x8000000000000000ull);
}

// ---------------- f64 effective weights, 2-stage ----------------
// comb inline: j<3 -> sw[3+j][c]-sw[j][c]; 3<=j<15 -> bw[j-3][c]
__device__ __forceinline__ double combf(const float* sw, const float* bw, int c, int j) {
  if (j < 3) return (double)sw[(3 + j) * 512 + c] - (double)sw[j * 512 + c];
  return (double)bw[(j - 3) * 512 + c];
}

__global__ __launch_bounds__(256) void k_weff_part(const float* __restrict__ cw,
                                                   const float* __restrict__ sw,
                                                   const float* __restrict__ bw,
                                                   double* __restrict__ Wpart) {
  int chunk = blockIdx.x / 9;            // 16 chunks of 32 channels
  int tb = blockIdx.x % 9;               // 9 t-blocks of 256
  int t = tb * 256 + threadIdx.x;        // 0..2303
  int c0 = chunk * 32;
  double acc[15];
#pragma unroll
  for (int j = 0; j < 15; ++j) acc[j] = 0.0;
#pragma unroll 1
  for (int c = c0; c < c0 + 32; ++c) {
    double v = (double)cw[c * 2304 + t];
#pragma unroll
    for (int j = 0; j < 15; ++j) acc[j] += v * combf(sw, bw, c, j);
  }
  double* o = Wpart + (((size_t)chunk * 2304 + t) << 4);
#pragma unroll
  for (int j = 0; j < 15; ++j) o[j] = acc[j];
  o[15] = 0.0;
}

// blocks 0..8: Weff[t][j] = sum over chunks; also emit f32 screen weights w3.
// block 9: fb f64 + fb32.
__global__ __launch_bounds__(256) void k_weff_fin(const double* __restrict__ Wpart,
                                                  const float* __restrict__ cb,
                                                  const float* __restrict__ sb,
                                                  const float* __restrict__ bb,
                                                  const float* __restrict__ sw,
                                                  const float* __restrict__ bw,
                                                  double* __restrict__ Weff,
                                                  double* __restrict__ fb,
                                                  float4* __restrict__ w3,
                                                  float* __restrict__ fb32) {
  if (blockIdx.x == 9) {
    __shared__ double ps[15][16];
    int tid = threadIdx.x;
    if (tid < 240) {
      int j = tid >> 4, part = tid & 15;
      double s = 0.0;
      for (int c = part * 32; c < part * 32 + 32; ++c)
        s += (double)cb[c] * combf(sw, bw, c, j);
      ps[j][part] = s;
    }
    __syncthreads();
    if (tid < 15) {
      double s = 0.0;
#pragma unroll
      for (int part = 0; part < 16; ++part) s += ps[tid][part];  // fixed order
      s += (tid < 3) ? ((double)sb[3 + tid] - (double)sb[tid]) : (double)bb[tid - 3];
      fb[tid] = s;
      if (tid < 3) fb32[tid] = (float)s;
    }
    if (tid == 15) fb32[3] = 0.f;
    return;
  }
  int t = blockIdx.x * 256 + threadIdx.x;
  double acc[15];
#pragma unroll
  for (int j = 0; j < 15; ++j) acc[j] = 0.0;
#pragma unroll 1
  for (int chunk = 0; chunk < 16; ++chunk) {
    const double* p = Wpart + (((size_t)chunk * 2304 + t) << 4);
#pragma unroll
    for (int j = 0; j < 15; ++j) acc[j] += p[j];
  }
  double* o = Weff + ((size_t)t << 4);
#pragma unroll
  for (int j = 0; j < 15; ++j) o[j] = acc[j];
  o[15] = 0.0;
  float4 wf;
  wf.x = (float)acc[0]; wf.y = (float)acc[1]; wf.z = (float)acc[2]; wf.w = 0.f;
  w3[t] = wf;
}

// ---------------- W5: k_refine-friendly weight layout ----------------
// W5[ci][(t9*3+a)*6 + {0..5}] = {d0w,d1w,d2w,d3w,scorew,pad}, ci stride 192
// doubles (1536 B, 16B-aligned records of 48 B). Pure copy of Weff -> bit-exact.
__global__ __launch_bounds__(256) void k_w5(const double* __restrict__ Weff,
                                            double* __restrict__ w5) {
  int idx = blockIdx.x * 256 + threadIdx.x;   // (t, a): t = ci*9+t9
  if (idx >= 2304 * 3) return;
  int t = idx / 3, a = idx % 3;
  int ci = t / 9, t9 = t % 9;
  const double* src = Weff + ((size_t)t << 4);
  double* dst = w5 + (size_t)ci * 192 + (size_t)(t9 * 3 + a) * 6;
  int jd = 3 + 4 * a;
  dst[0] = src[jd + 0];
  dst[1] = src[jd + 1];
  dst[2] = src[jd + 2];
  dst[3] = src[jd + 3];
  dst[4] = src[a];
  dst[5] = 0.0;
}

// ---------------- f32 screening pass ----------------
__device__ __forceinline__ void load9(float v[9], const float* __restrict__ ib,
                                      const bool rok[3], const bool cok[3],
                                      const int roff[3]) {
#pragma unroll
  for (int ky = 0; ky < 3; ++ky)
#pragma unroll
    for (int kx = 0; kx < 3; ++kx)
      v[ky * 3 + kx] = (rok[ky] && cok[kx]) ? ib[roff[ky] + kx] : 0.0f;
}

// TLP-doubled screen (R9): grid 1110 = 2 channel-halves per pixel tile, each
// wave owns a 32-channel serial chain. Partials q=(r0+r1)+(r2+r3) -> qpart;
// k_fcomb adds halves + fb32. f64 path untouched; logits32 tree perturbation
// ~1e-4 relative is absorbed by the screen's 2-bin margin.
__global__ __launch_bounds__(256) void k_fast(
    const float* __restrict__ p0, const float* __restrict__ p1,
    const float* __restrict__ p2, const float* __restrict__ p3,
    const float* __restrict__ p4,
    const float4* __restrict__ w3, float* __restrict__ qpart) {
  __shared__ float4 w3s[1152];       // 18.4 KB: this block's 128 channels
  __shared__ float red[4][64][3];
  int tid = threadIdx.x, wv = tid >> 6, ln = tid & 63;
  int t = blockIdx.x >> 1, hf = blockIdx.x & 1;
  int cbase = hf * 128;
  for (int i = tid; i < 1152; i += 256) w3s[i] = w3[cbase * 9 + i];
  int L = 0;
  while (L < 4 && t >= LV_TILE0[L + 1]) ++L;
  const float* inL = (L == 0) ? p0 : (L == 1) ? p1 : (L == 2) ? p2 : (L == 3) ? p3 : p4;
  int H = LV_H[L], W = LV_W[L], HW = H * W, PIX = LV_PIX[L];
  int pix = (t - LV_TILE0[L]) * 64 + ln;
  if (pix >= PIX) pix = PIX - 1;           // clamp; k_fcomb skips invalid
  int h = pix / W, w = pix % W;
  bool rok[3], cok[3];
  int roff[3];
#pragma unroll
  for (int ky = 0; ky < 3; ++ky) {
    int iy = h + ky - 1;
    rok[ky] = (iy >= 0 && iy < H);
    roff[ky] = iy * W + w - 1;
  }
#pragma unroll
  for (int kx = 0; kx < 3; ++kx) {
    int ix = w + kx - 1;
    cok[kx] = (ix >= 0 && ix < W);
  }
  int lci0 = wv * 32;                      // LDS channel index within half
  const float* ibn = inL + (size_t)(cbase + lci0) * HW;
  float vn[9];
  load9(vn, ibn, rok, cok, roff);          // prefetch first channel
  __syncthreads();
  float a0 = 0.f, a1 = 0.f, a2 = 0.f;
#pragma unroll 1
  for (int c = 0; c < 32; ++c) {
    float vc[9];
#pragma unroll
    for (int q = 0; q < 9; ++q) vc[q] = vn[q];
    if (c < 31) {                          // uniform; prefetch next channel
      ibn += HW;
      load9(vn, ibn, rok, cok, roff);
    }
    const float4* wr = w3s + (lci0 + c) * 9;
#pragma unroll
    for (int t9 = 0; t9 < 9; ++t9) {
      float4 wt = wr[t9];                  // broadcast ds_read_b128
      float vv = vc[t9];
      a0 += vv * wt.x; a1 += vv * wt.y; a2 += vv * wt.z;
    }
  }
  red[wv][ln][0] = a0; red[wv][ln][1] = a1; red[wv][ln][2] = a2;
  __syncthreads();
  if (wv == 0) {
    float* o = qpart + ((size_t)(t * 2 + hf) * 64 + ln) * 3;
#pragma unroll
    for (int a = 0; a < 3; ++a)
      o[a] = (red[0][ln][a] + red[1][ln][a]) + (red[2][ln][a] + red[3][ln][a]);
  }
}

// combine channel-halves: f = (q0+q1)+fb32 -> logits32 + histogram
__global__ __launch_bounds__(256) void k_fcomb(
    const float* __restrict__ qpart, const float* __restrict__ fb32,
    float* __restrict__ logits32, uint32_t* __restrict__ hist) {
  int tid = threadIdx.x, ln = tid & 63;
  int t = blockIdx.x * 4 + (tid >> 6);
  if (t >= 555) return;
  int L = 0;
  while (L < 4 && t >= LV_TILE0[L + 1]) ++L;
  int PIX = LV_PIX[L];
  int pix = (t - LV_TILE0[L]) * 64 + ln;
  if (pix >= PIX) return;
  const float* q0 = qpart + ((size_t)(t * 2 + 0) * 64 + ln) * 3;
  const float* q1 = qpart + ((size_t)(t * 2 + 1) * 64 + ln) * 3;
  int gbase = LV_AOFF[L] + pix * 3;
#pragma unroll
  for (int a = 0; a < 3; ++a) {
    float f = (q0[a] + q1[a]) + fb32[a];
    logits32[gbase + a] = f;
    atomicAdd(&hist[sort32f(f) >> 16], 1u);
  }
}

// ---------------- edge finder (with 2-bin safety margin) ----------------
__global__ __launch_bounds__(1024) void k_edge(const uint32_t* __restrict__ hist,
                                               uint32_t* __restrict__ cnts) {
  __shared__ uint32_t cs[1024];
  __shared__ uint32_t g_grp, g_suf;
  int t = threadIdx.x, wv = t >> 6, ln = t & 63;
#pragma unroll 4
  for (int r = 0; r < 64; ++r) {
    int g = r * 16 + wv;
    uint32_t x = hist[g * 64 + ln];
#pragma unroll
    for (int off = 32; off > 0; off >>= 1) x += __shfl_down(x, off);
    if (ln == 0) cs[g] = x;
  }
  __syncthreads();
  for (int off = 1; off < 1024; off <<= 1) {
    uint32_t v = cs[t] + ((t + off < 1024) ? cs[t + off] : 0u);
    __syncthreads();
    cs[t] = v;
    __syncthreads();
  }
  uint32_t sufnext = (t < 1023) ? cs[t + 1] : 0u;
  if (cs[t] >= PRE_NMS && sufnext < PRE_NMS) {   // unique t
    g_grp = (uint32_t)t;
    g_suf = sufnext;
  }
  __syncthreads();
  if (t < 64) {   // wave 0: refine edge within the winning 64-bin group
    uint32_t grp = g_grp, suf = g_suf;
    uint32_t x = hist[grp * 64 + t];
    uint32_t S = x;
#pragma unroll
    for (int off = 1; off < 64; off <<= 1) {
      uint32_t y = __shfl_down(S, off);
      if (t + off < 64) S += y;
    }
    unsigned long long mask = __ballot(suf + S >= PRE_NMS);
    int hi = 63 - (int)__clzll(mask);
    if (t == hi) {
      uint32_t e = grp * 64 + (uint32_t)hi;
      cnts[1] = (e > 2) ? e - 2 : 0;     // -2 bin margin: f32 superset of f64 top-k
    }
  }
}

// ---------------- ordered pool compaction (f32 screen) ----------------
__global__ __launch_bounds__(256) void k_cnt(const float* __restrict__ logits32,
                                             const uint32_t* __restrict__ cnts,
                                             uint32_t* __restrict__ bcnt) {
  __shared__ uint32_t wc[4];
  int tid = threadIdx.x;
  int i = blockIdx.x * 256 + tid;
  uint32_t edge = cnts[1];
  bool pass = (i < N_ANCH) && ((sort32f(logits32[i]) >> 16) >= edge);
  unsigned long long m = __ballot(pass);
  if ((tid & 63) == 0) wc[tid >> 6] = (uint32_t)__popcll(m);
  __syncthreads();
  if (tid == 0) bcnt[blockIdx.x] = wc[0] + wc[1] + wc[2] + wc[3];
}

__global__ __launch_bounds__(256) void k_fill(const float* __restrict__ logits32,
                                              uint32_t* __restrict__ cnts,
                                              const uint32_t* __restrict__ bcnt,
                                              uint32_t* __restrict__ alist) {
  __shared__ uint32_t red[256];
  __shared__ uint32_t woff[4];
  int tid = threadIdx.x, wv = tid >> 6, ln = tid & 63;
  // exclusive prefix over preceding blocks (416 values, trivial)
  uint32_t s = 0;
  for (int k = tid; k < blockIdx.x; k += 256) s += bcnt[k];
  red[tid] = s;
  __syncthreads();
#pragma unroll
  for (int off = 128; off > 0; off >>= 1) {
    if (tid < off) red[tid] += red[tid + off];
    __syncthreads();
  }
  uint32_t base = red[0];
  int i = blockIdx.x * 256 + tid;
  uint32_t edge = cnts[1];
  bool pass = (i < N_ANCH) && ((sort32f(logits32[i]) >> 16) >= edge);
  unsigned long long m = __ballot(pass);
  if (ln == 0) woff[wv] = (uint32_t)__popcll(m);
  __syncthreads();
  uint32_t off_in_blk = 0;
  for (int k = 0; k < wv; ++k) off_in_blk += woff[k];
  if (pass) {
    uint32_t pos = base + off_in_blk + (uint32_t)__popcll(m & ((1ull << ln) - 1ull));
    if (pos < POOL_CAP) alist[pos] = (uint32_t)i;
  }
  if (blockIdx.x == ((N_ANCH + 255) / 256 - 1) && tid == 0)
    cnts[0] = base + woff[0] + woff[1] + woff[2] + woff[3];   // uncapped total
}

// ---------------- f64 refine: per-chunk partials ----------------
// Chunks 0..3 (64 serial channels each) are freely distributable; only the
// final left-assoc combine is order-fixed. 2 half-blocks per 64-slot group,
// 128 threads each, grid 256. Per-chunk FMA order (ci asc, tap asc) and LDS
// weight staging unchanged from R2.
__global__ __launch_bounds__(128) void k_refine(
    const float* __restrict__ p0, const float* __restrict__ p1,
    const float* __restrict__ p2, const float* __restrict__ p3,
    const float* __restrict__ p4,
    const double* __restrict__ w5,
    const uint32_t* __restrict__ alist, const uint32_t* __restrict__ cnts,
    double* __restrict__ ppart) {
  __shared__ int4 wlds[2][768];            // 12 KB per wave
  int tid = threadIdx.x, wv = tid >> 6, ln = tid & 63;
  int cnt = (int)cnts[0];
  if (cnt > POOL_CAP) cnt = POOL_CAP;
  int grp = blockIdx.x >> 1, half = blockIdx.x & 1;
  int base = grp * 64;
  if (base >= cnt) return;                 // uniform early-exit
  int slot = base + ln;
  if (slot >= cnt) slot = cnt - 1;         // dup tail (benign same-value writes)
  int gi = (int)alist[slot];
  int gpix = gi / 3, a = gi - gpix * 3;
  int L = 0;
  while (L < 4 && gpix >= GPOFF[L + 1]) ++L;
  int pix = gpix - GPOFF[L];
  const float* inL = (L == 0) ? p0 : (L == 1) ? p1 : (L == 2) ? p2 : (L == 3) ? p3 : p4;
  int H = LV_H[L], W = LV_W[L], HW = H * W;
  int h = pix / W, w = pix % W;
  bool rok[3], cok[3];
  int roff[3];
#pragma unroll
  for (int ky = 0; ky < 3; ++ky) {
    int iy = h + ky - 1;
    rok[ky] = (iy >= 0 && iy < H);
    roff[ky] = iy * W + w - 1;
  }
#pragma unroll
  for (int kx = 0; kx < 3; ++kx) {
    int ix = w + kx - 1;
    cok[kx] = (ix >= 0 && ix < W);
  }
  int chunk = half * 2 + wv;               // 0..3: 64-channel serial chunk
  int ci0 = chunk * 64;
  const char* wbc = (const char*)&wlds[wv][0];
  // prologue: stage weight chunk 0 (channels ci0 .. ci0+8)
  {
    const int4* gs = (const int4*)((const char*)w5 + (size_t)ci0 * 1536);
    int4 r[12];
#pragma unroll
    for (int i = 0; i < 12; ++i) r[i] = gs[i * 64 + ln];
#pragma unroll
    for (int i = 0; i < 12; ++i) wlds[wv][i * 64 + ln] = r[i];
  }
  double sc = 0.0, d0 = 0.0, d1 = 0.0, d2 = 0.0, d3 = 0.0;
  const float* ibn = inL + (size_t)ci0 * HW;
  float vn[9];
  load9(vn, ibn, rok, cok, roff);          // feature prefetch for channel 0
#pragma unroll 1
  for (int k = 0; k < 8; ++k) {
    int4 r[12];
    if (k < 7) {                           // issue next chunk's weight loads
      const int4* gs =
          (const int4*)((const char*)w5 + (size_t)(ci0 + (k + 1) * 8) * 1536);
#pragma unroll
      for (int i = 0; i < 12; ++i) r[i] = gs[i * 64 + ln];
    }
#pragma unroll 1
    for (int c2 = 0; c2 < 8; ++c2) {
      float vc[9];
#pragma unroll
      for (int q = 0; q < 9; ++q) vc[q] = vn[q];
      int lc = k * 8 + c2;
      if (lc < 63) {                       // uniform; prefetch next channel
        ibn += HW;
        load9(vn, ibn, rok, cok, roff);
      }
      const char* b2 = wbc + c2 * 1536 + a * 48;
#pragma unroll
      for (int t9 = 0; t9 < 9; ++t9) {
        double vd = (double)vc[t9];
        double2 w01 = *(const double2*)(b2 + t9 * 144);
        double2 w23 = *(const double2*)(b2 + t9 * 144 + 16);
        double  w4  = *(const double*)(b2 + t9 * 144 + 32);
        d0 += vd * w01.x; d1 += vd * w01.y;
        d2 += vd * w23.x; d3 += vd * w23.y;
        sc += vd * w4;
      }
    }
    if (k < 7) {                           // land next chunk in LDS
#pragma unroll
      for (int i = 0; i < 12; ++i) wlds[wv][i * 64 + ln] = r[i];
    }
  }
  double* o = ppart + ((size_t)slot * 4 + chunk) * 5;
  o[0] = sc; o[1] = d0; o[2] = d1; o[3] = d2; o[4] = d3;
}

// ---------------- combine partials: bit-exact ((c0+c1)+c2)+c3 ----------------
__global__ __launch_bounds__(256) void k_comb(
    const uint32_t* __restrict__ alist, const uint32_t* __restrict__ cnts,
    const double* __restrict__ ppart, const double* __restrict__ fb,
    double* __restrict__ logits, double* __restrict__ deltas,
    uint64_t* __restrict__ pkey) {
  int e = blockIdx.x * 256 + threadIdx.x;
  int cnt = (int)cnts[0];
  if (cnt > POOL_CAP) cnt = POOL_CAP;
  if (blockIdx.x * 256 >= cnt) return;     // uniform early-exit
  if (e >= cnt) return;
  int gi = (int)alist[e];
  int a = gi - (gi / 3) * 3;
  const double* p = ppart + (size_t)e * 20;
  double f[5];
#pragma unroll
  for (int j = 0; j < 5; ++j)
    f[j] = ((p[0 + j] + p[5 + j]) + p[10 + j]) + p[15 + j];   // left-assoc
  int js = a, jd = 3 + 4 * a;
  double lg = f[0] + fb[js];
  logits[gi] = lg;
  deltas[gi * 4 + 0] = f[1] + fb[jd + 0];
  deltas[gi * 4 + 1] = f[2] + fb[jd + 1];
  deltas[gi * 4 + 2] = f[3] + fb[jd + 2];
  deltas[gi * 4 + 3] = f[4] + fb[jd + 3];
  // top-47 bits of sortable f64 logit; low 17 bits inverted index ->
  // rank-descending breaks score ties by ascending index (top_k semantics)
  pkey[e] = (sort64(lg) & ~0x1FFFFull) | (uint64_t)(0x1FFFFu - (uint32_t)gi);
}

// ---------------- 2D rank-by-counting: 32 i-tiles x 16 j-chunks ----------------
// rank32[e] += #{j in chunk : pkey[j] > pkey[e]}  (u32 atomics: exact, commutative)
__global__ __launch_bounds__(256) void k_rank_cnt(const uint32_t* __restrict__ cnts,
                                                  const uint64_t* __restrict__ pkey,
                                                  uint32_t* __restrict__ rank32) {
  __shared__ uint64_t lk[512];
  int t = threadIdx.x;
  int cnt = (int)cnts[0];
  if (cnt > POOL_CAP) cnt = POOL_CAP;
  int it = blockIdx.x >> 4, jc = blockIdx.x & 15;
  int e = it * 256 + t;
  int c0 = jc * 512;
  if (it * 256 >= cnt || c0 >= cnt) return;   // uniform early-exit
  int lim = cnt - c0; if (lim > 512) lim = 512;
  for (int i = t; i < 512; i += 256) lk[i] = (i < lim) ? pkey[c0 + i] : 0ull;
  __syncthreads();
  bool active = e < cnt;
  uint64_t mykey = active ? pkey[e] : ~0ull;   // ~0 counts nothing
  int r = 0;
#pragma unroll 8
  for (int j = 0; j < 512; ++j) r += (lk[j] > mykey) ? 1 : 0;
  if (active && r) atomicAdd(&rank32[e], (uint32_t)r);
}

// ---------------- scatter by rank + box decode ----------------
__global__ __launch_bounds__(256) void k_scatter(const uint32_t* __restrict__ cnts,
                                                 const uint64_t* __restrict__ pkey,
                                                 const uint32_t* __restrict__ rank32,
                                                 const double* __restrict__ logits,
                                                 const double* __restrict__ deltas,
                                                 const float* __restrict__ im_info,
                                                 double* __restrict__ ss,
                                                 double* __restrict__ sbx,
                                                 float4* __restrict__ bxf,
                                                 float* __restrict__ areaf) {
  int t = threadIdx.x;
  int cnt = (int)cnts[0];
  if (cnt > POOL_CAP) cnt = POOL_CAP;
  int e = blockIdx.x * 256 + t;
  if (blockIdx.x * 256 >= cnt) return;     // uniform
  if (e >= cnt) return;
  int rank = (int)rank32[e];
  if (rank >= PRE_NMS) return;
  uint64_t mykey = pkey[e];
  int gi = 0x1FFFF - (int)(mykey & 0x1FFFFull);
  int L = 0;
  while (L < 4 && gi >= LV_AOFF[L + 1]) ++L;
  int rel = gi - LV_AOFF[L];
  int pix = rel / 3, a = rel % 3;
  int W = LV_W[L];
  int h = pix / W, w = pix % W;
  double imW1 = (double)im_info[1] - 1.0;
  double imH1 = (double)im_info[0] - 1.0;
  double shx = (double)(w * LV_STRIDE[L]), shy = (double)(h * LV_STRIDE[L]);
  double ax1 = BASE_ANCH[L][a][0] + shx, ay1 = BASE_ANCH[L][a][1] + shy;
  double ax2 = BASE_ANCH[L][a][2] + shx, ay2 = BASE_ANCH[L][a][3] + shy;
  double dx = deltas[gi * 4 + 0], dy = deltas[gi * 4 + 1];
  double dw = deltas[gi * 4 + 2], dh = deltas[gi * 4 + 3];
  double wa = ax2 - ax1 + 1.0, ha = ay2 - ay1 + 1.0;
  double cx = ax1 + 0.5 * wa, cy = ay1 + 0.5 * ha;
  double pcx = dx * wa + cx, pcy = dy * ha + cy;
  double pw = exp(dw) * wa, ph = exp(dh) * ha;
  double x1 = fmin(fmax(pcx - 0.5 * pw, 0.0), imW1);
  double y1 = fmin(fmax(pcy - 0.5 * ph, 0.0), imH1);
  double x2 = fmin(fmax(pcx + 0.5 * pw, 0.0), imW1);
  double y2 = fmin(fmax(pcy + 0.5 * ph, 0.0), imH1);
  ss[rank] = 1.0 / (1.0 + exp(-logits[gi]));
  sbx[rank * 4 + 0] = x1; sbx[rank * 4 + 1] = y1;
  sbx[rank * 4 + 2] = x2; sbx[rank * 4 + 3] = y2;
  float4 bf;
  bf.x = (float)x1; bf.y = (float)y1; bf.z = (float)x2; bf.w = (float)y2;
  bxf[rank] = bf;
  areaf[rank] = (float)((x2 - x1 + 1.0) * (y2 - y1 + 1.0));
}

// ---------------- exact f64 IoU decision (reference semantics) ----------------
__device__ __forceinline__ bool iou_gt(const double* A, const double* B) {
  double areaA = (A[2] - A[0] + 1.0) * (A[3] - A[1] + 1.0);
  double areaB = (B[2] - B[0] + 1.0) * (B[3] - B[1] + 1.0);
  double xx1 = fmax(A[0], B[0]), yy1 = fmax(A[1], B[1]);
  double xx2 = fmin(A[2], B[2]), yy2 = fmin(A[3], B[3]);
  double iw = fmax(0.0, xx2 - xx1 + 1.0), ih = fmax(0.0, yy2 - yy1 + 1.0);
  double inter = iw * ih;
  return inter > 0.7 * (areaA + areaB - inter);
}

// ---------------- suppression matrix build (upper triangle) ----------------
__global__ __launch_bounds__(256) void k_build(const double* __restrict__ sbx,
                                               const float4* __restrict__ bxf,
                                               const float* __restrict__ areaf,
                                               uint64_t* __restrict__ Sup) {
  __shared__ float cbx[256][5];
  __shared__ float rbx[64][5];
  int blk = blockIdx.x;
  int rtile = blk / 24, ctile = blk % 24;   // 94 x 24
  int t = threadIdx.x, q = t >> 6, ln = t & 63;
  int r = rtile * 64 + ln;
  int w = ctile * 4 + q;                    // word 0..95
  {
    int c = ctile * 256 + t;
    float4 b;
    float ar;
    if (c < NMS_BLKS * 64) { b = bxf[c]; ar = areaf[c]; }
    else { b.x = b.y = b.z = b.w = 0.f; ar = 0.f; }
    cbx[t][0] = b.x; cbx[t][1] = b.y; cbx[t][2] = b.z; cbx[t][3] = b.w; cbx[t][4] = ar;
    if (t < 64) {
      int rr = rtile * 64 + t;
      float4 rb = bxf[rr];
      rbx[t][0] = rb.x; rbx[t][1] = rb.y; rbx[t][2] = rb.z; rbx[t][3] = rb.w;
      rbx[t][4] = areaf[rr];
    }
  }
  __syncthreads();
  uint64_t bits = 0ull;
  int j0 = w * 64;
  if (w < NMS_BLKS && j0 + 63 > r) {
    float ax1 = rbx[ln][0], ay1 = rbx[ln][1], ax2 = rbx[ln][2], ay2 = rbx[ln][3];
    float aar = rbx[ln][4];
#pragma unroll 4
    for (int jj = 0; jj < 64; ++jj) {
      int j = j0 + jj;
      if (j <= r) continue;
      int cl = q * 64 + jj;
      float iw = fminf(ax2, cbx[cl][2]) - fmaxf(ax1, cbx[cl][0]) + 1.f;
      float ih = fminf(ay2, cbx[cl][3]) - fmaxf(ay1, cbx[cl][1]) + 1.f;
      float inter = fmaxf(iw, 0.f) * fmaxf(ih, 0.f);
      float d = inter - 0.7f * (aar + cbx[cl][4] - inter);
      bool sup;
      if (d > 4.0f) sup = true;
      else if (d < -4.0f) sup = false;
      else sup = iou_gt(sbx + (size_t)r * 4, sbx + (size_t)j * 4);  // rare
      if (sup) bits |= 1ull << jj;
    }
  }
  Sup[(size_t)r * SUP_W + w] = bits;
}

// ---------------- pipelined greedy NMS scan, vmcnt kept across barriers ----
// R9 postmortem: __syncthreads() drains vmcnt(0) per wave BEFORE s_barrier, so
// both scattered-load rounds (wave-0 prefetch + ORer row gathers) sat ON the
// barrier path every phase (~1840cy/phase). This kernel has NO cross-wave
// global-memory communication (Sup read-only), so the drain is unnecessary:
// use raw s_barrier with lgkmcnt(0)-only (LDS visibility), letting global
// loads stay in flight across barriers (per-wave vmcnt waits at use).
//  - wave 0: diag/nxt1/nxt2 prefetched one phase ahead; folds words b+1 AND
//    b+2 of new keeps (2 extra off-critical-path readlanes per keep).
//  - waves 1-15: 1-phase-deep pipeline: ISSUE register loads at phase b
//    (keeps of b-1, words >= b+2, 4 held u64, static idx), OR into ext at
//    b+1. Overflow (>40 keeps/phase, rare) direct-loads at consume.
// Coverage of keeps from phase a: wave-0 folds a+1,a+2 at a; ORers issue at
// a+1 (words >= a+3), land at a+2, first read at a+3. Greedy order identical
// -> same keep set (absmax 0).
__global__ __launch_bounds__(1024) void k_scan(const uint64_t* __restrict__ Sup,
                                               const double* __restrict__ ss,
                                               const double* __restrict__ sbx,
                                               float* __restrict__ out) {
  __shared__ uint16_t keep[POST_NMS];
  __shared__ uint32_t ext_arr[SUP_W][2];
  __shared__ int s_kcnt, s_done;
  __shared__ int s_pend[2][2];             // parity-double-buffered pend range
  int t = threadIdx.x, wv = t >> 6, ln = t & 63;
  for (int i = t; i < SUP_W * 2; i += 1024) ext_arr[i >> 1][i & 1] = 0u;
  if (t == 0) { s_kcnt = 0; s_done = 0; }
  if (t < 4) s_pend[t >> 1][t & 1] = 0;
  uint64_t diag = 0ull, nxt1 = 0ull, nxt2 = 0ull;
  if (wv == 0) {                           // prefetch block-0 words 0,1,2
    size_t r = (size_t)ln * SUP_W;
    diag = Sup[r + 0];
    nxt1 = Sup[r + 1];
    nxt2 = Sup[r + 2];
  }
  uint64_t rv0 = 0, rv1 = 0, rv2 = 0, rv3 = 0;   // ORer pipeline registers
  int pw = 0, plo = 0, phi = 0;
  __syncthreads();
  for (int b = 0; b < NMS_BLKS; ++b) {
    if (wv == 0) {
      uint64_t myrow = diag & ~((2ull << ln) - 1ull);
      uint64_t myn1 = nxt1, myn2 = nxt2;
      if (b + 1 < NMS_BLKS) {              // issue next-phase prefetch early
        size_t r = (size_t)((b + 1) * 64 + ln) * SUP_W;
        diag = Sup[r + (b + 1)];
        nxt1 = Sup[r + (b + 2)];           // b+2 <= 94 < SUP_W
        nxt2 = Sup[r + (b + 3)];           // b+3 <= 95 < SUP_W (b <= 92 here)
      }
      uint64_t ext = ((uint64_t)ext_arr[b][1] << 32) | ext_arr[b][0];
      int base = b * 64;
      if (base + 63 >= PRE_NMS) {
        int v = PRE_NMS - base;            // 48 for the tail block
        ext |= ~((1ull << v) - 1ull);
      }
      int K0 = s_kcnt;
      // scalarize: avail is wave-uniform; greedy chain runs on the scalar
      // unit with readlane broadcasts (no ds_bpermute).
      uint64_t avail;
      {
        uint64_t a0 = ~ext;
        uint32_t alo = __builtin_amdgcn_readfirstlane((uint32_t)a0);
        uint32_t ahi = __builtin_amdgcn_readfirstlane((uint32_t)(a0 >> 32));
        avail = ((uint64_t)ahi << 32) | alo;
      }
      uint32_t mr_lo = (uint32_t)myrow, mr_hi = (uint32_t)(myrow >> 32);
      uint32_t n1_lo = (uint32_t)myn1, n1_hi = (uint32_t)(myn1 >> 32);
      uint32_t n2_lo = (uint32_t)myn2, n2_hi = (uint32_t)(myn2 >> 32);
      uint64_t kp = 0ull, extn1 = 0ull, extn2 = 0ull;
      int lim = POST_NMS - K0, nk = 0;
      while (avail && nk < lim) {
        int i2 = __ffsll((unsigned long long)avail) - 1;
        uint32_t rlo = (uint32_t)__builtin_amdgcn_readlane((int)mr_lo, i2);
        uint32_t rhi = (uint32_t)__builtin_amdgcn_readlane((int)mr_hi, i2);
        uint32_t a1l = (uint32_t)__builtin_amdgcn_readlane((int)n1_lo, i2);
        uint32_t a1h = (uint32_t)__builtin_amdgcn_readlane((int)n1_hi, i2);
        uint32_t a2l = (uint32_t)__builtin_amdgcn_readlane((int)n2_lo, i2);
        uint32_t a2h = (uint32_t)__builtin_amdgcn_readlane((int)n2_hi, i2);
        kp |= 1ull << i2;
        ++nk;
        extn1 |= ((uint64_t)a1h << 32) | a1l;
        extn2 |= ((uint64_t)a2h << 32) | a2l;
        avail &= ~(((uint64_t)rhi << 32) | rlo);
        avail &= ~(1ull << i2);
      }
      if ((kp >> ln) & 1ull) {
        int pos = K0 + __popcll(kp & ((1ull << ln) - 1ull));
        keep[pos] = (uint16_t)(base + ln);
      }
      if (ln == 0) {
        if ((uint32_t)extn1)         atomicOr(&ext_arr[b + 1][0], (uint32_t)extn1);
        if ((uint32_t)(extn1 >> 32)) atomicOr(&ext_arr[b + 1][1],
                                              (uint32_t)(extn1 >> 32));
        if ((uint32_t)extn2)         atomicOr(&ext_arr[b + 2][0], (uint32_t)extn2);
        if ((uint32_t)(extn2 >> 32)) atomicOr(&ext_arr[b + 2][1],
                                              (uint32_t)(extn2 >> 32));
        s_kcnt = K0 + nk;
        s_pend[(b + 1) & 1][0] = K0;       // pend range for next phase's ORers
        s_pend[(b + 1) & 1][1] = K0 + nk;
        if (K0 + nk >= POST_NMS || b + 1 >= NMS_BLKS) s_done = 1;
      }
    } else {
      int tt = t - 64;                     // 0..959
      int g = tt / 96, w = tt - g * 96;    // 10 row-groups x 96 words
      // consume: OR values loaded last phase (keeps of b-2, words >= b+1)
      if (phi > plo) {
        uint64_t v = rv0 | rv1 | rv2 | rv3;
        for (int q = plo + 40 + g; q < phi; q += 10)   // overflow (rare)
          v |= Sup[(size_t)keep[q] * SUP_W + pw];
        if (v) {
          if ((uint32_t)v)         atomicOr(&ext_arr[pw][0], (uint32_t)v);
          if ((uint32_t)(v >> 32)) atomicOr(&ext_arr[pw][1], (uint32_t)(v >> 32));
        }
      }
      rv0 = rv1 = rv2 = rv3 = 0ull;
      plo = 0; phi = 0;
      // issue: register loads for keeps of b-1, words >= b+2 (land at b+1)
      int lo = s_pend[b & 1][0], hi = s_pend[b & 1][1];
      if (hi > lo && w >= b + 2) {
        int q = lo + g;
        if (q < hi) rv0 = Sup[(size_t)keep[q] * SUP_W + w];
        q += 10;
        if (q < hi) rv1 = Sup[(size_t)keep[q] * SUP_W + w];
        q += 10;
        if (q < hi) rv2 = Sup[(size_t)keep[q] * SUP_W + w];
        q += 10;
        if (q < hi) rv3 = Sup[(size_t)keep[q] * SUP_W + w];
        plo = lo; phi = hi; pw = w;
      }
    }
    // raw barrier: drain LDS only; global loads stay in flight (per-wave
    // vmcnt waits happen at each wave's own use point next phase).
    asm volatile("s_waitcnt lgkmcnt(0)" ::: "memory");
    __builtin_amdgcn_s_barrier();
    asm volatile("" ::: "memory");
    if (s_done) break;                     // uniform: LDS value after barrier
  }
  __syncthreads();
  int KF = s_kcnt;
  for (int r = t; r < POST_NMS; r += 1024) {
    float* o = out + r * 6;
    if (r < KF) {
      int p = keep[r];
      o[0] = 0.f;
      o[1] = (float)sbx[p * 4 + 0];
      o[2] = (float)sbx[p * 4 + 1];
      o[3] = (float)sbx[p * 4 + 2];
      o[4] = (float)sbx[p * 4 + 3];
      o[5] = (float)ss[p];
    } else {
#pragma unroll
      for (int c = 0; c < 6; ++c) o[c] = 0.f;
    }
  }
}

// ---------------- host launch ----------------
extern "C" void kernel_launch(void* const* d_in, const int* in_sizes, int n_in,
                              void* d_out, int out_size, void* d_ws, size_t ws_size,
                              hipStream_t stream) {
  const float* p0 = (const float*)d_in[0];
  const float* p1 = (const float*)d_in[1];
  const float* p2 = (const float*)d_in[2];
  const float* p3 = (const float*)d_in[3];
  const float* p4 = (const float*)d_in[4];
  const float* im_info = (const float*)d_in[5];
  const float* cw = (const float*)d_in[6];
  const float* cb = (const float*)d_in[7];
  const float* sw = (const float*)d_in[8];
  const float* sb = (const float*)d_in[9];
  const float* bw = (const float*)d_in[10];
  const float* bb = (const float*)d_in[11];
  char* ws = (char*)d_ws;
  // ws layout (bytes):
  uint32_t* hist    = (uint32_t*)(ws + 0);         // 65536 u32 -> 262144
  uint32_t* cnts    = (uint32_t*)(ws + 262144);    // [0]=pool [1]=edge -> 262208
  double*   fb      = (double*)  (ws + 262208);    // 16 f64 -> 262336
  float*    fb32    = (float*)   (ws + 262336);    // 4 f32  -> 262352
  double*   logits  = (double*)  (ws + 262352);    // 106392 f64 -> 1113488
  double*   deltas  = (double*)  (ws + 1113488);   // 425568 f64 -> 4518032
  float*    logits32= (float*)   (ws + 4518032);   // 106392 f32 -> 4943600
  float4*   w3      = (float4*)  (ws + 4943600);   // 2304 float4 -> 4980464
  double*   Weff    = (double*)  (ws + 4980464);   // 2304*16 f64 -> 5275376
  double*   Wpart   = (double*)  (ws + 5275376);   // 16*2304*16 f64 -> 9993968
  uint32_t* alist   = (uint32_t*)(ws + 9993968);   // 8192 u32 -> 10026736
  double*   ssort   = (double*)  (ws + 10026736);  // 6016 f64 -> 10074864
  double*   sbx     = (double*)  (ws + 10074864);  // 6016*4 f64 -> 10267376
  float4*   bxf     = (float4*)  (ws + 10267376);  // 6016 float4 -> 10363632
  float*    areaf   = (float*)   (ws + 10363632);  // 6016 f32 -> 10387696
  uint64_t* Sup     = (uint64_t*)(ws + 10387696);  // 6016*96 u64 -> 15007984
  uint64_t* pkey    = (uint64_t*)(ws + 15007984);  // 8192 u64 -> 15073520
  uint32_t* rank32  = (uint32_t*)(ws + 15073520);  // 8192 u32 -> 15106288
  uint32_t* bcnt    = hist;                        // reuse: hist dead after k_edge
  double*   W5      = Wpart;                       // reuse: Wpart dead after k_weff_fin
  double*   ppart   = (double*)(ws + 5275376 + 524288);   // in Wpart, past W5
  float*    qpart   = (float*) (ws + 5275376 + 2097152);  // in Wpart, past ppart
  float* out = (float*)d_out;

  hipMemsetAsync(ws, 0, 262208, stream);             // hist + counters
  hipMemsetAsync(rank32, 0, 32768, stream);          // rank accumulators
  k_weff_part<<<144, 256, 0, stream>>>(cw, sw, bw, Wpart);
  k_weff_fin<<<10, 256, 0, stream>>>(Wpart, cb, sb, bb, sw, bw, Weff, fb, w3, fb32);
  k_w5<<<27, 256, 0, stream>>>(Weff, W5);
  k_fast<<<1110, 256, 0, stream>>>(p0, p1, p2, p3, p4, w3, qpart);
  k_fcomb<<<139, 256, 0, stream>>>(qpart, fb32, logits32, hist);
  k_edge<<<1, 1024, 0, stream>>>(hist, cnts);
  k_cnt<<<416, 256, 0, stream>>>(logits32, cnts, bcnt);
  k_fill<<<416, 256, 0, stream>>>(logits32, cnts, bcnt, alist);
  k_refine<<<256, 128, 0, stream>>>(p0, p1, p2, p3, p4, W5, alist, cnts, ppart);
  k_comb<<<32, 256, 0, stream>>>(alist, cnts, ppart, fb, logits, deltas, pkey);
  k_rank_cnt<<<512, 256, 0, stream>>>(cnts, pkey, rank32);
  k_scatter<<<32, 256, 0, stream>>>(cnts, pkey, rank32, logits, deltas, im_info,
                                    ssort, sbx, bxf, areaf);
  k_build<<<94 * 24, 256, 0, stream>>>(sbx, bxf, areaf, Sup);
  k_scan<<<1, 1024, 0, stream>>>(Sup, ssort, sbx, out);
}

// Round 11
// 409.991 us; speedup vs baseline: 1.0213x; 1.0213x over previous
//
#include <hip/hip_runtime.h>
#include <stdint.h>

#define N_ANCH   106392
#define PRE_NMS  6000
#define POST_NMS 1000
#define POOL_CAP 8192
#define NMS_BLKS 94   // 94*64 = 6016 >= 6000
#define SUP_W    96   // padded words per suppression row

static __device__ const int    LV_H[5]      = {128, 64, 32, 16, 8};
static __device__ const int    LV_W[5]      = {208, 104, 52, 26, 13};
static __device__ const int    LV_STRIDE[5] = {4, 8, 16, 32, 64};
static __device__ const int    LV_PIX[5]    = {26624, 6656, 1664, 416, 104};
static __device__ const int    LV_TILE0[6]  = {0, 416, 520, 546, 553, 555};
static __device__ const int    LV_AOFF[6]  = {0, 79872, 99840, 104832, 106080, 106392};
static __device__ const int    GPOFF[6]     = {0, 26624, 33280, 34944, 35360, 35464};
// Base anchors computed with np.round (half-even) semantics, verified by hand.
static __device__ const double BASE_ANCH[5][3][4] = {
  {{-22.,-10.,25.,13.},   {-14.,-14.,17.,17.},    {-10.,-22.,13.,25.}},
  {{-40.,-20.,47.,27.},   {-28.,-28.,35.,35.},    {-20.,-44.,27.,51.}},
  {{-84.,-40.,99.,55.},   {-56.,-56.,71.,71.},    {-36.,-80.,51.,95.}},
  {{-164.,-72.,195.,103.},{-112.,-112.,143.,143.},{-76.,-168.,107.,199.}},
  {{-332.,-152.,395.,215.},{-224.,-224.,287.,287.},{-148.,-328.,211.,391.}}
};

// sortable mappings (monotone): bigger value -> bigger key
__device__ __forceinline__ uint32_t sort32f(float f) {
  uint32_t u = __float_as_uint(f);
  return ((int)u < 0) ? ~u : (u | 0x80000000u);
}
__device__ __forceinline__ uint64_t sort64(double d) {
  uint64_t u = (uint64_t)__double_as_longlong(d);
  return ((long long)u < 0) ? ~u : (u | 0x8000000000000000ull);
}

// ---------------- f64 effective weights, 2-stage ----------------
// comb inline: j<3 -> sw[3+j][c]-sw[j][c]; 3<=j<15 -> bw[j-3][c]
__device__ __forceinline__ double combf(const float* sw, const float* bw, int c, int j) {
  if (j < 3) return (double)sw[(3 + j) * 512 + c] - (double)sw[j * 512 + c];
  return (double)bw[(j - 3) * 512 + c];
}

__global__ __launch_bounds__(256) void k_weff_part(const float* __restrict__ cw,
                                                   const float* __restrict__ sw,
                                                   const float* __restrict__ bw,
                                                   double* __restrict__ Wpart) {
  int chunk = blockIdx.x / 9;            // 16 chunks of 32 channels
  int tb = blockIdx.x % 9;               // 9 t-blocks of 256
  int t = tb * 256 + threadIdx.x;        // 0..2303
  int c0 = chunk * 32;
  double acc[15];
#pragma unroll
  for (int j = 0; j < 15; ++j) acc[j] = 0.0;
#pragma unroll 1
  for (int c = c0; c < c0 + 32; ++c) {
    double v = (double)cw[c * 2304 + t];
#pragma unroll
    for (int j = 0; j < 15; ++j) acc[j] += v * combf(sw, bw, c, j);
  }
  double* o = Wpart + (((size_t)chunk * 2304 + t) << 4);
#pragma unroll
  for (int j = 0; j < 15; ++j) o[j] = acc[j];
  o[15] = 0.0;
}

// blocks 0..8: Weff[t][j] = sum over chunks; also emit f32 screen weights w3.
// block 9: fb f64 + fb32.
__global__ __launch_bounds__(256) void k_weff_fin(const double* __restrict__ Wpart,
                                                  const float* __restrict__ cb,
                                                  const float* __restrict__ sb,
                                                  const float* __restrict__ bb,
                                                  const float* __restrict__ sw,
                                                  const float* __restrict__ bw,
                                                  double* __restrict__ Weff,
                                                  double* __restrict__ fb,
                                                  float4* __restrict__ w3,
                                                  float* __restrict__ fb32) {
  if (blockIdx.x == 9) {
    __shared__ double ps[15][16];
    int tid = threadIdx.x;
    if (tid < 240) {
      int j = tid >> 4, part = tid & 15;
      double s = 0.0;
      for (int c = part * 32; c < part * 32 + 32; ++c)
        s += (double)cb[c] * combf(sw, bw, c, j);
      ps[j][part] = s;
    }
    __syncthreads();
    if (tid < 15) {
      double s = 0.0;
#pragma unroll
      for (int part = 0; part < 16; ++part) s += ps[tid][part];  // fixed order
      s += (tid < 3) ? ((double)sb[3 + tid] - (double)sb[tid]) : (double)bb[tid - 3];
      fb[tid] = s;
      if (tid < 3) fb32[tid] = (float)s;
    }
    if (tid == 15) fb32[3] = 0.f;
    return;
  }
  int t = blockIdx.x * 256 + threadIdx.x;
  double acc[15];
#pragma unroll
  for (int j = 0; j < 15; ++j) acc[j] = 0.0;
#pragma unroll 1
  for (int chunk = 0; chunk < 16; ++chunk) {
    const double* p = Wpart + (((size_t)chunk * 2304 + t) << 4);
#pragma unroll
    for (int j = 0; j < 15; ++j) acc[j] += p[j];
  }
  double* o = Weff + ((size_t)t << 4);
#pragma unroll
  for (int j = 0; j < 15; ++j) o[j] = acc[j];
  o[15] = 0.0;
  float4 wf;
  wf.x = (float)acc[0]; wf.y = (float)acc[1]; wf.z = (float)acc[2]; wf.w = 0.f;
  w3[t] = wf;
}

// ---------------- W5: k_refine-friendly weight layout ----------------
// W5[ci][(t9*3+a)*6 + {0..5}] = {d0w,d1w,d2w,d3w,scorew,pad}, ci stride 192
// doubles (1536 B, 16B-aligned records of 48 B). Pure copy of Weff -> bit-exact.
__global__ __launch_bounds__(256) void k_w5(const double* __restrict__ Weff,
                                            double* __restrict__ w5) {
  int idx = blockIdx.x * 256 + threadIdx.x;   // (t, a): t = ci*9+t9
  if (idx >= 2304 * 3) return;
  int t = idx / 3, a = idx % 3;
  int ci = t / 9, t9 = t % 9;
  const double* src = Weff + ((size_t)t << 4);
  double* dst = w5 + (size_t)ci * 192 + (size_t)(t9 * 3 + a) * 6;
  int jd = 3 + 4 * a;
  dst[0] = src[jd + 0];
  dst[1] = src[jd + 1];
  dst[2] = src[jd + 2];
  dst[3] = src[jd + 3];
  dst[4] = src[a];
  dst[5] = 0.0;
}

// ---------------- f32 screening pass ----------------
__device__ __forceinline__ void load9(float v[9], const float* __restrict__ ib,
                                      const bool rok[3], const bool cok[3],
                                      const int roff[3]) {
#pragma unroll
  for (int ky = 0; ky < 3; ++ky)
#pragma unroll
    for (int kx = 0; kx < 3; ++kx)
      v[ky * 3 + kx] = (rok[ky] && cok[kx]) ? ib[roff[ky] + kx] : 0.0f;
}

// TLP-doubled screen (R9): grid 1110 = 2 channel-halves per pixel tile, each
// wave owns a 32-channel serial chain. Partials q=(r0+r1)+(r2+r3) -> qpart;
// k_fcomb adds halves + fb32. f64 path untouched; logits32 tree perturbation
// ~1e-4 relative is absorbed by the screen's 2-bin margin.
__global__ __launch_bounds__(256) void k_fast(
    const float* __restrict__ p0, const float* __restrict__ p1,
    const float* __restrict__ p2, const float* __restrict__ p3,
    const float* __restrict__ p4,
    const float4* __restrict__ w3, float* __restrict__ qpart) {
  __shared__ float4 w3s[1152];       // 18.4 KB: this block's 128 channels
  __shared__ float red[4][64][3];
  int tid = threadIdx.x, wv = tid >> 6, ln = tid & 63;
  int t = blockIdx.x >> 1, hf = blockIdx.x & 1;
  int cbase = hf * 128;
  for (int i = tid; i < 1152; i += 256) w3s[i] = w3[cbase * 9 + i];
  int L = 0;
  while (L < 4 && t >= LV_TILE0[L + 1]) ++L;
  const float* inL = (L == 0) ? p0 : (L == 1) ? p1 : (L == 2) ? p2 : (L == 3) ? p3 : p4;
  int H = LV_H[L], W = LV_W[L], HW = H * W, PIX = LV_PIX[L];
  int pix = (t - LV_TILE0[L]) * 64 + ln;
  if (pix >= PIX) pix = PIX - 1;           // clamp; k_fcomb skips invalid
  int h = pix / W, w = pix % W;
  bool rok[3], cok[3];
  int roff[3];
#pragma unroll
  for (int ky = 0; ky < 3; ++ky) {
    int iy = h + ky - 1;
    rok[ky] = (iy >= 0 && iy < H);
    roff[ky] = iy * W + w - 1;
  }
#pragma unroll
  for (int kx = 0; kx < 3; ++kx) {
    int ix = w + kx - 1;
    cok[kx] = (ix >= 0 && ix < W);
  }
  int lci0 = wv * 32;                      // LDS channel index within half
  const float* ibn = inL + (size_t)(cbase + lci0) * HW;
  float vn[9];
  load9(vn, ibn, rok, cok, roff);          // prefetch first channel
  __syncthreads();
  float a0 = 0.f, a1 = 0.f, a2 = 0.f;
#pragma unroll 1
  for (int c = 0; c < 32; ++c) {
    float vc[9];
#pragma unroll
    for (int q = 0; q < 9; ++q) vc[q] = vn[q];
    if (c < 31) {                          // uniform; prefetch next channel
      ibn += HW;
      load9(vn, ibn, rok, cok, roff);
    }
    const float4* wr = w3s + (lci0 + c) * 9;
#pragma unroll
    for (int t9 = 0; t9 < 9; ++t9) {
      float4 wt = wr[t9];                  // broadcast ds_read_b128
      float vv = vc[t9];
      a0 += vv * wt.x; a1 += vv * wt.y; a2 += vv * wt.z;
    }
  }
  red[wv][ln][0] = a0; red[wv][ln][1] = a1; red[wv][ln][2] = a2;
  __syncthreads();
  if (wv == 0) {
    float* o = qpart + ((size_t)(t * 2 + hf) * 64 + ln) * 3;
#pragma unroll
    for (int a = 0; a < 3; ++a)
      o[a] = (red[0][ln][a] + red[1][ln][a]) + (red[2][ln][a] + red[3][ln][a]);
  }
}

// combine channel-halves: f = (q0+q1)+fb32 -> logits32 + histogram
__global__ __launch_bounds__(256) void k_fcomb(
    const float* __restrict__ qpart, const float* __restrict__ fb32,
    float* __restrict__ logits32, uint32_t* __restrict__ hist) {
  int tid = threadIdx.x, ln = tid & 63;
  int t = blockIdx.x * 4 + (tid >> 6);
  if (t >= 555) return;
  int L = 0;
  while (L < 4 && t >= LV_TILE0[L + 1]) ++L;
  int PIX = LV_PIX[L];
  int pix = (t - LV_TILE0[L]) * 64 + ln;
  if (pix >= PIX) return;
  const float* q0 = qpart + ((size_t)(t * 2 + 0) * 64 + ln) * 3;
  const float* q1 = qpart + ((size_t)(t * 2 + 1) * 64 + ln) * 3;
  int gbase = LV_AOFF[L] + pix * 3;
#pragma unroll
  for (int a = 0; a < 3; ++a) {
    float f = (q0[a] + q1[a]) + fb32[a];
    logits32[gbase + a] = f;
    atomicAdd(&hist[sort32f(f) >> 16], 1u);
  }
}

// ---------------- edge finder (with 2-bin safety margin) ----------------
__global__ __launch_bounds__(1024) void k_edge(const uint32_t* __restrict__ hist,
                                               uint32_t* __restrict__ cnts) {
  __shared__ uint32_t cs[1024];
  __shared__ uint32_t g_grp, g_suf;
  int t = threadIdx.x, wv = t >> 6, ln = t & 63;
#pragma unroll 4
  for (int r = 0; r < 64; ++r) {
    int g = r * 16 + wv;
    uint32_t x = hist[g * 64 + ln];
#pragma unroll
    for (int off = 32; off > 0; off >>= 1) x += __shfl_down(x, off);
    if (ln == 0) cs[g] = x;
  }
  __syncthreads();
  for (int off = 1; off < 1024; off <<= 1) {
    uint32_t v = cs[t] + ((t + off < 1024) ? cs[t + off] : 0u);
    __syncthreads();
    cs[t] = v;
    __syncthreads();
  }
  uint32_t sufnext = (t < 1023) ? cs[t + 1] : 0u;
  if (cs[t] >= PRE_NMS && sufnext < PRE_NMS) {   // unique t
    g_grp = (uint32_t)t;
    g_suf = sufnext;
  }
  __syncthreads();
  if (t < 64) {   // wave 0: refine edge within the winning 64-bin group
    uint32_t grp = g_grp, suf = g_suf;
    uint32_t x = hist[grp * 64 + t];
    uint32_t S = x;
#pragma unroll
    for (int off = 1; off < 64; off <<= 1) {
      uint32_t y = __shfl_down(S, off);
      if (t + off < 64) S += y;
    }
    unsigned long long mask = __ballot(suf + S >= PRE_NMS);
    int hi = 63 - (int)__clzll(mask);
    if (t == hi) {
      uint32_t e = grp * 64 + (uint32_t)hi;
      cnts[1] = (e > 2) ? e - 2 : 0;     // -2 bin margin: f32 superset of f64 top-k
    }
  }
}

// ---------------- ordered pool compaction (f32 screen) ----------------
__global__ __launch_bounds__(256) void k_cnt(const float* __restrict__ logits32,
                                             const uint32_t* __restrict__ cnts,
                                             uint32_t* __restrict__ bcnt) {
  __shared__ uint32_t wc[4];
  int tid = threadIdx.x;
  int i = blockIdx.x * 256 + tid;
  uint32_t edge = cnts[1];
  bool pass = (i < N_ANCH) && ((sort32f(logits32[i]) >> 16) >= edge);
  unsigned long long m = __ballot(pass);
  if ((tid & 63) == 0) wc[tid >> 6] = (uint32_t)__popcll(m);
  __syncthreads();
  if (tid == 0) bcnt[blockIdx.x] = wc[0] + wc[1] + wc[2] + wc[3];
}

__global__ __launch_bounds__(256) void k_fill(const float* __restrict__ logits32,
                                              uint32_t* __restrict__ cnts,
                                              const uint32_t* __restrict__ bcnt,
                                              uint32_t* __restrict__ alist) {
  __shared__ uint32_t red[256];
  __shared__ uint32_t woff[4];
  int tid = threadIdx.x, wv = tid >> 6, ln = tid & 63;
  // exclusive prefix over preceding blocks (416 values, trivial)
  uint32_t s = 0;
  for (int k = tid; k < blockIdx.x; k += 256) s += bcnt[k];
  red[tid] = s;
  __syncthreads();
#pragma unroll
  for (int off = 128; off > 0; off >>= 1) {
    if (tid < off) red[tid] += red[tid + off];
    __syncthreads();
  }
  uint32_t base = red[0];
  int i = blockIdx.x * 256 + tid;
  uint32_t edge = cnts[1];
  bool pass = (i < N_ANCH) && ((sort32f(logits32[i]) >> 16) >= edge);
  unsigned long long m = __ballot(pass);
  if (ln == 0) woff[wv] = (uint32_t)__popcll(m);
  __syncthreads();
  uint32_t off_in_blk = 0;
  for (int k = 0; k < wv; ++k) off_in_blk += woff[k];
  if (pass) {
    uint32_t pos = base + off_in_blk + (uint32_t)__popcll(m & ((1ull << ln) - 1ull));
    if (pos < POOL_CAP) alist[pos] = (uint32_t)i;
  }
  if (blockIdx.x == ((N_ANCH + 255) / 256 - 1) && tid == 0)
    cnts[0] = base + woff[0] + woff[1] + woff[2] + woff[3];   // uncapped total
}

// ---------------- f64 refine: per-chunk partials ----------------
// Chunks 0..3 (64 serial channels each) are freely distributable; only the
// final left-assoc combine is order-fixed. 2 half-blocks per 64-slot group,
// 128 threads each, grid 256. Per-chunk FMA order (ci asc, tap asc) and LDS
// weight staging unchanged from R2.
__global__ __launch_bounds__(128) void k_refine(
    const float* __restrict__ p0, const float* __restrict__ p1,
    const float* __restrict__ p2, const float* __restrict__ p3,
    const float* __restrict__ p4,
    const double* __restrict__ w5,
    const uint32_t* __restrict__ alist, const uint32_t* __restrict__ cnts,
    double* __restrict__ ppart) {
  __shared__ int4 wlds[2][768];            // 12 KB per wave
  int tid = threadIdx.x, wv = tid >> 6, ln = tid & 63;
  int cnt = (int)cnts[0];
  if (cnt > POOL_CAP) cnt = POOL_CAP;
  int grp = blockIdx.x >> 1, half = blockIdx.x & 1;
  int base = grp * 64;
  if (base >= cnt) return;                 // uniform early-exit
  int slot = base + ln;
  if (slot >= cnt) slot = cnt - 1;         // dup tail (benign same-value writes)
  int gi = (int)alist[slot];
  int gpix = gi / 3, a = gi - gpix * 3;
  int L = 0;
  while (L < 4 && gpix >= GPOFF[L + 1]) ++L;
  int pix = gpix - GPOFF[L];
  const float* inL = (L == 0) ? p0 : (L == 1) ? p1 : (L == 2) ? p2 : (L == 3) ? p3 : p4;
  int H = LV_H[L], W = LV_W[L], HW = H * W;
  int h = pix / W, w = pix % W;
  bool rok[3], cok[3];
  int roff[3];
#pragma unroll
  for (int ky = 0; ky < 3; ++ky) {
    int iy = h + ky - 1;
    rok[ky] = (iy >= 0 && iy < H);
    roff[ky] = iy * W + w - 1;
  }
#pragma unroll
  for (int kx = 0; kx < 3; ++kx) {
    int ix = w + kx - 1;
    cok[kx] = (ix >= 0 && ix < W);
  }
  int chunk = half * 2 + wv;               // 0..3: 64-channel serial chunk
  int ci0 = chunk * 64;
  const char* wbc = (const char*)&wlds[wv][0];
  // prologue: stage weight chunk 0 (channels ci0 .. ci0+8)
  {
    const int4* gs = (const int4*)((const char*)w5 + (size_t)ci0 * 1536);
    int4 r[12];
#pragma unroll
    for (int i = 0; i < 12; ++i) r[i] = gs[i * 64 + ln];
#pragma unroll
    for (int i = 0; i < 12; ++i) wlds[wv][i * 64 + ln] = r[i];
  }
  double sc = 0.0, d0 = 0.0, d1 = 0.0, d2 = 0.0, d3 = 0.0;
  const float* ibn = inL + (size_t)ci0 * HW;
  float vn[9];
  load9(vn, ibn, rok, cok, roff);          // feature prefetch for channel 0
#pragma unroll 1
  for (int k = 0; k < 8; ++k) {
    int4 r[12];
    if (k < 7) {                           // issue next chunk's weight loads
      const int4* gs =
          (const int4*)((const char*)w5 + (size_t)(ci0 + (k + 1) * 8) * 1536);
#pragma unroll
      for (int i = 0; i < 12; ++i) r[i] = gs[i * 64 + ln];
    }
#pragma unroll 1
    for (int c2 = 0; c2 < 8; ++c2) {
      float vc[9];
#pragma unroll
      for (int q = 0; q < 9; ++q) vc[q] = vn[q];
      int lc = k * 8 + c2;
      if (lc < 63) {                       // uniform; prefetch next channel
        ibn += HW;
        load9(vn, ibn, rok, cok, roff);
      }
      const char* b2 = wbc + c2 * 1536 + a * 48;
#pragma unroll
      for (int t9 = 0; t9 < 9; ++t9) {
        double vd = (double)vc[t9];
        double2 w01 = *(const double2*)(b2 + t9 * 144);
        double2 w23 = *(const double2*)(b2 + t9 * 144 + 16);
        double  w4  = *(const double*)(b2 + t9 * 144 + 32);
        d0 += vd * w01.x; d1 += vd * w01.y;
        d2 += vd * w23.x; d3 += vd * w23.y;
        sc += vd * w4;
      }
    }
    if (k < 7) {                           // land next chunk in LDS
#pragma unroll
      for (int i = 0; i < 12; ++i) wlds[wv][i * 64 + ln] = r[i];
    }
  }
  double* o = ppart + ((size_t)slot * 4 + chunk) * 5;
  o[0] = sc; o[1] = d0; o[2] = d1; o[3] = d2; o[4] = d3;
}

// ---------------- combine partials: bit-exact ((c0+c1)+c2)+c3 ----------------
__global__ __launch_bounds__(256) void k_comb(
    const uint32_t* __restrict__ alist, const uint32_t* __restrict__ cnts,
    const double* __restrict__ ppart, const double* __restrict__ fb,
    double* __restrict__ logits, double* __restrict__ deltas,
    uint64_t* __restrict__ pkey) {
  int e = blockIdx.x * 256 + threadIdx.x;
  int cnt = (int)cnts[0];
  if (cnt > POOL_CAP) cnt = POOL_CAP;
  if (blockIdx.x * 256 >= cnt) return;     // uniform early-exit
  if (e >= cnt) return;
  int gi = (int)alist[e];
  int a = gi - (gi / 3) * 3;
  const double* p = ppart + (size_t)e * 20;
  double f[5];
#pragma unroll
  for (int j = 0; j < 5; ++j)
    f[j] = ((p[0 + j] + p[5 + j]) + p[10 + j]) + p[15 + j];   // left-assoc
  int js = a, jd = 3 + 4 * a;
  double lg = f[0] + fb[js];
  logits[gi] = lg;
  deltas[gi * 4 + 0] = f[1] + fb[jd + 0];
  deltas[gi * 4 + 1] = f[2] + fb[jd + 1];
  deltas[gi * 4 + 2] = f[3] + fb[jd + 2];
  deltas[gi * 4 + 3] = f[4] + fb[jd + 3];
  // top-47 bits of sortable f64 logit; low 17 bits inverted index ->
  // rank-descending breaks score ties by ascending index (top_k semantics)
  pkey[e] = (sort64(lg) & ~0x1FFFFull) | (uint64_t)(0x1FFFFu - (uint32_t)gi);
}

// ---------------- 2D rank-by-counting: 32 i-tiles x 16 j-chunks ----------------
// rank32[e] += #{j in chunk : pkey[j] > pkey[e]}  (u32 atomics: exact, commutative)
__global__ __launch_bounds__(256) void k_rank_cnt(const uint32_t* __restrict__ cnts,
                                                  const uint64_t* __restrict__ pkey,
                                                  uint32_t* __restrict__ rank32) {
  __shared__ uint64_t lk[512];
  int t = threadIdx.x;
  int cnt = (int)cnts[0];
  if (cnt > POOL_CAP) cnt = POOL_CAP;
  int it = blockIdx.x >> 4, jc = blockIdx.x & 15;
  int e = it * 256 + t;
  int c0 = jc * 512;
  if (it * 256 >= cnt || c0 >= cnt) return;   // uniform early-exit
  int lim = cnt - c0; if (lim > 512) lim = 512;
  for (int i = t; i < 512; i += 256) lk[i] = (i < lim) ? pkey[c0 + i] : 0ull;
  __syncthreads();
  bool active = e < cnt;
  uint64_t mykey = active ? pkey[e] : ~0ull;   // ~0 counts nothing
  int r = 0;
#pragma unroll 8
  for (int j = 0; j < 512; ++j) r += (lk[j] > mykey) ? 1 : 0;
  if (active && r) atomicAdd(&rank32[e], (uint32_t)r);
}

// ---------------- scatter by rank + box decode ----------------
__global__ __launch_bounds__(256) void k_scatter(const uint32_t* __restrict__ cnts,
                                                 const uint64_t* __restrict__ pkey,
                                                 const uint32_t* __restrict__ rank32,
                                                 const double* __restrict__ logits,
                                                 const double* __restrict__ deltas,
                                                 const float* __restrict__ im_info,
                                                 double* __restrict__ ss,
                                                 double* __restrict__ sbx,
                                                 float4* __restrict__ bxf,
                                                 float* __restrict__ areaf) {
  int t = threadIdx.x;
  int cnt = (int)cnts[0];
  if (cnt > POOL_CAP) cnt = POOL_CAP;
  int e = blockIdx.x * 256 + t;
  if (blockIdx.x * 256 >= cnt) return;     // uniform
  if (e >= cnt) return;
  int rank = (int)rank32[e];
  if (rank >= PRE_NMS) return;
  uint64_t mykey = pkey[e];
  int gi = 0x1FFFF - (int)(mykey & 0x1FFFFull);
  int L = 0;
  while (L < 4 && gi >= LV_AOFF[L + 1]) ++L;
  int rel = gi - LV_AOFF[L];
  int pix = rel / 3, a = rel % 3;
  int W = LV_W[L];
  int h = pix / W, w = pix % W;
  double imW1 = (double)im_info[1] - 1.0;
  double imH1 = (double)im_info[0] - 1.0;
  double shx = (double)(w * LV_STRIDE[L]), shy = (double)(h * LV_STRIDE[L]);
  double ax1 = BASE_ANCH[L][a][0] + shx, ay1 = BASE_ANCH[L][a][1] + shy;
  double ax2 = BASE_ANCH[L][a][2] + shx, ay2 = BASE_ANCH[L][a][3] + shy;
  double dx = deltas[gi * 4 + 0], dy = deltas[gi * 4 + 1];
  double dw = deltas[gi * 4 + 2], dh = deltas[gi * 4 + 3];
  double wa = ax2 - ax1 + 1.0, ha = ay2 - ay1 + 1.0;
  double cx = ax1 + 0.5 * wa, cy = ay1 + 0.5 * ha;
  double pcx = dx * wa + cx, pcy = dy * ha + cy;
  double pw = exp(dw) * wa, ph = exp(dh) * ha;
  double x1 = fmin(fmax(pcx - 0.5 * pw, 0.0), imW1);
  double y1 = fmin(fmax(pcy - 0.5 * ph, 0.0), imH1);
  double x2 = fmin(fmax(pcx + 0.5 * pw, 0.0), imW1);
  double y2 = fmin(fmax(pcy + 0.5 * ph, 0.0), imH1);
  ss[rank] = 1.0 / (1.0 + exp(-logits[gi]));
  sbx[rank * 4 + 0] = x1; sbx[rank * 4 + 1] = y1;
  sbx[rank * 4 + 2] = x2; sbx[rank * 4 + 3] = y2;
  float4 bf;
  bf.x = (float)x1; bf.y = (float)y1; bf.z = (float)x2; bf.w = (float)y2;
  bxf[rank] = bf;
  areaf[rank] = (float)((x2 - x1 + 1.0) * (y2 - y1 + 1.0));
}

// ---------------- exact f64 IoU decision (reference semantics) ----------------
__device__ __forceinline__ bool iou_gt(const double* A, const double* B) {
  double areaA = (A[2] - A[0] + 1.0) * (A[3] - A[1] + 1.0);
  double areaB = (B[2] - B[0] + 1.0) * (B[3] - B[1] + 1.0);
  double xx1 = fmax(A[0], B[0]), yy1 = fmax(A[1], B[1]);
  double xx2 = fmin(A[2], B[2]), yy2 = fmin(A[3], B[3]);
  double iw = fmax(0.0, xx2 - xx1 + 1.0), ih = fmax(0.0, yy2 - yy1 + 1.0);
  double inter = iw * ih;
  return inter > 0.7 * (areaA + areaB - inter);
}

// ---------------- suppression matrix build (upper triangle) ----------------
__global__ __launch_bounds__(256) void k_build(const double* __restrict__ sbx,
                                               const float4* __restrict__ bxf,
                                               const float* __restrict__ areaf,
                                               uint64_t* __restrict__ Sup) {
  __shared__ float cbx[256][5];
  __shared__ float rbx[64][5];
  int blk = blockIdx.x;
  int rtile = blk / 24, ctile = blk % 24;   // 94 x 24
  int t = threadIdx.x, q = t >> 6, ln = t & 63;
  int r = rtile * 64 + ln;
  int w = ctile * 4 + q;                    // word 0..95
  {
    int c = ctile * 256 + t;
    float4 b;
    float ar;
    if (c < NMS_BLKS * 64) { b = bxf[c]; ar = areaf[c]; }
    else { b.x = b.y = b.z = b.w = 0.f; ar = 0.f; }
    cbx[t][0] = b.x; cbx[t][1] = b.y; cbx[t][2] = b.z; cbx[t][3] = b.w; cbx[t][4] = ar;
    if (t < 64) {
      int rr = rtile * 64 + t;
      float4 rb = bxf[rr];
      rbx[t][0] = rb.x; rbx[t][1] = rb.y; rbx[t][2] = rb.z; rbx[t][3] = rb.w;
      rbx[t][4] = areaf[rr];
    }
  }
  __syncthreads();
  uint64_t bits = 0ull;
  int j0 = w * 64;
  if (w < NMS_BLKS && j0 + 63 > r) {
    float ax1 = rbx[ln][0], ay1 = rbx[ln][1], ax2 = rbx[ln][2], ay2 = rbx[ln][3];
    float aar = rbx[ln][4];
#pragma unroll 4
    for (int jj = 0; jj < 64; ++jj) {
      int j = j0 + jj;
      if (j <= r) continue;
      int cl = q * 64 + jj;
      float iw = fminf(ax2, cbx[cl][2]) - fmaxf(ax1, cbx[cl][0]) + 1.f;
      float ih = fminf(ay2, cbx[cl][3]) - fmaxf(ay1, cbx[cl][1]) + 1.f;
      float inter = fmaxf(iw, 0.f) * fmaxf(ih, 0.f);
      float d = inter - 0.7f * (aar + cbx[cl][4] - inter);
      bool sup;
      if (d > 4.0f) sup = true;
      else if (d < -4.0f) sup = false;
      else sup = iou_gt(sbx + (size_t)r * 4, sbx + (size_t)j * 4);  // rare
      if (sup) bits |= 1ull << jj;
    }
  }
  Sup[(size_t)r * SUP_W + w] = bits;
}

// ---------------- single-barrier pipelined greedy NMS scan (scalar chain) ----
// R9 version (reverted from R10): wave-uniform greedy chain on the scalar
// unit (s_ff1 -> readlane x2 -> s_andn2, ~25cy/keep). Next-block ext fold =
// two extra readlanes per keep off the critical path. Waves 1-15 OR full
// remaining rows of phase b-1 keeps concurrently; one barrier per phase.
// R10's A/B showed: no-vmcnt-drain barrier + deeper fold REGRESSED (+8.5us)
// -- the drain is not the bottleneck; readlanes-per-keep on the serial chain
// is the currency. Keep the 4-readlane version.
__global__ __launch_bounds__(1024) void k_scan(const uint64_t* __restrict__ Sup,
                                               const double* __restrict__ ss,
                                               const double* __restrict__ sbx,
                                               float* __restrict__ out) {
  __shared__ uint16_t keep[POST_NMS];
  __shared__ uint32_t ext_arr[SUP_W][2];
  __shared__ int s_kcnt, s_done;
  __shared__ int s_pend[2][2];             // parity-double-buffered pend range
  int t = threadIdx.x, wv = t >> 6, ln = t & 63;
  for (int i = t; i < SUP_W * 2; i += 1024) ext_arr[i >> 1][i & 1] = 0u;
  if (t == 0) { s_kcnt = 0; s_done = 0; }
  if (t < 4) s_pend[t >> 1][t & 1] = 0;
  uint64_t diag = 0ull, nxt = 0ull;
  if (wv == 0) {                           // prefetch block-0 diag pair
    size_t r = (size_t)ln * SUP_W;
    diag = Sup[r + 0];
    nxt  = Sup[r + 1];
  }
  __syncthreads();
  for (int b = 0; b < NMS_BLKS; ++b) {
    if (wv == 0) {
      uint64_t myrow = diag & ~((2ull << ln) - 1ull);
      uint64_t mynxt = nxt;
      if (b + 1 < NMS_BLKS) {              // issue next-phase prefetch early
        size_t r = (size_t)((b + 1) * 64 + ln) * SUP_W;
        diag = Sup[r + (b + 1)];
        nxt  = Sup[r + (b + 2)];           // b+2 <= 95 < SUP_W
      }
      uint64_t ext = ((uint64_t)ext_arr[b][1] << 32) | ext_arr[b][0];
      int base = b * 64;
      if (base + 63 >= PRE_NMS) {
        int v = PRE_NMS - base;            // 48 for the tail block
        ext |= ~((1ull << v) - 1ull);
      }
      int K0 = s_kcnt;
      // scalarize: avail is wave-uniform; hoist to SGPRs so the greedy chain
      // runs on the scalar unit with readlane broadcasts (no ds_bpermute).
      uint64_t avail;
      {
        uint64_t a0 = ~ext;
        uint32_t alo = __builtin_amdgcn_readfirstlane((uint32_t)a0);
        uint32_t ahi = __builtin_amdgcn_readfirstlane((uint32_t)(a0 >> 32));
        avail = ((uint64_t)ahi << 32) | alo;
      }
      uint32_t mr_lo = (uint32_t)myrow, mr_hi = (uint32_t)(myrow >> 32);
      uint32_t mn_lo = (uint32_t)mynxt, mn_hi = (uint32_t)(mynxt >> 32);
      uint64_t kp = 0ull, extn = 0ull;
      int lim = POST_NMS - K0, nk = 0;
      while (avail && nk < lim) {
        int i2 = __ffsll((unsigned long long)avail) - 1;
        uint32_t rlo = (uint32_t)__builtin_amdgcn_readlane((int)mr_lo, i2);
        uint32_t rhi = (uint32_t)__builtin_amdgcn_readlane((int)mr_hi, i2);
        uint32_t qlo = (uint32_t)__builtin_amdgcn_readlane((int)mn_lo, i2);
        uint32_t qhi = (uint32_t)__builtin_amdgcn_readlane((int)mn_hi, i2);
        kp |= 1ull << i2;
        ++nk;
        extn |= ((uint64_t)qhi << 32) | qlo;
        avail &= ~(((uint64_t)rhi << 32) | rlo);
        avail &= ~(1ull << i2);
      }
      if ((kp >> ln) & 1ull) {
        int pos = K0 + __popcll(kp & ((1ull << ln) - 1ull));
        keep[pos] = (uint16_t)(base + ln);
      }
      if (ln == 0) {
        if ((uint32_t)extn)         atomicOr(&ext_arr[b + 1][0], (uint32_t)extn);
        if ((uint32_t)(extn >> 32)) atomicOr(&ext_arr[b + 1][1],
                                             (uint32_t)(extn >> 32));
        s_kcnt = K0 + nk;
        s_pend[(b + 1) & 1][0] = K0;       // pend range for next phase's ORers
        s_pend[(b + 1) & 1][1] = K0 + nk;
        if (K0 + nk >= POST_NMS || b + 1 >= NMS_BLKS) s_done = 1;
      }
    } else {
      // waves 1-15: full-row OR of phase b-1's keeps, words >= b+1 only
      // (word b was folded by wave 0 last phase; wave 0 reads word b now).
      int lo = s_pend[b & 1][0], hi = s_pend[b & 1][1];
      if (hi > lo) {
        int tt = t - 64;                   // 0..959
        int g = tt / 96, w = tt - g * 96;  // 10 row-groups x 96 words
        if (w >= b + 1) {
          uint64_t v = 0ull;
          for (int q = lo + g; q < hi; q += 10)
            v |= Sup[(size_t)keep[q] * SUP_W + w];
          if (v) {
            if ((uint32_t)v)         atomicOr(&ext_arr[w][0], (uint32_t)v);
            if ((uint32_t)(v >> 32)) atomicOr(&ext_arr[w][1], (uint32_t)(v >> 32));
          }
        }
      }
    }
    __syncthreads();
    if (s_done) break;                     // uniform: LDS value after barrier
  }
  __syncthreads();
  int KF = s_kcnt;
  for (int r = t; r < POST_NMS; r += 1024) {
    float* o = out + r * 6;
    if (r < KF) {
      int p = keep[r];
      o[0] = 0.f;
      o[1] = (float)sbx[p * 4 + 0];
      o[2] = (float)sbx[p * 4 + 1];
      o[3] = (float)sbx[p * 4 + 2];
      o[4] = (float)sbx[p * 4 + 3];
      o[5] = (float)ss[p];
    } else {
#pragma unroll
      for (int c = 0; c < 6; ++c) o[c] = 0.f;
    }
  }
}

// ---------------- host launch ----------------
extern "C" void kernel_launch(void* const* d_in, const int* in_sizes, int n_in,
                              void* d_out, int out_size, void* d_ws, size_t ws_size,
                              hipStream_t stream) {
  const float* p0 = (const float*)d_in[0];
  const float* p1 = (const float*)d_in[1];
  const float* p2 = (const float*)d_in[2];
  const float* p3 = (const float*)d_in[3];
  const float* p4 = (const float*)d_in[4];
  const float* im_info = (const float*)d_in[5];
  const float* cw = (const float*)d_in[6];
  const float* cb = (const float*)d_in[7];
  const float* sw = (const float*)d_in[8];
  const float* sb = (const float*)d_in[9];
  const float* bw = (const float*)d_in[10];
  const float* bb = (const float*)d_in[11];
  char* ws = (char*)d_ws;
  // ws layout (bytes):
  uint32_t* hist    = (uint32_t*)(ws + 0);         // 65536 u32 -> 262144
  uint32_t* cnts    = (uint32_t*)(ws + 262144);    // [0]=pool [1]=edge -> 262208
  double*   fb      = (double*)  (ws + 262208);    // 16 f64 -> 262336
  float*    fb32    = (float*)   (ws + 262336);    // 4 f32  -> 262352
  double*   logits  = (double*)  (ws + 262352);    // 106392 f64 -> 1113488
  double*   deltas  = (double*)  (ws + 1113488);   // 425568 f64 -> 4518032
  float*    logits32= (float*)   (ws + 4518032);   // 106392 f32 -> 4943600
  float4*   w3      = (float4*)  (ws + 4943600);   // 2304 float4 -> 4980464
  double*   Weff    = (double*)  (ws + 4980464);   // 2304*16 f64 -> 5275376
  double*   Wpart   = (double*)  (ws + 5275376);   // 16*2304*16 f64 -> 9993968
  uint32_t* alist   = (uint32_t*)(ws + 9993968);   // 8192 u32 -> 10026736
  double*   ssort   = (double*)  (ws + 10026736);  // 6016 f64 -> 10074864
  double*   sbx     = (double*)  (ws + 10074864);  // 6016*4 f64 -> 10267376
  float4*   bxf     = (float4*)  (ws + 10267376);  // 6016 float4 -> 10363632
  float*    areaf   = (float*)   (ws + 10363632);  // 6016 f32 -> 10387696
  uint64_t* Sup     = (uint64_t*)(ws + 10387696);  // 6016*96 u64 -> 15007984
  uint64_t* pkey    = (uint64_t*)(ws + 15007984);  // 8192 u64 -> 15073520
  uint32_t* rank32  = (uint32_t*)(ws + 15073520);  // 8192 u32 -> 15106288
  uint32_t* bcnt    = hist;                        // reuse: hist dead after k_edge
  double*   W5      = Wpart;                       // reuse: Wpart dead after k_weff_fin
  double*   ppart   = (double*)(ws + 5275376 + 524288);   // in Wpart, past W5
  float*    qpart   = (float*) (ws + 5275376 + 2097152);  // in Wpart, past ppart
  float* out = (float*)d_out;

  hipMemsetAsync(ws, 0, 262208, stream);             // hist + counters
  hipMemsetAsync(rank32, 0, 32768, stream);          // rank accumulators
  k_weff_part<<<144, 256, 0, stream>>>(cw, sw, bw, Wpart);
  k_weff_fin<<<10, 256, 0, stream>>>(Wpart, cb, sb, bb, sw, bw, Weff, fb, w3, fb32);
  k_w5<<<27, 256, 0, stream>>>(Weff, W5);
  k_fast<<<1110, 256, 0, stream>>>(p0, p1, p2, p3, p4, w3, qpart);
  k_fcomb<<<139, 256, 0, stream>>>(qpart, fb32, logits32, hist);
  k_edge<<<1, 1024, 0, stream>>>(hist, cnts);
  k_cnt<<<416, 256, 0, stream>>>(logits32, cnts, bcnt);
  k_fill<<<416, 256, 0, stream>>>(logits32, cnts, bcnt, alist);
  k_refine<<<256, 128, 0, stream>>>(p0, p1, p2, p3, p4, W5, alist, cnts, ppart);
  k_comb<<<32, 256, 0, stream>>>(alist, cnts, ppart, fb, logits, deltas, pkey);
  k_rank_cnt<<<512, 256, 0, stream>>>(cnts, pkey, rank32);
  k_scatter<<<32, 256, 0, stream>>>(cnts, pkey, rank32, logits, deltas, im_info,
                                    ssort, sbx, bxf, areaf);
  k_build<<<94 * 24, 256, 0, stream>>>(sbx, bxf, areaf, Sup);
  k_scan<<<1, 1024, 0, stream>>>(Sup, ssort, sbx, out);
}

// Round 12
// 404.975 us; speedup vs baseline: 1.0340x; 1.0124x over previous
//
#include <hip/hip_runtime.h>
#include <stdint.h>

#define N_ANCH   106392
#define PRE_NMS  6000
#define POST_NMS 1000
#define POOL_CAP 8192
#define NMS_BLKS 94   // 94*64 = 6016 >= 6000
#define SUP_W    96   // padded words per suppression row

static __device__ const int    LV_H[5]      = {128, 64, 32, 16, 8};
static __device__ const int    LV_W[5]      = {208, 104, 52, 26, 13};
static __device__ const int    LV_STRIDE[5] = {4, 8, 16, 32, 64};
static __device__ const int    LV_PIX[5]    = {26624, 6656, 1664, 416, 104};
static __device__ const int    LV_TILE0[6]  = {0, 416, 520, 546, 553, 555};
static __device__ const int    LV_AOFF[6]  = {0, 79872, 99840, 104832, 106080, 106392};
static __device__ const int    GPOFF[6]     = {0, 26624, 33280, 34944, 35360, 35464};
// Base anchors computed with np.round (half-even) semantics, verified by hand.
static __device__ const double BASE_ANCH[5][3][4] = {
  {{-22.,-10.,25.,13.},   {-14.,-14.,17.,17.},    {-10.,-22.,13.,25.}},
  {{-40.,-20.,47.,27.},   {-28.,-28.,35.,35.},    {-20.,-44.,27.,51.}},
  {{-84.,-40.,99.,55.},   {-56.,-56.,71.,71.},    {-36.,-80.,51.,95.}},
  {{-164.,-72.,195.,103.},{-112.,-112.,143.,143.},{-76.,-168.,107.,199.}},
  {{-332.,-152.,395.,215.},{-224.,-224.,287.,287.},{-148.,-328.,211.,391.}}
};

// sortable mappings (monotone): bigger value -> bigger key
__device__ __forceinline__ uint32_t sort32f(float f) {
  uint32_t u = __float_as_uint(f);
  return ((int)u < 0) ? ~u : (u | 0x80000000u);
}
__device__ __forceinline__ uint64_t sort64(double d) {
  uint64_t u = (uint64_t)__double_as_longlong(d);
  return ((long long)u < 0) ? ~u : (u | 0x8000000000000000ull);
}

// ---------------- f64 effective weights, 2-stage ----------------
// comb inline: j<3 -> sw[3+j][c]-sw[j][c]; 3<=j<15 -> bw[j-3][c]
__device__ __forceinline__ double combf(const float* sw, const float* bw, int c, int j) {
  if (j < 3) return (double)sw[(3 + j) * 512 + c] - (double)sw[j * 512 + c];
  return (double)bw[(j - 3) * 512 + c];
}

// Also zeroes hist+cnts (65552 u32) and rank32 (8192 u32) -- replaces the two
// hipMemsetAsync dispatches (same position in the dependency order: first
// kernel of the pipeline; consumers run in strictly later kernels).
__global__ __launch_bounds__(256) void k_weff_part(const float* __restrict__ cw,
                                                   const float* __restrict__ sw,
                                                   const float* __restrict__ bw,
                                                   double* __restrict__ Wpart,
                                                   uint32_t* __restrict__ zb1,
                                                   uint32_t* __restrict__ zb2) {
  {
    int gz = blockIdx.x * 256 + threadIdx.x;      // 36864 threads
    for (int z = gz; z < 65552; z += 36864) zb1[z] = 0u;
    if (gz < 8192) zb2[gz] = 0u;
  }
  int chunk = blockIdx.x / 9;            // 16 chunks of 32 channels
  int tb = blockIdx.x % 9;               // 9 t-blocks of 256
  int t = tb * 256 + threadIdx.x;        // 0..2303
  int c0 = chunk * 32;
  double acc[15];
#pragma unroll
  for (int j = 0; j < 15; ++j) acc[j] = 0.0;
#pragma unroll 1
  for (int c = c0; c < c0 + 32; ++c) {
    double v = (double)cw[c * 2304 + t];
#pragma unroll
    for (int j = 0; j < 15; ++j) acc[j] += v * combf(sw, bw, c, j);
  }
  double* o = Wpart + (((size_t)chunk * 2304 + t) << 4);
#pragma unroll
  for (int j = 0; j < 15; ++j) o[j] = acc[j];
  o[15] = 0.0;
}

// blocks 0..8: sum partials over chunks -> emit W5 records (k_refine layout)
// directly + f32 screen weights w3. Block 9: fb f64 + fb32. W5 values are
// bit-identical to the old Weff->k_w5 copy path (same acc values). W5 lives
// in the (currently dead) deltas region: k_refine reads it before k_comb
// overwrites deltas, and k_scatter reads only pool-gi deltas (all fresh).
__global__ __launch_bounds__(256) void k_weff_fin(const double* __restrict__ Wpart,
                                                  const float* __restrict__ cb,
                                                  const float* __restrict__ sb,
                                                  const float* __restrict__ bb,
                                                  const float* __restrict__ sw,
                                                  const float* __restrict__ bw,
                                                  double* __restrict__ w5,
                                                  double* __restrict__ fb,
                                                  float4* __restrict__ w3,
                                                  float* __restrict__ fb32) {
  if (blockIdx.x == 9) {
    __shared__ double ps[15][16];
    int tid = threadIdx.x;
    if (tid < 240) {
      int j = tid >> 4, part = tid & 15;
      double s = 0.0;
      for (int c = part * 32; c < part * 32 + 32; ++c)
        s += (double)cb[c] * combf(sw, bw, c, j);
      ps[j][part] = s;
    }
    __syncthreads();
    if (tid < 15) {
      double s = 0.0;
#pragma unroll
      for (int part = 0; part < 16; ++part) s += ps[tid][part];  // fixed order
      s += (tid < 3) ? ((double)sb[3 + tid] - (double)sb[tid]) : (double)bb[tid - 3];
      fb[tid] = s;
      if (tid < 3) fb32[tid] = (float)s;
    }
    if (tid == 15) fb32[3] = 0.f;
    return;
  }
  int t = blockIdx.x * 256 + threadIdx.x;
  double acc[15];
#pragma unroll
  for (int j = 0; j < 15; ++j) acc[j] = 0.0;
#pragma unroll 1
  for (int chunk = 0; chunk < 16; ++chunk) {
    const double* p = Wpart + (((size_t)chunk * 2304 + t) << 4);
#pragma unroll
    for (int j = 0; j < 15; ++j) acc[j] += p[j];
  }
  int ci = t / 9, t9 = t - ci * 9;
  double* base = w5 + (size_t)ci * 192 + (size_t)t9 * 18;   // 3 records x 6
#pragma unroll
  for (int a = 0; a < 3; ++a) {
    double* dst = base + a * 6;
    int jd = 3 + 4 * a;
    dst[0] = acc[jd + 0];
    dst[1] = acc[jd + 1];
    dst[2] = acc[jd + 2];
    dst[3] = acc[jd + 3];
    dst[4] = acc[a];
    dst[5] = 0.0;
  }
  float4 wf;
  wf.x = (float)acc[0]; wf.y = (float)acc[1]; wf.z = (float)acc[2]; wf.w = 0.f;
  w3[t] = wf;
}

// ---------------- f32 screening pass ----------------
__device__ __forceinline__ void load9(float v[9], const float* __restrict__ ib,
                                      const bool rok[3], const bool cok[3],
                                      const int roff[3]) {
#pragma unroll
  for (int ky = 0; ky < 3; ++ky)
#pragma unroll
    for (int kx = 0; kx < 3; ++kx)
      v[ky * 3 + kx] = (rok[ky] && cok[kx]) ? ib[roff[ky] + kx] : 0.0f;
}

// TLP-doubled screen (R9): grid 1110 = 2 channel-halves per pixel tile, each
// wave owns a 32-channel serial chain. Partials q=(r0+r1)+(r2+r3) -> qpart;
// k_fcomb adds halves + fb32. f64 path untouched; logits32 tree perturbation
// ~1e-4 relative is absorbed by the screen's 2-bin margin.
__global__ __launch_bounds__(256) void k_fast(
    const float* __restrict__ p0, const float* __restrict__ p1,
    const float* __restrict__ p2, const float* __restrict__ p3,
    const float* __restrict__ p4,
    const float4* __restrict__ w3, float* __restrict__ qpart) {
  __shared__ float4 w3s[1152];       // 18.4 KB: this block's 128 channels
  __shared__ float red[4][64][3];
  int tid = threadIdx.x, wv = tid >> 6, ln = tid & 63;
  int t = blockIdx.x >> 1, hf = blockIdx.x & 1;
  int cbase = hf * 128;
  for (int i = tid; i < 1152; i += 256) w3s[i] = w3[cbase * 9 + i];
  int L = 0;
  while (L < 4 && t >= LV_TILE0[L + 1]) ++L;
  const float* inL = (L == 0) ? p0 : (L == 1) ? p1 : (L == 2) ? p2 : (L == 3) ? p3 : p4;
  int H = LV_H[L], W = LV_W[L], HW = H * W, PIX = LV_PIX[L];
  int pix = (t - LV_TILE0[L]) * 64 + ln;
  if (pix >= PIX) pix = PIX - 1;           // clamp; k_fcomb skips invalid
  int h = pix / W, w = pix % W;
  bool rok[3], cok[3];
  int roff[3];
#pragma unroll
  for (int ky = 0; ky < 3; ++ky) {
    int iy = h + ky - 1;
    rok[ky] = (iy >= 0 && iy < H);
    roff[ky] = iy * W + w - 1;
  }
#pragma unroll
  for (int kx = 0; kx < 3; ++kx) {
    int ix = w + kx - 1;
    cok[kx] = (ix >= 0 && ix < W);
  }
  int lci0 = wv * 32;                      // LDS channel index within half
  const float* ibn = inL + (size_t)(cbase + lci0) * HW;
  float vn[9];
  load9(vn, ibn, rok, cok, roff);          // prefetch first channel
  __syncthreads();
  float a0 = 0.f, a1 = 0.f, a2 = 0.f;
#pragma unroll 1
  for (int c = 0; c < 32; ++c) {
    float vc[9];
#pragma unroll
    for (int q = 0; q < 9; ++q) vc[q] = vn[q];
    if (c < 31) {                          // uniform; prefetch next channel
      ibn += HW;
      load9(vn, ibn, rok, cok, roff);
    }
    const float4* wr = w3s + (lci0 + c) * 9;
#pragma unroll
    for (int t9 = 0; t9 < 9; ++t9) {
      float4 wt = wr[t9];                  // broadcast ds_read_b128
      float vv = vc[t9];
      a0 += vv * wt.x; a1 += vv * wt.y; a2 += vv * wt.z;
    }
  }
  red[wv][ln][0] = a0; red[wv][ln][1] = a1; red[wv][ln][2] = a2;
  __syncthreads();
  if (wv == 0) {
    float* o = qpart + ((size_t)(t * 2 + hf) * 64 + ln) * 3;
#pragma unroll
    for (int a = 0; a < 3; ++a)
      o[a] = (red[0][ln][a] + red[1][ln][a]) + (red[2][ln][a] + red[3][ln][a]);
  }
}

// combine channel-halves: f = (q0+q1)+fb32 -> logits32 + histogram
__global__ __launch_bounds__(256) void k_fcomb(
    const float* __restrict__ qpart, const float* __restrict__ fb32,
    float* __restrict__ logits32, uint32_t* __restrict__ hist) {
  int tid = threadIdx.x, ln = tid & 63;
  int t = blockIdx.x * 4 + (tid >> 6);
  if (t >= 555) return;
  int L = 0;
  while (L < 4 && t >= LV_TILE0[L + 1]) ++L;
  int PIX = LV_PIX[L];
  int pix = (t - LV_TILE0[L]) * 64 + ln;
  if (pix >= PIX) return;
  const float* q0 = qpart + ((size_t)(t * 2 + 0) * 64 + ln) * 3;
  const float* q1 = qpart + ((size_t)(t * 2 + 1) * 64 + ln) * 3;
  int gbase = LV_AOFF[L] + pix * 3;
#pragma unroll
  for (int a = 0; a < 3; ++a) {
    float f = (q0[a] + q1[a]) + fb32[a];
    logits32[gbase + a] = f;
    atomicAdd(&hist[sort32f(f) >> 16], 1u);
  }
}

// ---------------- edge finder (with 2-bin safety margin) ----------------
__global__ __launch_bounds__(1024) void k_edge(const uint32_t* __restrict__ hist,
                                               uint32_t* __restrict__ cnts) {
  __shared__ uint32_t cs[1024];
  __shared__ uint32_t g_grp, g_suf;
  int t = threadIdx.x, wv = t >> 6, ln = t & 63;
#pragma unroll 4
  for (int r = 0; r < 64; ++r) {
    int g = r * 16 + wv;
    uint32_t x = hist[g * 64 + ln];
#pragma unroll
    for (int off = 32; off > 0; off >>= 1) x += __shfl_down(x, off);
    if (ln == 0) cs[g] = x;
  }
  __syncthreads();
  for (int off = 1; off < 1024; off <<= 1) {
    uint32_t v = cs[t] + ((t + off < 1024) ? cs[t + off] : 0u);
    __syncthreads();
    cs[t] = v;
    __syncthreads();
  }
  uint32_t sufnext = (t < 1023) ? cs[t + 1] : 0u;
  if (cs[t] >= PRE_NMS && sufnext < PRE_NMS) {   // unique t
    g_grp = (uint32_t)t;
    g_suf = sufnext;
  }
  __syncthreads();
  if (t < 64) {   // wave 0: refine edge within the winning 64-bin group
    uint32_t grp = g_grp, suf = g_suf;
    uint32_t x = hist[grp * 64 + t];
    uint32_t S = x;
#pragma unroll
    for (int off = 1; off < 64; off <<= 1) {
      uint32_t y = __shfl_down(S, off);
      if (t + off < 64) S += y;
    }
    unsigned long long mask = __ballot(suf + S >= PRE_NMS);
    int hi = 63 - (int)__clzll(mask);
    if (t == hi) {
      uint32_t e = grp * 64 + (uint32_t)hi;
      cnts[1] = (e > 2) ? e - 2 : 0;     // -2 bin margin: f32 superset of f64 top-k
    }
  }
}

// ---------------- ordered pool compaction (f32 screen) ----------------
__global__ __launch_bounds__(256) void k_cnt(const float* __restrict__ logits32,
                                             const uint32_t* __restrict__ cnts,
                                             uint32_t* __restrict__ bcnt) {
  __shared__ uint32_t wc[4];
  int tid = threadIdx.x;
  int i = blockIdx.x * 256 + tid;
  uint32_t edge = cnts[1];
  bool pass = (i < N_ANCH) && ((sort32f(logits32[i]) >> 16) >= edge);
  unsigned long long m = __ballot(pass);
  if ((tid & 63) == 0) wc[tid >> 6] = (uint32_t)__popcll(m);
  __syncthreads();
  if (tid == 0) bcnt[blockIdx.x] = wc[0] + wc[1] + wc[2] + wc[3];
}

__global__ __launch_bounds__(256) void k_fill(const float* __restrict__ logits32,
                                              uint32_t* __restrict__ cnts,
                                              const uint32_t* __restrict__ bcnt,
                                              uint32_t* __restrict__ alist) {
  __shared__ uint32_t red[256];
  __shared__ uint32_t woff[4];
  int tid = threadIdx.x, wv = tid >> 6, ln = tid & 63;
  // exclusive prefix over preceding blocks (416 values, trivial)
  uint32_t s = 0;
  for (int k = tid; k < blockIdx.x; k += 256) s += bcnt[k];
  red[tid] = s;
  __syncthreads();
#pragma unroll
  for (int off = 128; off > 0; off >>= 1) {
    if (tid < off) red[tid] += red[tid + off];
    __syncthreads();
  }
  uint32_t base = red[0];
  int i = blockIdx.x * 256 + tid;
  uint32_t edge = cnts[1];
  bool pass = (i < N_ANCH) && ((sort32f(logits32[i]) >> 16) >= edge);
  unsigned long long m = __ballot(pass);
  if (ln == 0) woff[wv] = (uint32_t)__popcll(m);
  __syncthreads();
  uint32_t off_in_blk = 0;
  for (int k = 0; k < wv; ++k) off_in_blk += woff[k];
  if (pass) {
    uint32_t pos = base + off_in_blk + (uint32_t)__popcll(m & ((1ull << ln) - 1ull));
    if (pos < POOL_CAP) alist[pos] = (uint32_t)i;
  }
  if (blockIdx.x == ((N_ANCH + 255) / 256 - 1) && tid == 0)
    cnts[0] = base + woff[0] + woff[1] + woff[2] + woff[3];   // uncapped total
}

// ---------------- f64 refine: per-chunk partials ----------------
// Chunks 0..3 (64 serial channels each) are freely distributable; only the
// final left-assoc combine is order-fixed. 2 half-blocks per 64-slot group,
// 128 threads each, grid 256. Per-chunk FMA order (ci asc, tap asc) and LDS
// weight staging unchanged from R2.
__global__ __launch_bounds__(128) void k_refine(
    const float* __restrict__ p0, const float* __restrict__ p1,
    const float* __restrict__ p2, const float* __restrict__ p3,
    const float* __restrict__ p4,
    const double* __restrict__ w5,
    const uint32_t* __restrict__ alist, const uint32_t* __restrict__ cnts,
    double* __restrict__ ppart) {
  __shared__ int4 wlds[2][768];            // 12 KB per wave
  int tid = threadIdx.x, wv = tid >> 6, ln = tid & 63;
  int cnt = (int)cnts[0];
  if (cnt > POOL_CAP) cnt = POOL_CAP;
  int grp = blockIdx.x >> 1, half = blockIdx.x & 1;
  int base = grp * 64;
  if (base >= cnt) return;                 // uniform early-exit
  int slot = base + ln;
  if (slot >= cnt) slot = cnt - 1;         // dup tail (benign same-value writes)
  int gi = (int)alist[slot];
  int gpix = gi / 3, a = gi - gpix * 3;
  int L = 0;
  while (L < 4 && gpix >= GPOFF[L + 1]) ++L;
  int pix = gpix - GPOFF[L];
  const float* inL = (L == 0) ? p0 : (L == 1) ? p1 : (L == 2) ? p2 : (L == 3) ? p3 : p4;
  int H = LV_H[L], W = LV_W[L], HW = H * W;
  int h = pix / W, w = pix % W;
  bool rok[3], cok[3];
  int roff[3];
#pragma unroll
  for (int ky = 0; ky < 3; ++ky) {
    int iy = h + ky - 1;
    rok[ky] = (iy >= 0 && iy < H);
    roff[ky] = iy * W + w - 1;
  }
#pragma unroll
  for (int kx = 0; kx < 3; ++kx) {
    int ix = w + kx - 1;
    cok[kx] = (ix >= 0 && ix < W);
  }
  int chunk = half * 2 + wv;               // 0..3: 64-channel serial chunk
  int ci0 = chunk * 64;
  const char* wbc = (const char*)&wlds[wv][0];
  // prologue: stage weight chunk 0 (channels ci0 .. ci0+8)
  {
    const int4* gs = (const int4*)((const char*)w5 + (size_t)ci0 * 1536);
    int4 r[12];
#pragma unroll
    for (int i = 0; i < 12; ++i) r[i] = gs[i * 64 + ln];
#pragma unroll
    for (int i = 0; i < 12; ++i) wlds[wv][i * 64 + ln] = r[i];
  }
  double sc = 0.0, d0 = 0.0, d1 = 0.0, d2 = 0.0, d3 = 0.0;
  const float* ibn = inL + (size_t)ci0 * HW;
  float vn[9];
  load9(vn, ibn, rok, cok, roff);          // feature prefetch for channel 0
#pragma unroll 1
  for (int k = 0; k < 8; ++k) {
    int4 r[12];
    if (k < 7) {                           // issue next chunk's weight loads
      const int4* gs =
          (const int4*)((const char*)w5 + (size_t)(ci0 + (k + 1) * 8) * 1536);
#pragma unroll
      for (int i = 0; i < 12; ++i) r[i] = gs[i * 64 + ln];
    }
#pragma unroll 1
    for (int c2 = 0; c2 < 8; ++c2) {
      float vc[9];
#pragma unroll
      for (int q = 0; q < 9; ++q) vc[q] = vn[q];
      int lc = k * 8 + c2;
      if (lc < 63) {                       // uniform; prefetch next channel
        ibn += HW;
        load9(vn, ibn, rok, cok, roff);
      }
      const char* b2 = wbc + c2 * 1536 + a * 48;
#pragma unroll
      for (int t9 = 0; t9 < 9; ++t9) {
        double vd = (double)vc[t9];
        double2 w01 = *(const double2*)(b2 + t9 * 144);
        double2 w23 = *(const double2*)(b2 + t9 * 144 + 16);
        double  w4  = *(const double*)(b2 + t9 * 144 + 32);
        d0 += vd * w01.x; d1 += vd * w01.y;
        d2 += vd * w23.x; d3 += vd * w23.y;
        sc += vd * w4;
      }
    }
    if (k < 7) {                           // land next chunk in LDS
#pragma unroll
      for (int i = 0; i < 12; ++i) wlds[wv][i * 64 + ln] = r[i];
    }
  }
  double* o = ppart + ((size_t)slot * 4 + chunk) * 5;
  o[0] = sc; o[1] = d0; o[2] = d1; o[3] = d2; o[4] = d3;
}

// ---------------- combine partials: bit-exact ((c0+c1)+c2)+c3 ----------------
// Writes deltas over the (now dead) W5 region -- W5's last reader is k_refine.
__global__ __launch_bounds__(256) void k_comb(
    const uint32_t* __restrict__ alist, const uint32_t* __restrict__ cnts,
    const double* __restrict__ ppart, const double* __restrict__ fb,
    double* __restrict__ logits, double* __restrict__ deltas,
    uint64_t* __restrict__ pkey) {
  int e = blockIdx.x * 256 + threadIdx.x;
  int cnt = (int)cnts[0];
  if (cnt > POOL_CAP) cnt = POOL_CAP;
  if (blockIdx.x * 256 >= cnt) return;     // uniform early-exit
  if (e >= cnt) return;
  int gi = (int)alist[e];
  int a = gi - (gi / 3) * 3;
  const double* p = ppart + (size_t)e * 20;
  double f[5];
#pragma unroll
  for (int j = 0; j < 5; ++j)
    f[j] = ((p[0 + j] + p[5 + j]) + p[10 + j]) + p[15 + j];   // left-assoc
  int js = a, jd = 3 + 4 * a;
  double lg = f[0] + fb[js];
  logits[gi] = lg;
  deltas[gi * 4 + 0] = f[1] + fb[jd + 0];
  deltas[gi * 4 + 1] = f[2] + fb[jd + 1];
  deltas[gi * 4 + 2] = f[3] + fb[jd + 2];
  deltas[gi * 4 + 3] = f[4] + fb[jd + 3];
  // top-47 bits of sortable f64 logit; low 17 bits inverted index ->
  // rank-descending breaks score ties by ascending index (top_k semantics)
  pkey[e] = (sort64(lg) & ~0x1FFFFull) | (uint64_t)(0x1FFFFu - (uint32_t)gi);
}

// ---------------- 2D rank-by-counting: 32 i-tiles x 16 j-chunks ----------------
// rank32[e] += #{j in chunk : pkey[j] > pkey[e]}  (u32 atomics: exact, commutative)
__global__ __launch_bounds__(256) void k_rank_cnt(const uint32_t* __restrict__ cnts,
                                                  const uint64_t* __restrict__ pkey,
                                                  uint32_t* __restrict__ rank32) {
  __shared__ uint64_t lk[512];
  int t = threadIdx.x;
  int cnt = (int)cnts[0];
  if (cnt > POOL_CAP) cnt = POOL_CAP;
  int it = blockIdx.x >> 4, jc = blockIdx.x & 15;
  int e = it * 256 + t;
  int c0 = jc * 512;
  if (it * 256 >= cnt || c0 >= cnt) return;   // uniform early-exit
  int lim = cnt - c0; if (lim > 512) lim = 512;
  for (int i = t; i < 512; i += 256) lk[i] = (i < lim) ? pkey[c0 + i] : 0ull;
  __syncthreads();
  bool active = e < cnt;
  uint64_t mykey = active ? pkey[e] : ~0ull;   // ~0 counts nothing
  int r = 0;
#pragma unroll 8
  for (int j = 0; j < 512; ++j) r += (lk[j] > mykey) ? 1 : 0;
  if (active && r) atomicAdd(&rank32[e], (uint32_t)r);
}

// ---------------- scatter by rank + box decode ----------------
__global__ __launch_bounds__(256) void k_scatter(const uint32_t* __restrict__ cnts,
                                                 const uint64_t* __restrict__ pkey,
                                                 const uint32_t* __restrict__ rank32,
                                                 const double* __restrict__ logits,
                                                 const double* __restrict__ deltas,
                                                 const float* __restrict__ im_info,
                                                 double* __restrict__ ss,
                                                 double* __restrict__ sbx,
                                                 float4* __restrict__ bxf,
                                                 float* __restrict__ areaf) {
  int t = threadIdx.x;
  int cnt = (int)cnts[0];
  if (cnt > POOL_CAP) cnt = POOL_CAP;
  int e = blockIdx.x * 256 + t;
  if (blockIdx.x * 256 >= cnt) return;     // uniform
  if (e >= cnt) return;
  int rank = (int)rank32[e];
  if (rank >= PRE_NMS) return;
  uint64_t mykey = pkey[e];
  int gi = 0x1FFFF - (int)(mykey & 0x1FFFFull);
  int L = 0;
  while (L < 4 && gi >= LV_AOFF[L + 1]) ++L;
  int rel = gi - LV_AOFF[L];
  int pix = rel / 3, a = rel % 3;
  int W = LV_W[L];
  int h = pix / W, w = pix % W;
  double imW1 = (double)im_info[1] - 1.0;
  double imH1 = (double)im_info[0] - 1.0;
  double shx = (double)(w * LV_STRIDE[L]), shy = (double)(h * LV_STRIDE[L]);
  double ax1 = BASE_ANCH[L][a][0] + shx, ay1 = BASE_ANCH[L][a][1] + shy;
  double ax2 = BASE_ANCH[L][a][2] + shx, ay2 = BASE_ANCH[L][a][3] + shy;
  double dx = deltas[gi * 4 + 0], dy = deltas[gi * 4 + 1];
  double dw = deltas[gi * 4 + 2], dh = deltas[gi * 4 + 3];
  double wa = ax2 - ax1 + 1.0, ha = ay2 - ay1 + 1.0;
  double cx = ax1 + 0.5 * wa, cy = ay1 + 0.5 * ha;
  double pcx = dx * wa + cx, pcy = dy * ha + cy;
  double pw = exp(dw) * wa, ph = exp(dh) * ha;
  double x1 = fmin(fmax(pcx - 0.5 * pw, 0.0), imW1);
  double y1 = fmin(fmax(pcy - 0.5 * ph, 0.0), imH1);
  double x2 = fmin(fmax(pcx + 0.5 * pw, 0.0), imW1);
  double y2 = fmin(fmax(pcy + 0.5 * ph, 0.0), imH1);
  ss[rank] = 1.0 / (1.0 + exp(-logits[gi]));
  sbx[rank * 4 + 0] = x1; sbx[rank * 4 + 1] = y1;
  sbx[rank * 4 + 2] = x2; sbx[rank * 4 + 3] = y2;
  float4 bf;
  bf.x = (float)x1; bf.y = (float)y1; bf.z = (float)x2; bf.w = (float)y2;
  bxf[rank] = bf;
  areaf[rank] = (float)((x2 - x1 + 1.0) * (y2 - y1 + 1.0));
}

// ---------------- exact f64 IoU decision (reference semantics) ----------------
__device__ __forceinline__ bool iou_gt(const double* A, const double* B) {
  double areaA = (A[2] - A[0] + 1.0) * (A[3] - A[1] + 1.0);
  double areaB = (B[2] - B[0] + 1.0) * (B[3] - B[1] + 1.0);
  double xx1 = fmax(A[0], B[0]), yy1 = fmax(A[1], B[1]);
  double xx2 = fmin(A[2], B[2]), yy2 = fmin(A[3], B[3]);
  double iw = fmax(0.0, xx2 - xx1 + 1.0), ih = fmax(0.0, yy2 - yy1 + 1.0);
  double inter = iw * ih;
  return inter > 0.7 * (areaA + areaB - inter);
}

// ---------------- suppression matrix build (upper triangle) ----------------
__global__ __launch_bounds__(256) void k_build(const double* __restrict__ sbx,
                                               const float4* __restrict__ bxf,
                                               const float* __restrict__ areaf,
                                               uint64_t* __restrict__ Sup) {
  __shared__ float cbx[256][5];
  __shared__ float rbx[64][5];
  int blk = blockIdx.x;
  int rtile = blk / 24, ctile = blk % 24;   // 94 x 24
  int t = threadIdx.x, q = t >> 6, ln = t & 63;
  int r = rtile * 64 + ln;
  int w = ctile * 4 + q;                    // word 0..95
  {
    int c = ctile * 256 + t;
    float4 b;
    float ar;
    if (c < NMS_BLKS * 64) { b = bxf[c]; ar = areaf[c]; }
    else { b.x = b.y = b.z = b.w = 0.f; ar = 0.f; }
    cbx[t][0] = b.x; cbx[t][1] = b.y; cbx[t][2] = b.z; cbx[t][3] = b.w; cbx[t][4] = ar;
    if (t < 64) {
      int rr = rtile * 64 + t;
      float4 rb = bxf[rr];
      rbx[t][0] = rb.x; rbx[t][1] = rb.y; rbx[t][2] = rb.z; rbx[t][3] = rb.w;
      rbx[t][4] = areaf[rr];
    }
  }
  __syncthreads();
  uint64_t bits = 0ull;
  int j0 = w * 64;
  if (w < NMS_BLKS && j0 + 63 > r) {
    float ax1 = rbx[ln][0], ay1 = rbx[ln][1], ax2 = rbx[ln][2], ay2 = rbx[ln][3];
    float aar = rbx[ln][4];
#pragma unroll 4
    for (int jj = 0; jj < 64; ++jj) {
      int j = j0 + jj;
      if (j <= r) continue;
      int cl = q * 64 + jj;
      float iw = fminf(ax2, cbx[cl][2]) - fmaxf(ax1, cbx[cl][0]) + 1.f;
      float ih = fminf(ay2, cbx[cl][3]) - fmaxf(ay1, cbx[cl][1]) + 1.f;
      float inter = fmaxf(iw, 0.f) * fmaxf(ih, 0.f);
      float d = inter - 0.7f * (aar + cbx[cl][4] - inter);
      bool sup;
      if (d > 4.0f) sup = true;
      else if (d < -4.0f) sup = false;
      else sup = iou_gt(sbx + (size_t)r * 4, sbx + (size_t)j * 4);  // rare
      if (sup) bits |= 1ull << jj;
    }
  }
  Sup[(size_t)r * SUP_W + w] = bits;
}

// ---------------- single-barrier pipelined greedy NMS scan (scalar chain) ----
// R9 version: wave-uniform greedy chain on the scalar unit (s_ff1 ->
// readlane x2 -> s_andn2). Next-block ext fold = two extra readlanes per keep
// off the critical path. Waves 1-15 OR full remaining rows of phase b-1 keeps
// concurrently; one barrier per phase. R10's A/B showed the no-vmcnt-drain
// barrier + deeper fold REGRESSED; readlanes-per-keep on the serial chain is
// the currency -- keep the 4-readlane version.
__global__ __launch_bounds__(1024) void k_scan(const uint64_t* __restrict__ Sup,
                                               const double* __restrict__ ss,
                                               const double* __restrict__ sbx,
                                               float* __restrict__ out) {
  __shared__ uint16_t keep[POST_NMS];
  __shared__ uint32_t ext_arr[SUP_W][2];
  __shared__ int s_kcnt, s_done;
  __shared__ int s_pend[2][2];             // parity-double-buffered pend range
  int t = threadIdx.x, wv = t >> 6, ln = t & 63;
  for (int i = t; i < SUP_W * 2; i += 1024) ext_arr[i >> 1][i & 1] = 0u;
  if (t == 0) { s_kcnt = 0; s_done = 0; }
  if (t < 4) s_pend[t >> 1][t & 1] = 0;
  uint64_t diag = 0ull, nxt = 0ull;
  if (wv == 0) {                           // prefetch block-0 diag pair
    size_t r = (size_t)ln * SUP_W;
    diag = Sup[r + 0];
    nxt  = Sup[r + 1];
  }
  __syncthreads();
  for (int b = 0; b < NMS_BLKS; ++b) {
    if (wv == 0) {
      uint64_t myrow = diag & ~((2ull << ln) - 1ull);
      uint64_t mynxt = nxt;
      if (b + 1 < NMS_BLKS) {              // issue next-phase prefetch early
        size_t r = (size_t)((b + 1) * 64 + ln) * SUP_W;
        diag = Sup[r + (b + 1)];
        nxt  = Sup[r + (b + 2)];           // b+2 <= 95 < SUP_W
      }
      uint64_t ext = ((uint64_t)ext_arr[b][1] << 32) | ext_arr[b][0];
      int base = b * 64;
      if (base + 63 >= PRE_NMS) {
        int v = PRE_NMS - base;            // 48 for the tail block
        ext |= ~((1ull << v) - 1ull);
      }
      int K0 = s_kcnt;
      // scalarize: avail is wave-uniform; hoist to SGPRs so the greedy chain
      // runs on the scalar unit with readlane broadcasts (no ds_bpermute).
      uint64_t avail;
      {
        uint64_t a0 = ~ext;
        uint32_t alo = __builtin_amdgcn_readfirstlane((uint32_t)a0);
        uint32_t ahi = __builtin_amdgcn_readfirstlane((uint32_t)(a0 >> 32));
        avail = ((uint64_t)ahi << 32) | alo;
      }
      uint32_t mr_lo = (uint32_t)myrow, mr_hi = (uint32_t)(myrow >> 32);
      uint32_t mn_lo = (uint32_t)mynxt, mn_hi = (uint32_t)(mynxt >> 32);
      uint64_t kp = 0ull, extn = 0ull;
      int lim = POST_NMS - K0, nk = 0;
      while (avail && nk < lim) {
        int i2 = __ffsll((unsigned long long)avail) - 1;
        uint32_t rlo = (uint32_t)__builtin_amdgcn_readlane((int)mr_lo, i2);
        uint32_t rhi = (uint32_t)__builtin_amdgcn_readlane((int)mr_hi, i2);
        uint32_t qlo = (uint32_t)__builtin_amdgcn_readlane((int)mn_lo, i2);
        uint32_t qhi = (uint32_t)__builtin_amdgcn_readlane((int)mn_hi, i2);
        kp |= 1ull << i2;
        ++nk;
        extn |= ((uint64_t)qhi << 32) | qlo;
        avail &= ~(((uint64_t)rhi << 32) | rlo);
        avail &= ~(1ull << i2);
      }
      if ((kp >> ln) & 1ull) {
        int pos = K0 + __popcll(kp & ((1ull << ln) - 1ull));
        keep[pos] = (uint16_t)(base + ln);
      }
      if (ln == 0) {
        if ((uint32_t)extn)         atomicOr(&ext_arr[b + 1][0], (uint32_t)extn);
        if ((uint32_t)(extn >> 32)) atomicOr(&ext_arr[b + 1][1],
                                             (uint32_t)(extn >> 32));
        s_kcnt = K0 + nk;
        s_pend[(b + 1) & 1][0] = K0;       // pend range for next phase's ORers
        s_pend[(b + 1) & 1][1] = K0 + nk;
        if (K0 + nk >= POST_NMS || b + 1 >= NMS_BLKS) s_done = 1;
      }
    } else {
      // waves 1-15: full-row OR of phase b-1's keeps, words >= b+1 only
      // (word b was folded by wave 0 last phase; wave 0 reads word b now).
      int lo = s_pend[b & 1][0], hi = s_pend[b & 1][1];
      if (hi > lo) {
        int tt = t - 64;                   // 0..959
        int g = tt / 96, w = tt - g * 96;  // 10 row-groups x 96 words
        if (w >= b + 1) {
          uint64_t v = 0ull;
          for (int q = lo + g; q < hi; q += 10)
            v |= Sup[(size_t)keep[q] * SUP_W + w];
          if (v) {
            if ((uint32_t)v)         atomicOr(&ext_arr[w][0], (uint32_t)v);
            if ((uint32_t)(v >> 32)) atomicOr(&ext_arr[w][1], (uint32_t)(v >> 32));
          }
        }
      }
    }
    __syncthreads();
    if (s_done) break;                     // uniform: LDS value after barrier
  }
  __syncthreads();
  int KF = s_kcnt;
  for (int r = t; r < POST_NMS; r += 1024) {
    float* o = out + r * 6;
    if (r < KF) {
      int p = keep[r];
      o[0] = 0.f;
      o[1] = (float)sbx[p * 4 + 0];
      o[2] = (float)sbx[p * 4 + 1];
      o[3] = (float)sbx[p * 4 + 2];
      o[4] = (float)sbx[p * 4 + 3];
      o[5] = (float)ss[p];
    } else {
#pragma unroll
      for (int c = 0; c < 6; ++c) o[c] = 0.f;
    }
  }
}

// ---------------- host launch ----------------
extern "C" void kernel_launch(void* const* d_in, const int* in_sizes, int n_in,
                              void* d_out, int out_size, void* d_ws, size_t ws_size,
                              hipStream_t stream) {
  const float* p0 = (const float*)d_in[0];
  const float* p1 = (const float*)d_in[1];
  const float* p2 = (const float*)d_in[2];
  const float* p3 = (const float*)d_in[3];
  const float* p4 = (const float*)d_in[4];
  const float* im_info = (const float*)d_in[5];
  const float* cw = (const float*)d_in[6];
  const float* cb = (const float*)d_in[7];
  const float* sw = (const float*)d_in[8];
  const float* sb = (const float*)d_in[9];
  const float* bw = (const float*)d_in[10];
  const float* bb = (const float*)d_in[11];
  char* ws = (char*)d_ws;
  // ws layout (bytes):
  uint32_t* hist    = (uint32_t*)(ws + 0);         // 65536 u32 -> 262144
  uint32_t* cnts    = (uint32_t*)(ws + 262144);    // [0]=pool [1]=edge -> 262208
  double*   fb      = (double*)  (ws + 262208);    // 16 f64 -> 262336
  float*    fb32    = (float*)   (ws + 262336);    // 4 f32  -> 262352
  double*   logits  = (double*)  (ws + 262352);    // 106392 f64 -> 1113488
  double*   deltas  = (double*)  (ws + 1113488);   // 425568 f64 -> 4518032
  float*    logits32= (float*)   (ws + 4518032);   // 106392 f32 -> 4943600
  float4*   w3      = (float4*)  (ws + 4943600);   // 2304 float4 -> 4980464
  // (ws+4980464 .. 5275376: former Weff region, now unused)
  double*   Wpart   = (double*)  (ws + 5275376);   // 16*2304*16 f64 -> 9993968
  uint32_t* alist   = (uint32_t*)(ws + 9993968);   // 8192 u32 -> 10026736
  double*   ssort   = (double*)  (ws + 10026736);  // 6016 f64 -> 10074864
  double*   sbx     = (double*)  (ws + 10074864);  // 6016*4 f64 -> 10267376
  float4*   bxf     = (float4*)  (ws + 10267376);  // 6016 float4 -> 10363632
  float*    areaf   = (float*)   (ws + 10363632);  // 6016 f32 -> 10387696
  uint64_t* Sup     = (uint64_t*)(ws + 10387696);  // 6016*96 u64 -> 15007984
  uint64_t* pkey    = (uint64_t*)(ws + 15007984);  // 8192 u64 -> 15073520
  uint32_t* rank32  = (uint32_t*)(ws + 15073520);  // 8192 u32 -> 15106288
  uint32_t* bcnt    = hist;                        // reuse: hist dead after k_edge
  // W5 (256ch*192 f64 = 393216 B) lives in the deltas region: written by
  // k_weff_fin, last read by k_refine, then k_comb overwrites with deltas
  // (k_scatter reads only pool-gi deltas, all freshly written). No overlap
  // with Wpart partials (which k_weff_fin reads concurrently).
  double*   W5      = deltas;
  double*   ppart   = (double*)(ws + 5275376 + 524288);   // in Wpart, past head
  float*    qpart   = (float*) (ws + 5275376 + 2097152);  // in Wpart, past ppart
  float* out = (float*)d_out;

  // zeroing of hist+cnts+rank32 is folded into k_weff_part (first dispatch)
  k_weff_part<<<144, 256, 0, stream>>>(cw, sw, bw, Wpart, hist, rank32);
  k_weff_fin<<<10, 256, 0, stream>>>(Wpart, cb, sb, bb, sw, bw, W5, fb, w3, fb32);
  k_fast<<<1110, 256, 0, stream>>>(p0, p1, p2, p3, p4, w3, qpart);
  k_fcomb<<<139, 256, 0, stream>>>(qpart, fb32, logits32, hist);
  k_edge<<<1, 1024, 0, stream>>>(hist, cnts);
  k_cnt<<<416, 256, 0, stream>>>(logits32, cnts, bcnt);
  k_fill<<<416, 256, 0, stream>>>(logits32, cnts, bcnt, alist);
  k_refine<<<256, 128, 0, stream>>>(p0, p1, p2, p3, p4, W5, alist, cnts, ppart);
  k_comb<<<32, 256, 0, stream>>>(alist, cnts, ppart, fb, logits, deltas, pkey);
  k_rank_cnt<<<512, 256, 0, stream>>>(cnts, pkey, rank32);
  k_scatter<<<32, 256, 0, stream>>>(cnts, pkey, rank32, logits, deltas, im_info,
                                    ssort, sbx, bxf, areaf);
  k_build<<<94 * 24, 256, 0, stream>>>(sbx, bxf, areaf, Sup);
  k_scan<<<1, 1024, 0, stream>>>(Sup, ssort, sbx, out);
}

// Round 13
// 402.115 us; speedup vs baseline: 1.0413x; 1.0071x over previous
//
#include <hip/hip_runtime.h>
#include <stdint.h>

#define N_ANCH   106392
#define PRE_NMS  6000
#define POST_NMS 1000
#define POOL_CAP 8192
#define NMS_BLKS 94   // 94*64 = 6016 >= 6000
#define SUP_W    96   // padded words per suppression row

static __device__ const int    LV_H[5]      = {128, 64, 32, 16, 8};
static __device__ const int    LV_W[5]      = {208, 104, 52, 26, 13};
static __device__ const int    LV_STRIDE[5] = {4, 8, 16, 32, 64};
static __device__ const int    LV_PIX[5]    = {26624, 6656, 1664, 416, 104};
static __device__ const int    LV_TILE0[6]  = {0, 416, 520, 546, 553, 555};
static __device__ const int    LV_AOFF[6]  = {0, 79872, 99840, 104832, 106080, 106392};
static __device__ const int    GPOFF[6]     = {0, 26624, 33280, 34944, 35360, 35464};
// Base anchors computed with np.round (half-even) semantics, verified by hand.
static __device__ const double BASE_ANCH[5][3][4] = {
  {{-22.,-10.,25.,13.},   {-14.,-14.,17.,17.},    {-10.,-22.,13.,25.}},
  {{-40.,-20.,47.,27.},   {-28.,-28.,35.,35.},    {-20.,-44.,27.,51.}},
  {{-84.,-40.,99.,55.},   {-56.,-56.,71.,71.},    {-36.,-80.,51.,95.}},
  {{-164.,-72.,195.,103.},{-112.,-112.,143.,143.},{-76.,-168.,107.,199.}},
  {{-332.,-152.,395.,215.},{-224.,-224.,287.,287.},{-148.,-328.,211.,391.}}
};

// sortable mappings (monotone): bigger value -> bigger key
__device__ __forceinline__ uint32_t sort32f(float f) {
  uint32_t u = __float_as_uint(f);
  return ((int)u < 0) ? ~u : (u | 0x80000000u);
}
__device__ __forceinline__ uint64_t sort64(double d) {
  uint64_t u = (uint64_t)__double_as_longlong(d);
  return ((long long)u < 0) ? ~u : (u | 0x8000000000000000ull);
}

// ---------------- f64 effective weights, 2-stage ----------------
// comb inline: j<3 -> sw[3+j][c]-sw[j][c]; 3<=j<15 -> bw[j-3][c]
__device__ __forceinline__ double combf(const float* sw, const float* bw, int c, int j) {
  if (j < 3) return (double)sw[(3 + j) * 512 + c] - (double)sw[j * 512 + c];
  return (double)bw[(j - 3) * 512 + c];
}

// Also zeroes hist+cnts (65552 u32) and rank32 (8192 u32) -- replaces the two
// hipMemsetAsync dispatches (same position in the dependency order: first
// kernel of the pipeline; consumers run in strictly later kernels).
__global__ __launch_bounds__(256) void k_weff_part(const float* __restrict__ cw,
                                                   const float* __restrict__ sw,
                                                   const float* __restrict__ bw,
                                                   double* __restrict__ Wpart,
                                                   uint32_t* __restrict__ zb1,
                                                   uint32_t* __restrict__ zb2) {
  {
    int gz = blockIdx.x * 256 + threadIdx.x;      // 36864 threads
    for (int z = gz; z < 65552; z += 36864) zb1[z] = 0u;
    if (gz < 8192) zb2[gz] = 0u;
  }
  int chunk = blockIdx.x / 9;            // 16 chunks of 32 channels
  int tb = blockIdx.x % 9;               // 9 t-blocks of 256
  int t = tb * 256 + threadIdx.x;        // 0..2303
  int c0 = chunk * 32;
  double acc[15];
#pragma unroll
  for (int j = 0; j < 15; ++j) acc[j] = 0.0;
#pragma unroll 1
  for (int c = c0; c < c0 + 32; ++c) {
    double v = (double)cw[c * 2304 + t];
#pragma unroll
    for (int j = 0; j < 15; ++j) acc[j] += v * combf(sw, bw, c, j);
  }
  double* o = Wpart + (((size_t)chunk * 2304 + t) << 4);
#pragma unroll
  for (int j = 0; j < 15; ++j) o[j] = acc[j];
  o[15] = 0.0;
}

// blocks 0..8: sum partials over chunks -> emit W5 records (k_refine layout)
// directly + f32 screen weights w3. Block 9: fb f64 + fb32. W5 values are
// bit-identical to the old Weff->k_w5 copy path (same acc values). W5 lives
// in the (currently dead) deltas region: k_refine reads it before k_comb
// overwrites deltas, and k_scatter reads only pool-gi deltas (all fresh).
__global__ __launch_bounds__(256) void k_weff_fin(const double* __restrict__ Wpart,
                                                  const float* __restrict__ cb,
                                                  const float* __restrict__ sb,
                                                  const float* __restrict__ bb,
                                                  const float* __restrict__ sw,
                                                  const float* __restrict__ bw,
                                                  double* __restrict__ w5,
                                                  double* __restrict__ fb,
                                                  float4* __restrict__ w3,
                                                  float* __restrict__ fb32) {
  if (blockIdx.x == 9) {
    __shared__ double ps[15][16];
    int tid = threadIdx.x;
    if (tid < 240) {
      int j = tid >> 4, part = tid & 15;
      double s = 0.0;
      for (int c = part * 32; c < part * 32 + 32; ++c)
        s += (double)cb[c] * combf(sw, bw, c, j);
      ps[j][part] = s;
    }
    __syncthreads();
    if (tid < 15) {
      double s = 0.0;
#pragma unroll
      for (int part = 0; part < 16; ++part) s += ps[tid][part];  // fixed order
      s += (tid < 3) ? ((double)sb[3 + tid] - (double)sb[tid]) : (double)bb[tid - 3];
      fb[tid] = s;
      if (tid < 3) fb32[tid] = (float)s;
    }
    if (tid == 15) fb32[3] = 0.f;
    return;
  }
  int t = blockIdx.x * 256 + threadIdx.x;
  double acc[15];
#pragma unroll
  for (int j = 0; j < 15; ++j) acc[j] = 0.0;
#pragma unroll 1
  for (int chunk = 0; chunk < 16; ++chunk) {
    const double* p = Wpart + (((size_t)chunk * 2304 + t) << 4);
#pragma unroll
    for (int j = 0; j < 15; ++j) acc[j] += p[j];
  }
  int ci = t / 9, t9 = t - ci * 9;
  double* base = w5 + (size_t)ci * 192 + (size_t)t9 * 18;   // 3 records x 6
#pragma unroll
  for (int a = 0; a < 3; ++a) {
    double* dst = base + a * 6;
    int jd = 3 + 4 * a;
    dst[0] = acc[jd + 0];
    dst[1] = acc[jd + 1];
    dst[2] = acc[jd + 2];
    dst[3] = acc[jd + 3];
    dst[4] = acc[a];
    dst[5] = 0.0;
  }
  float4 wf;
  wf.x = (float)acc[0]; wf.y = (float)acc[1]; wf.z = (float)acc[2]; wf.w = 0.f;
  w3[t] = wf;
}

// ---------------- f32 screening pass ----------------
__device__ __forceinline__ void load9(float v[9], const float* __restrict__ ib,
                                      const bool rok[3], const bool cok[3],
                                      const int roff[3]) {
#pragma unroll
  for (int ky = 0; ky < 3; ++ky)
#pragma unroll
    for (int kx = 0; kx < 3; ++kx)
      v[ky * 3 + kx] = (rok[ky] && cok[kx]) ? ib[roff[ky] + kx] : 0.0f;
}

// TLP-doubled screen (R9): grid 1110 = 2 channel-halves per pixel tile, each
// wave owns a 32-channel serial chain. Partials q=(r0+r1)+(r2+r3) -> qpart;
// k_fcomb adds halves + fb32. f64 path untouched; logits32 tree perturbation
// ~1e-4 relative is absorbed by the screen's 2-bin margin.
__global__ __launch_bounds__(256) void k_fast(
    const float* __restrict__ p0, const float* __restrict__ p1,
    const float* __restrict__ p2, const float* __restrict__ p3,
    const float* __restrict__ p4,
    const float4* __restrict__ w3, float* __restrict__ qpart) {
  __shared__ float4 w3s[1152];       // 18.4 KB: this block's 128 channels
  __shared__ float red[4][64][3];
  int tid = threadIdx.x, wv = tid >> 6, ln = tid & 63;
  int t = blockIdx.x >> 1, hf = blockIdx.x & 1;
  int cbase = hf * 128;
  for (int i = tid; i < 1152; i += 256) w3s[i] = w3[cbase * 9 + i];
  int L = 0;
  while (L < 4 && t >= LV_TILE0[L + 1]) ++L;
  const float* inL = (L == 0) ? p0 : (L == 1) ? p1 : (L == 2) ? p2 : (L == 3) ? p3 : p4;
  int H = LV_H[L], W = LV_W[L], HW = H * W, PIX = LV_PIX[L];
  int pix = (t - LV_TILE0[L]) * 64 + ln;
  if (pix >= PIX) pix = PIX - 1;           // clamp; k_fcomb skips invalid
  int h = pix / W, w = pix % W;
  bool rok[3], cok[3];
  int roff[3];
#pragma unroll
  for (int ky = 0; ky < 3; ++ky) {
    int iy = h + ky - 1;
    rok[ky] = (iy >= 0 && iy < H);
    roff[ky] = iy * W + w - 1;
  }
#pragma unroll
  for (int kx = 0; kx < 3; ++kx) {
    int ix = w + kx - 1;
    cok[kx] = (ix >= 0 && ix < W);
  }
  int lci0 = wv * 32;                      // LDS channel index within half
  const float* ibn = inL + (size_t)(cbase + lci0) * HW;
  float vn[9];
  load9(vn, ibn, rok, cok, roff);          // prefetch first channel
  __syncthreads();
  float a0 = 0.f, a1 = 0.f, a2 = 0.f;
#pragma unroll 1
  for (int c = 0; c < 32; ++c) {
    float vc[9];
#pragma unroll
    for (int q = 0; q < 9; ++q) vc[q] = vn[q];
    if (c < 31) {                          // uniform; prefetch next channel
      ibn += HW;
      load9(vn, ibn, rok, cok, roff);
    }
    const float4* wr = w3s + (lci0 + c) * 9;
#pragma unroll
    for (int t9 = 0; t9 < 9; ++t9) {
      float4 wt = wr[t9];                  // broadcast ds_read_b128
      float vv = vc[t9];
      a0 += vv * wt.x; a1 += vv * wt.y; a2 += vv * wt.z;
    }
  }
  red[wv][ln][0] = a0; red[wv][ln][1] = a1; red[wv][ln][2] = a2;
  __syncthreads();
  if (wv == 0) {
    float* o = qpart + ((size_t)(t * 2 + hf) * 64 + ln) * 3;
#pragma unroll
    for (int a = 0; a < 3; ++a)
      o[a] = (red[0][ln][a] + red[1][ln][a]) + (red[2][ln][a] + red[3][ln][a]);
  }
}

// combine channel-halves: f = (q0+q1)+fb32 -> logits32 + histogram
__global__ __launch_bounds__(256) void k_fcomb(
    const float* __restrict__ qpart, const float* __restrict__ fb32,
    float* __restrict__ logits32, uint32_t* __restrict__ hist) {
  int tid = threadIdx.x, ln = tid & 63;
  int t = blockIdx.x * 4 + (tid >> 6);
  if (t >= 555) return;
  int L = 0;
  while (L < 4 && t >= LV_TILE0[L + 1]) ++L;
  int PIX = LV_PIX[L];
  int pix = (t - LV_TILE0[L]) * 64 + ln;
  if (pix >= PIX) return;
  const float* q0 = qpart + ((size_t)(t * 2 + 0) * 64 + ln) * 3;
  const float* q1 = qpart + ((size_t)(t * 2 + 1) * 64 + ln) * 3;
  int gbase = LV_AOFF[L] + pix * 3;
#pragma unroll
  for (int a = 0; a < 3; ++a) {
    float f = (q0[a] + q1[a]) + fb32[a];
    logits32[gbase + a] = f;
    atomicAdd(&hist[sort32f(f) >> 16], 1u);
  }
}

// ---------------- edge finder (with 2-bin safety margin) ----------------
__global__ __launch_bounds__(1024) void k_edge(const uint32_t* __restrict__ hist,
                                               uint32_t* __restrict__ cnts) {
  __shared__ uint32_t cs[1024];
  __shared__ uint32_t g_grp, g_suf;
  int t = threadIdx.x, wv = t >> 6, ln = t & 63;
#pragma unroll 4
  for (int r = 0; r < 64; ++r) {
    int g = r * 16 + wv;
    uint32_t x = hist[g * 64 + ln];
#pragma unroll
    for (int off = 32; off > 0; off >>= 1) x += __shfl_down(x, off);
    if (ln == 0) cs[g] = x;
  }
  __syncthreads();
  for (int off = 1; off < 1024; off <<= 1) {
    uint32_t v = cs[t] + ((t + off < 1024) ? cs[t + off] : 0u);
    __syncthreads();
    cs[t] = v;
    __syncthreads();
  }
  uint32_t sufnext = (t < 1023) ? cs[t + 1] : 0u;
  if (cs[t] >= PRE_NMS && sufnext < PRE_NMS) {   // unique t
    g_grp = (uint32_t)t;
    g_suf = sufnext;
  }
  __syncthreads();
  if (t < 64) {   // wave 0: refine edge within the winning 64-bin group
    uint32_t grp = g_grp, suf = g_suf;
    uint32_t x = hist[grp * 64 + t];
    uint32_t S = x;
#pragma unroll
    for (int off = 1; off < 64; off <<= 1) {
      uint32_t y = __shfl_down(S, off);
      if (t + off < 64) S += y;
    }
    unsigned long long mask = __ballot(suf + S >= PRE_NMS);
    int hi = 63 - (int)__clzll(mask);
    if (t == hi) {
      uint32_t e = grp * 64 + (uint32_t)hi;
      cnts[1] = (e > 2) ? e - 2 : 0;     // -2 bin margin: f32 superset of f64 top-k
    }
  }
}

// ---------------- ordered pool compaction (f32 screen) ----------------
__global__ __launch_bounds__(256) void k_cnt(const float* __restrict__ logits32,
                                             const uint32_t* __restrict__ cnts,
                                             uint32_t* __restrict__ bcnt) {
  __shared__ uint32_t wc[4];
  int tid = threadIdx.x;
  int i = blockIdx.x * 256 + tid;
  uint32_t edge = cnts[1];
  bool pass = (i < N_ANCH) && ((sort32f(logits32[i]) >> 16) >= edge);
  unsigned long long m = __ballot(pass);
  if ((tid & 63) == 0) wc[tid >> 6] = (uint32_t)__popcll(m);
  __syncthreads();
  if (tid == 0) bcnt[blockIdx.x] = wc[0] + wc[1] + wc[2] + wc[3];
}

__global__ __launch_bounds__(256) void k_fill(const float* __restrict__ logits32,
                                              uint32_t* __restrict__ cnts,
                                              const uint32_t* __restrict__ bcnt,
                                              uint32_t* __restrict__ alist) {
  __shared__ uint32_t red[256];
  __shared__ uint32_t woff[4];
  int tid = threadIdx.x, wv = tid >> 6, ln = tid & 63;
  // exclusive prefix over preceding blocks (416 values, trivial)
  uint32_t s = 0;
  for (int k = tid; k < blockIdx.x; k += 256) s += bcnt[k];
  red[tid] = s;
  __syncthreads();
#pragma unroll
  for (int off = 128; off > 0; off >>= 1) {
    if (tid < off) red[tid] += red[tid + off];
    __syncthreads();
  }
  uint32_t base = red[0];
  int i = blockIdx.x * 256 + tid;
  uint32_t edge = cnts[1];
  bool pass = (i < N_ANCH) && ((sort32f(logits32[i]) >> 16) >= edge);
  unsigned long long m = __ballot(pass);
  if (ln == 0) woff[wv] = (uint32_t)__popcll(m);
  __syncthreads();
  uint32_t off_in_blk = 0;
  for (int k = 0; k < wv; ++k) off_in_blk += woff[k];
  if (pass) {
    uint32_t pos = base + off_in_blk + (uint32_t)__popcll(m & ((1ull << ln) - 1ull));
    if (pos < POOL_CAP) alist[pos] = (uint32_t)i;
  }
  if (blockIdx.x == ((N_ANCH + 255) / 256 - 1) && tid == 0)
    cnts[0] = base + woff[0] + woff[1] + woff[2] + woff[3];   // uncapped total
}

// ---------------- f64 refine: per-chunk partials ----------------
// Chunks 0..3 (64 serial channels each) are freely distributable; only the
// final left-assoc combine is order-fixed. 2 half-blocks per 64-slot group,
// 128 threads each, grid 256. Per-chunk FMA order (ci asc, tap asc) and LDS
// weight staging unchanged from R2.
__global__ __launch_bounds__(128) void k_refine(
    const float* __restrict__ p0, const float* __restrict__ p1,
    const float* __restrict__ p2, const float* __restrict__ p3,
    const float* __restrict__ p4,
    const double* __restrict__ w5,
    const uint32_t* __restrict__ alist, const uint32_t* __restrict__ cnts,
    double* __restrict__ ppart) {
  __shared__ int4 wlds[2][768];            // 12 KB per wave
  int tid = threadIdx.x, wv = tid >> 6, ln = tid & 63;
  int cnt = (int)cnts[0];
  if (cnt > POOL_CAP) cnt = POOL_CAP;
  int grp = blockIdx.x >> 1, half = blockIdx.x & 1;
  int base = grp * 64;
  if (base >= cnt) return;                 // uniform early-exit
  int slot = base + ln;
  if (slot >= cnt) slot = cnt - 1;         // dup tail (benign same-value writes)
  int gi = (int)alist[slot];
  int gpix = gi / 3, a = gi - gpix * 3;
  int L = 0;
  while (L < 4 && gpix >= GPOFF[L + 1]) ++L;
  int pix = gpix - GPOFF[L];
  const float* inL = (L == 0) ? p0 : (L == 1) ? p1 : (L == 2) ? p2 : (L == 3) ? p3 : p4;
  int H = LV_H[L], W = LV_W[L], HW = H * W;
  int h = pix / W, w = pix % W;
  bool rok[3], cok[3];
  int roff[3];
#pragma unroll
  for (int ky = 0; ky < 3; ++ky) {
    int iy = h + ky - 1;
    rok[ky] = (iy >= 0 && iy < H);
    roff[ky] = iy * W + w - 1;
  }
#pragma unroll
  for (int kx = 0; kx < 3; ++kx) {
    int ix = w + kx - 1;
    cok[kx] = (ix >= 0 && ix < W);
  }
  int chunk = half * 2 + wv;               // 0..3: 64-channel serial chunk
  int ci0 = chunk * 64;
  const char* wbc = (const char*)&wlds[wv][0];
  // prologue: stage weight chunk 0 (channels ci0 .. ci0+8)
  {
    const int4* gs = (const int4*)((const char*)w5 + (size_t)ci0 * 1536);
    int4 r[12];
#pragma unroll
    for (int i = 0; i < 12; ++i) r[i] = gs[i * 64 + ln];
#pragma unroll
    for (int i = 0; i < 12; ++i) wlds[wv][i * 64 + ln] = r[i];
  }
  double sc = 0.0, d0 = 0.0, d1 = 0.0, d2 = 0.0, d3 = 0.0;
  const float* ibn = inL + (size_t)ci0 * HW;
  float vn[9];
  load9(vn, ibn, rok, cok, roff);          // feature prefetch for channel 0
#pragma unroll 1
  for (int k = 0; k < 8; ++k) {
    int4 r[12];
    if (k < 7) {                           // issue next chunk's weight loads
      const int4* gs =
          (const int4*)((const char*)w5 + (size_t)(ci0 + (k + 1) * 8) * 1536);
#pragma unroll
      for (int i = 0; i < 12; ++i) r[i] = gs[i * 64 + ln];
    }
#pragma unroll 1
    for (int c2 = 0; c2 < 8; ++c2) {
      float vc[9];
#pragma unroll
      for (int q = 0; q < 9; ++q) vc[q] = vn[q];
      int lc = k * 8 + c2;
      if (lc < 63) {                       // uniform; prefetch next channel
        ibn += HW;
        load9(vn, ibn, rok, cok, roff);
      }
      const char* b2 = wbc + c2 * 1536 + a * 48;
#pragma unroll
      for (int t9 = 0; t9 < 9; ++t9) {
        double vd = (double)vc[t9];
        double2 w01 = *(const double2*)(b2 + t9 * 144);
        double2 w23 = *(const double2*)(b2 + t9 * 144 + 16);
        double  w4  = *(const double*)(b2 + t9 * 144 + 32);
        d0 += vd * w01.x; d1 += vd * w01.y;
        d2 += vd * w23.x; d3 += vd * w23.y;
        sc += vd * w4;
      }
    }
    if (k < 7) {                           // land next chunk in LDS
#pragma unroll
      for (int i = 0; i < 12; ++i) wlds[wv][i * 64 + ln] = r[i];
    }
  }
  double* o = ppart + ((size_t)slot * 4 + chunk) * 5;
  o[0] = sc; o[1] = d0; o[2] = d1; o[3] = d2; o[4] = d3;
}

// ---------------- combine partials: bit-exact ((c0+c1)+c2)+c3 ----------------
// Writes deltas over the (now dead) W5 region -- W5's last reader is k_refine.
__global__ __launch_bounds__(256) void k_comb(
    const uint32_t* __restrict__ alist, const uint32_t* __restrict__ cnts,
    const double* __restrict__ ppart, const double* __restrict__ fb,
    double* __restrict__ logits, double* __restrict__ deltas,
    uint64_t* __restrict__ pkey) {
  int e = blockIdx.x * 256 + threadIdx.x;
  int cnt = (int)cnts[0];
  if (cnt > POOL_CAP) cnt = POOL_CAP;
  if (blockIdx.x * 256 >= cnt) return;     // uniform early-exit
  if (e >= cnt) return;
  int gi = (int)alist[e];
  int a = gi - (gi / 3) * 3;
  const double* p = ppart + (size_t)e * 20;
  double f[5];
#pragma unroll
  for (int j = 0; j < 5; ++j)
    f[j] = ((p[0 + j] + p[5 + j]) + p[10 + j]) + p[15 + j];   // left-assoc
  int js = a, jd = 3 + 4 * a;
  double lg = f[0] + fb[js];
  logits[gi] = lg;
  deltas[gi * 4 + 0] = f[1] + fb[jd + 0];
  deltas[gi * 4 + 1] = f[2] + fb[jd + 1];
  deltas[gi * 4 + 2] = f[3] + fb[jd + 2];
  deltas[gi * 4 + 3] = f[4] + fb[jd + 3];
  // top-47 bits of sortable f64 logit; low 17 bits inverted index ->
  // rank-descending breaks score ties by ascending index (top_k semantics)
  pkey[e] = (sort64(lg) & ~0x1FFFFull) | (uint64_t)(0x1FFFFu - (uint32_t)gi);
}

// ---------------- 2D rank-by-counting: 32 i-tiles x 16 j-chunks ----------------
// rank32[e] += #{j in chunk : pkey[j] > pkey[e]}  (u32 atomics: exact, commutative)
__global__ __launch_bounds__(256) void k_rank_cnt(const uint32_t* __restrict__ cnts,
                                                  const uint64_t* __restrict__ pkey,
                                                  uint32_t* __restrict__ rank32) {
  __shared__ uint64_t lk[512];
  int t = threadIdx.x;
  int cnt = (int)cnts[0];
  if (cnt > POOL_CAP) cnt = POOL_CAP;
  int it = blockIdx.x >> 4, jc = blockIdx.x & 15;
  int e = it * 256 + t;
  int c0 = jc * 512;
  if (it * 256 >= cnt || c0 >= cnt) return;   // uniform early-exit
  int lim = cnt - c0; if (lim > 512) lim = 512;
  for (int i = t; i < 512; i += 256) lk[i] = (i < lim) ? pkey[c0 + i] : 0ull;
  __syncthreads();
  bool active = e < cnt;
  uint64_t mykey = active ? pkey[e] : ~0ull;   // ~0 counts nothing
  int r = 0;
#pragma unroll 8
  for (int j = 0; j < 512; ++j) r += (lk[j] > mykey) ? 1 : 0;
  if (active && r) atomicAdd(&rank32[e], (uint32_t)r);
}

// ---------------- scatter by rank + box decode ----------------
__global__ __launch_bounds__(256) void k_scatter(const uint32_t* __restrict__ cnts,
                                                 const uint64_t* __restrict__ pkey,
                                                 const uint32_t* __restrict__ rank32,
                                                 const double* __restrict__ logits,
                                                 const double* __restrict__ deltas,
                                                 const float* __restrict__ im_info,
                                                 double* __restrict__ ss,
                                                 double* __restrict__ sbx,
                                                 float4* __restrict__ bxf,
                                                 float* __restrict__ areaf) {
  int t = threadIdx.x;
  int cnt = (int)cnts[0];
  if (cnt > POOL_CAP) cnt = POOL_CAP;
  int e = blockIdx.x * 256 + t;
  if (blockIdx.x * 256 >= cnt) return;     // uniform
  if (e >= cnt) return;
  int rank = (int)rank32[e];
  if (rank >= PRE_NMS) return;
  uint64_t mykey = pkey[e];
  int gi = 0x1FFFF - (int)(mykey & 0x1FFFFull);
  int L = 0;
  while (L < 4 && gi >= LV_AOFF[L + 1]) ++L;
  int rel = gi - LV_AOFF[L];
  int pix = rel / 3, a = rel % 3;
  int W = LV_W[L];
  int h = pix / W, w = pix % W;
  double imW1 = (double)im_info[1] - 1.0;
  double imH1 = (double)im_info[0] - 1.0;
  double shx = (double)(w * LV_STRIDE[L]), shy = (double)(h * LV_STRIDE[L]);
  double ax1 = BASE_ANCH[L][a][0] + shx, ay1 = BASE_ANCH[L][a][1] + shy;
  double ax2 = BASE_ANCH[L][a][2] + shx, ay2 = BASE_ANCH[L][a][3] + shy;
  double dx = deltas[gi * 4 + 0], dy = deltas[gi * 4 + 1];
  double dw = deltas[gi * 4 + 2], dh = deltas[gi * 4 + 3];
  double wa = ax2 - ax1 + 1.0, ha = ay2 - ay1 + 1.0;
  double cx = ax1 + 0.5 * wa, cy = ay1 + 0.5 * ha;
  double pcx = dx * wa + cx, pcy = dy * ha + cy;
  double pw = exp(dw) * wa, ph = exp(dh) * ha;
  double x1 = fmin(fmax(pcx - 0.5 * pw, 0.0), imW1);
  double y1 = fmin(fmax(pcy - 0.5 * ph, 0.0), imH1);
  double x2 = fmin(fmax(pcx + 0.5 * pw, 0.0), imW1);
  double y2 = fmin(fmax(pcy + 0.5 * ph, 0.0), imH1);
  ss[rank] = 1.0 / (1.0 + exp(-logits[gi]));
  sbx[rank * 4 + 0] = x1; sbx[rank * 4 + 1] = y1;
  sbx[rank * 4 + 2] = x2; sbx[rank * 4 + 3] = y2;
  float4 bf;
  bf.x = (float)x1; bf.y = (float)y1; bf.z = (float)x2; bf.w = (float)y2;
  bxf[rank] = bf;
  areaf[rank] = (float)((x2 - x1 + 1.0) * (y2 - y1 + 1.0));
}

// ---------------- exact f64 IoU decision (reference semantics) ----------------
__device__ __forceinline__ bool iou_gt(const double* A, const double* B) {
  double areaA = (A[2] - A[0] + 1.0) * (A[3] - A[1] + 1.0);
  double areaB = (B[2] - B[0] + 1.0) * (B[3] - B[1] + 1.0);
  double xx1 = fmax(A[0], B[0]), yy1 = fmax(A[1], B[1]);
  double xx2 = fmin(A[2], B[2]), yy2 = fmin(A[3], B[3]);
  double iw = fmax(0.0, xx2 - xx1 + 1.0), ih = fmax(0.0, yy2 - yy1 + 1.0);
  double inter = iw * ih;
  return inter > 0.7 * (areaA + areaB - inter);
}

// ---------------- suppression matrix build (upper triangle) ----------------
// R13: blocks whose entire word range lies strictly below the diagonal block
// (ctile*4+3 < rtile) write only never-read Sup words -- k_scan touches
// Sup[r][w] solely at w = r/64 (diag), w = r/64+1 (nxt fold), and w >= b+1
// for keeps from block b-1 = r/64 (ORers), i.e. always w >= r/64. ~48% of
// the 2256 blocks early-exit before staging (block-uniform, pre-barrier).
__global__ __launch_bounds__(256) void k_build(const double* __restrict__ sbx,
                                               const float4* __restrict__ bxf,
                                               const float* __restrict__ areaf,
                                               uint64_t* __restrict__ Sup) {
  __shared__ float cbx[256][5];
  __shared__ float rbx[64][5];
  int blk = blockIdx.x;
  int rtile = blk / 24, ctile = blk % 24;   // 94 x 24
  if (ctile * 4 + 3 < rtile) return;        // uniform: all words unread
  int t = threadIdx.x, q = t >> 6, ln = t & 63;
  int r = rtile * 64 + ln;
  int w = ctile * 4 + q;                    // word 0..95
  {
    int c = ctile * 256 + t;
    float4 b;
    float ar;
    if (c < NMS_BLKS * 64) { b = bxf[c]; ar = areaf[c]; }
    else { b.x = b.y = b.z = b.w = 0.f; ar = 0.f; }
    cbx[t][0] = b.x; cbx[t][1] = b.y; cbx[t][2] = b.z; cbx[t][3] = b.w; cbx[t][4] = ar;
    if (t < 64) {
      int rr = rtile * 64 + t;
      float4 rb = bxf[rr];
      rbx[t][0] = rb.x; rbx[t][1] = rb.y; rbx[t][2] = rb.z; rbx[t][3] = rb.w;
      rbx[t][4] = areaf[rr];
    }
  }
  __syncthreads();
  uint64_t bits = 0ull;
  int j0 = w * 64;
  if (w < NMS_BLKS && j0 + 63 > r) {
    float ax1 = rbx[ln][0], ay1 = rbx[ln][1], ax2 = rbx[ln][2], ay2 = rbx[ln][3];
    float aar = rbx[ln][4];
#pragma unroll 4
    for (int jj = 0; jj < 64; ++jj) {
      int j = j0 + jj;
      if (j <= r) continue;
      int cl = q * 64 + jj;
      float iw = fminf(ax2, cbx[cl][2]) - fmaxf(ax1, cbx[cl][0]) + 1.f;
      float ih = fminf(ay2, cbx[cl][3]) - fmaxf(ay1, cbx[cl][1]) + 1.f;
      float inter = fmaxf(iw, 0.f) * fmaxf(ih, 0.f);
      float d = inter - 0.7f * (aar + cbx[cl][4] - inter);
      bool sup;
      if (d > 4.0f) sup = true;
      else if (d < -4.0f) sup = false;
      else sup = iou_gt(sbx + (size_t)r * 4, sbx + (size_t)j * 4);  // rare
      if (sup) bits |= 1ull << jj;
    }
  }
  Sup[(size_t)r * SUP_W + w] = bits;
}

// ---------------- single-barrier pipelined greedy NMS scan (scalar chain) ----
// R9 version: wave-uniform greedy chain on the scalar unit (s_ff1 ->
// readlane x2 -> s_andn2). Next-block ext fold = two extra readlanes per keep
// off the critical path. Waves 1-15 OR full remaining rows of phase b-1 keeps
// concurrently; one barrier per phase. R10's A/B showed the no-vmcnt-drain
// barrier + deeper fold REGRESSED; readlanes-per-keep on the serial chain is
// the currency -- keep the 4-readlane version.
__global__ __launch_bounds__(1024) void k_scan(const uint64_t* __restrict__ Sup,
                                               const double* __restrict__ ss,
                                               const double* __restrict__ sbx,
                                               float* __restrict__ out) {
  __shared__ uint16_t keep[POST_NMS];
  __shared__ uint32_t ext_arr[SUP_W][2];
  __shared__ int s_kcnt, s_done;
  __shared__ int s_pend[2][2];             // parity-double-buffered pend range
  int t = threadIdx.x, wv = t >> 6, ln = t & 63;
  for (int i = t; i < SUP_W * 2; i += 1024) ext_arr[i >> 1][i & 1] = 0u;
  if (t == 0) { s_kcnt = 0; s_done = 0; }
  if (t < 4) s_pend[t >> 1][t & 1] = 0;
  uint64_t diag = 0ull, nxt = 0ull;
  if (wv == 0) {                           // prefetch block-0 diag pair
    size_t r = (size_t)ln * SUP_W;
    diag = Sup[r + 0];
    nxt  = Sup[r + 1];
  }
  __syncthreads();
  for (int b = 0; b < NMS_BLKS; ++b) {
    if (wv == 0) {
      uint64_t myrow = diag & ~((2ull << ln) - 1ull);
      uint64_t mynxt = nxt;
      if (b + 1 < NMS_BLKS) {              // issue next-phase prefetch early
        size_t r = (size_t)((b + 1) * 64 + ln) * SUP_W;
        diag = Sup[r + (b + 1)];
        nxt  = Sup[r + (b + 2)];           // b+2 <= 95 < SUP_W
      }
      uint64_t ext = ((uint64_t)ext_arr[b][1] << 32) | ext_arr[b][0];
      int base = b * 64;
      if (base + 63 >= PRE_NMS) {
        int v = PRE_NMS - base;            // 48 for the tail block
        ext |= ~((1ull << v) - 1ull);
      }
      int K0 = s_kcnt;
      // scalarize: avail is wave-uniform; hoist to SGPRs so the greedy chain
      // runs on the scalar unit with readlane broadcasts (no ds_bpermute).
      uint64_t avail;
      {
        uint64_t a0 = ~ext;
        uint32_t alo = __builtin_amdgcn_readfirstlane((uint32_t)a0);
        uint32_t ahi = __builtin_amdgcn_readfirstlane((uint32_t)(a0 >> 32));
        avail = ((uint64_t)ahi << 32) | alo;
      }
      uint32_t mr_lo = (uint32_t)myrow, mr_hi = (uint32_t)(myrow >> 32);
      uint32_t mn_lo = (uint32_t)mynxt, mn_hi = (uint32_t)(mynxt >> 32);
      uint64_t kp = 0ull, extn = 0ull;
      int lim = POST_NMS - K0, nk = 0;
      while (avail && nk < lim) {
        int i2 = __ffsll((unsigned long long)avail) - 1;
        uint32_t rlo = (uint32_t)__builtin_amdgcn_readlane((int)mr_lo, i2);
        uint32_t rhi = (uint32_t)__builtin_amdgcn_readlane((int)mr_hi, i2);
        uint32_t qlo = (uint32_t)__builtin_amdgcn_readlane((int)mn_lo, i2);
        uint32_t qhi = (uint32_t)__builtin_amdgcn_readlane((int)mn_hi, i2);
        kp |= 1ull << i2;
        ++nk;
        extn |= ((uint64_t)qhi << 32) | qlo;
        avail &= ~(((uint64_t)rhi << 32) | rlo);
        avail &= ~(1ull << i2);
      }
      if ((kp >> ln) & 1ull) {
        int pos = K0 + __popcll(kp & ((1ull << ln) - 1ull));
        keep[pos] = (uint16_t)(base + ln);
      }
      if (ln == 0) {
        if ((uint32_t)extn)         atomicOr(&ext_arr[b + 1][0], (uint32_t)extn);
        if ((uint32_t)(extn >> 32)) atomicOr(&ext_arr[b + 1][1],
                                             (uint32_t)(extn >> 32));
        s_kcnt = K0 + nk;
        s_pend[(b + 1) & 1][0] = K0;       // pend range for next phase's ORers
        s_pend[(b + 1) & 1][1] = K0 + nk;
        if (K0 + nk >= POST_NMS || b + 1 >= NMS_BLKS) s_done = 1;
      }
    } else {
      // waves 1-15: full-row OR of phase b-1's keeps, words >= b+1 only
      // (word b was folded by wave 0 last phase; wave 0 reads word b now).
      int lo = s_pend[b & 1][0], hi = s_pend[b & 1][1];
      if (hi > lo) {
        int tt = t - 64;                   // 0..959
        int g = tt / 96, w = tt - g * 96;  // 10 row-groups x 96 words
        if (w >= b + 1) {
          uint64_t v = 0ull;
          for (int q = lo + g; q < hi; q += 10)
            v |= Sup[(size_t)keep[q] * SUP_W + w];
          if (v) {
            if ((uint32_t)v)         atomicOr(&ext_arr[w][0], (uint32_t)v);
            if ((uint32_t)(v >> 32)) atomicOr(&ext_arr[w][1], (uint32_t)(v >> 32));
          }
        }
      }
    }
    __syncthreads();
    if (s_done) break;                     // uniform: LDS value after barrier
  }
  __syncthreads();
  int KF = s_kcnt;
  for (int r = t; r < POST_NMS; r += 1024) {
    float* o = out + r * 6;
    if (r < KF) {
      int p = keep[r];
      o[0] = 0.f;
      o[1] = (float)sbx[p * 4 + 0];
      o[2] = (float)sbx[p * 4 + 1];
      o[3] = (float)sbx[p * 4 + 2];
      o[4] = (float)sbx[p * 4 + 3];
      o[5] = (float)ss[p];
    } else {
#pragma unroll
      for (int c = 0; c < 6; ++c) o[c] = 0.f;
    }
  }
}

// ---------------- host launch ----------------
extern "C" void kernel_launch(void* const* d_in, const int* in_sizes, int n_in,
                              void* d_out, int out_size, void* d_ws, size_t ws_size,
                              hipStream_t stream) {
  const float* p0 = (const float*)d_in[0];
  const float* p1 = (const float*)d_in[1];
  const float* p2 = (const float*)d_in[2];
  const float* p3 = (const float*)d_in[3];
  const float* p4 = (const float*)d_in[4];
  const float* im_info = (const float*)d_in[5];
  const float* cw = (const float*)d_in[6];
  const float* cb = (const float*)d_in[7];
  const float* sw = (const float*)d_in[8];
  const float* sb = (const float*)d_in[9];
  const float* bw = (const float*)d_in[10];
  const float* bb = (const float*)d_in[11];
  char* ws = (char*)d_ws;
  // ws layout (bytes):
  uint32_t* hist    = (uint32_t*)(ws + 0);         // 65536 u32 -> 262144
  uint32_t* cnts    = (uint32_t*)(ws + 262144);    // [0]=pool [1]=edge -> 262208
  double*   fb      = (double*)  (ws + 262208);    // 16 f64 -> 262336
  float*    fb32    = (float*)   (ws + 262336);    // 4 f32  -> 262352
  double*   logits  = (double*)  (ws + 262352);    // 106392 f64 -> 1113488
  double*   deltas  = (double*)  (ws + 1113488);   // 425568 f64 -> 4518032
  float*    logits32= (float*)   (ws + 4518032);   // 106392 f32 -> 4943600
  float4*   w3      = (float4*)  (ws + 4943600);   // 2304 float4 -> 4980464
  // (ws+4980464 .. 5275376: former Weff region, now unused)
  double*   Wpart   = (double*)  (ws + 5275376);   // 16*2304*16 f64 -> 9993968
  uint32_t* alist   = (uint32_t*)(ws + 9993968);   // 8192 u32 -> 10026736
  double*   ssort   = (double*)  (ws + 10026736);  // 6016 f64 -> 10074864
  double*   sbx     = (double*)  (ws + 10074864);  // 6016*4 f64 -> 10267376
  float4*   bxf     = (float4*)  (ws + 10267376);  // 6016 float4 -> 10363632
  float*    areaf   = (float*)   (ws + 10363632);  // 6016 f32 -> 10387696
  uint64_t* Sup     = (uint64_t*)(ws + 10387696);  // 6016*96 u64 -> 15007984
  uint64_t* pkey    = (uint64_t*)(ws + 15007984);  // 8192 u64 -> 15073520
  uint32_t* rank32  = (uint32_t*)(ws + 15073520);  // 8192 u32 -> 15106288
  uint32_t* bcnt    = hist;                        // reuse: hist dead after k_edge
  // W5 (256ch*192 f64 = 393216 B) lives in the deltas region: written by
  // k_weff_fin, last read by k_refine, then k_comb overwrites with deltas
  // (k_scatter reads only pool-gi deltas, all freshly written). No overlap
  // with Wpart partials (which k_weff_fin reads concurrently).
  double*   W5      = deltas;
  double*   ppart   = (double*)(ws + 5275376 + 524288);   // in Wpart, past head
  float*    qpart   = (float*) (ws + 5275376 + 2097152);  // in Wpart, past ppart
  float* out = (float*)d_out;

  // zeroing of hist+cnts+rank32 is folded into k_weff_part (first dispatch)
  k_weff_part<<<144, 256, 0, stream>>>(cw, sw, bw, Wpart, hist, rank32);
  k_weff_fin<<<10, 256, 0, stream>>>(Wpart, cb, sb, bb, sw, bw, W5, fb, w3, fb32);
  k_fast<<<1110, 256, 0, stream>>>(p0, p1, p2, p3, p4, w3, qpart);
  k_fcomb<<<139, 256, 0, stream>>>(qpart, fb32, logits32, hist);
  k_edge<<<1, 1024, 0, stream>>>(hist, cnts);
  k_cnt<<<416, 256, 0, stream>>>(logits32, cnts, bcnt);
  k_fill<<<416, 256, 0, stream>>>(logits32, cnts, bcnt, alist);
  k_refine<<<256, 128, 0, stream>>>(p0, p1, p2, p3, p4, W5, alist, cnts, ppart);
  k_comb<<<32, 256, 0, stream>>>(alist, cnts, ppart, fb, logits, deltas, pkey);
  k_rank_cnt<<<512, 256, 0, stream>>>(cnts, pkey, rank32);
  k_scatter<<<32, 256, 0, stream>>>(cnts, pkey, rank32, logits, deltas, im_info,
                                    ssort, sbx, bxf, areaf);
  k_build<<<94 * 24, 256, 0, stream>>>(sbx, bxf, areaf, Sup);
  k_scan<<<1, 1024, 0, stream>>>(Sup, ssort, sbx, out);
}

// Round 14
// 401.210 us; speedup vs baseline: 1.0437x; 1.0023x over previous
//
#include <hip/hip_runtime.h>
#include <stdint.h>

#define N_ANCH   106392
#define PRE_NMS  6000
#define POST_NMS 1000
#define POOL_CAP 8192
#define NMS_BLKS 94   // 94*64 = 6016 >= 6000
#define SUP_W    96   // padded words per suppression row

static __device__ const int    LV_H[5]      = {128, 64, 32, 16, 8};
static __device__ const int    LV_W[5]      = {208, 104, 52, 26, 13};
static __device__ const int    LV_STRIDE[5] = {4, 8, 16, 32, 64};
static __device__ const int    LV_PIX[5]    = {26624, 6656, 1664, 416, 104};
static __device__ const int    LV_TILE0[6]  = {0, 416, 520, 546, 553, 555};
static __device__ const int    LV_AOFF[6]  = {0, 79872, 99840, 104832, 106080, 106392};
static __device__ const int    GPOFF[6]     = {0, 26624, 33280, 34944, 35360, 35464};
// Base anchors computed with np.round (half-even) semantics, verified by hand.
static __device__ const double BASE_ANCH[5][3][4] = {
  {{-22.,-10.,25.,13.},   {-14.,-14.,17.,17.},    {-10.,-22.,13.,25.}},
  {{-40.,-20.,47.,27.},   {-28.,-28.,35.,35.},    {-20.,-44.,27.,51.}},
  {{-84.,-40.,99.,55.},   {-56.,-56.,71.,71.},    {-36.,-80.,51.,95.}},
  {{-164.,-72.,195.,103.},{-112.,-112.,143.,143.},{-76.,-168.,107.,199.}},
  {{-332.,-152.,395.,215.},{-224.,-224.,287.,287.},{-148.,-328.,211.,391.}}
};

// sortable mappings (monotone): bigger value -> bigger key
__device__ __forceinline__ uint32_t sort32f(float f) {
  uint32_t u = __float_as_uint(f);
  return ((int)u < 0) ? ~u : (u | 0x80000000u);
}
__device__ __forceinline__ uint64_t sort64(double d) {
  uint64_t u = (uint64_t)__double_as_longlong(d);
  return ((long long)u < 0) ? ~u : (u | 0x8000000000000000ull);
}

// ---------------- f64 effective weights, 2-stage ----------------
// comb inline: j<3 -> sw[3+j][c]-sw[j][c]; 3<=j<15 -> bw[j-3][c]
__device__ __forceinline__ double combf(const float* sw, const float* bw, int c, int j) {
  if (j < 3) return (double)sw[(3 + j) * 512 + c] - (double)sw[j * 512 + c];
  return (double)bw[(j - 3) * 512 + c];
}

// R14: grid split by j-halves (144 -> 288 blocks; the 15 j-accumulators are
// independent, so this changes NO summation tree) + 1-deep cw prefetch +
// TRANSPOSED Wpart layout [chunk][j][2304] (lane-contiguous writes; the old
// (chunk*2304+t)*16+j layout had 128B lane stride = ~16x transaction
// amplification on 4.4 MB of f64 traffic, both here and in k_weff_fin).
// Also zeroes hist+cnts (65552 u32) and rank32 (8192 u32) -- replaces the
// two hipMemsetAsync dispatches.
__global__ __launch_bounds__(256) void k_weff_part(const float* __restrict__ cw,
                                                   const float* __restrict__ sw,
                                                   const float* __restrict__ bw,
                                                   double* __restrict__ Wpart,
                                                   uint32_t* __restrict__ zb1,
                                                   uint32_t* __restrict__ zb2) {
  {
    int gz = blockIdx.x * 256 + threadIdx.x;      // 73728 threads
    for (int z = gz; z < 65552; z += 73728) zb1[z] = 0u;
    if (gz < 8192) zb2[gz] = 0u;
  }
  int chunk = blockIdx.x / 18;           // 16 chunks of 32 channels
  int rem   = blockIdx.x % 18;
  int jh    = rem / 9;                   // j-half: 0 -> j=0..7, 1 -> j=8..14
  int tb    = rem % 9;                   // 9 t-blocks of 256
  int t = tb * 256 + threadIdx.x;        // 0..2303
  int c0 = chunk * 32;
  if (jh == 0) {
    double acc[8];
#pragma unroll
    for (int j = 0; j < 8; ++j) acc[j] = 0.0;
    double vn = (double)cw[c0 * 2304 + t];
#pragma unroll 1
    for (int c = c0; c < c0 + 32; ++c) {
      double v = vn;
      if (c < c0 + 31) vn = (double)cw[(c + 1) * 2304 + t];
#pragma unroll
      for (int j = 0; j < 8; ++j) acc[j] += v * combf(sw, bw, c, j);
    }
#pragma unroll
    for (int j = 0; j < 8; ++j)
      Wpart[(size_t)(chunk * 15 + j) * 2304 + t] = acc[j];
  } else {
    double acc[7];
#pragma unroll
    for (int j = 0; j < 7; ++j) acc[j] = 0.0;
    double vn = (double)cw[c0 * 2304 + t];
#pragma unroll 1
    for (int c = c0; c < c0 + 32; ++c) {
      double v = vn;
      if (c < c0 + 31) vn = (double)cw[(c + 1) * 2304 + t];
#pragma unroll
      for (int j = 0; j < 7; ++j) acc[j] += v * combf(sw, bw, c, 8 + j);
    }
#pragma unroll
    for (int j = 0; j < 7; ++j)
      Wpart[(size_t)(chunk * 15 + 8 + j) * 2304 + t] = acc[j];
  }
}

// blocks 0..8: sum partials over chunks (transposed, coalesced reads, 1-deep
// chunk prefetch; chunk order 0..15 unchanged -> bit-exact) -> emit W5
// records (k_refine layout) + f32 screen weights w3. Block 9: fb f64 + fb32.
// W5 lives in the (currently dead) deltas region: k_refine reads it before
// k_comb overwrites deltas; k_scatter reads only pool-gi deltas (all fresh).
__global__ __launch_bounds__(256) void k_weff_fin(const double* __restrict__ Wpart,
                                                  const float* __restrict__ cb,
                                                  const float* __restrict__ sb,
                                                  const float* __restrict__ bb,
                                                  const float* __restrict__ sw,
                                                  const float* __restrict__ bw,
                                                  double* __restrict__ w5,
                                                  double* __restrict__ fb,
                                                  float4* __restrict__ w3,
                                                  float* __restrict__ fb32) {
  if (blockIdx.x == 9) {
    __shared__ double ps[15][16];
    int tid = threadIdx.x;
    if (tid < 240) {
      int j = tid >> 4, part = tid & 15;
      double s = 0.0;
      for (int c = part * 32; c < part * 32 + 32; ++c)
        s += (double)cb[c] * combf(sw, bw, c, j);
      ps[j][part] = s;
    }
    __syncthreads();
    if (tid < 15) {
      double s = 0.0;
#pragma unroll
      for (int part = 0; part < 16; ++part) s += ps[tid][part];  // fixed order
      s += (tid < 3) ? ((double)sb[3 + tid] - (double)sb[tid]) : (double)bb[tid - 3];
      fb[tid] = s;
      if (tid < 3) fb32[tid] = (float)s;
    }
    if (tid == 15) fb32[3] = 0.f;
    return;
  }
  int t = blockIdx.x * 256 + threadIdx.x;
  double acc[15], pn[15];
#pragma unroll
  for (int j = 0; j < 15; ++j) acc[j] = 0.0;
#pragma unroll
  for (int j = 0; j < 15; ++j) pn[j] = Wpart[(size_t)j * 2304 + t];  // chunk 0
#pragma unroll 1
  for (int chunk = 0; chunk < 16; ++chunk) {
    double pc[15];
#pragma unroll
    for (int j = 0; j < 15; ++j) pc[j] = pn[j];
    if (chunk < 15) {                    // prefetch next chunk (coalesced)
#pragma unroll
      for (int j = 0; j < 15; ++j)
        pn[j] = Wpart[(size_t)((chunk + 1) * 15 + j) * 2304 + t];
    }
#pragma unroll
    for (int j = 0; j < 15; ++j) acc[j] += pc[j];
  }
  int ci = t / 9, t9 = t - ci * 9;
  double* base = w5 + (size_t)ci * 192 + (size_t)t9 * 18;   // 3 records x 6
#pragma unroll
  for (int a = 0; a < 3; ++a) {
    double* dst = base + a * 6;
    int jd = 3 + 4 * a;
    dst[0] = acc[jd + 0];
    dst[1] = acc[jd + 1];
    dst[2] = acc[jd + 2];
    dst[3] = acc[jd + 3];
    dst[4] = acc[a];
    dst[5] = 0.0;
  }
  float4 wf;
  wf.x = (float)acc[0]; wf.y = (float)acc[1]; wf.z = (float)acc[2]; wf.w = 0.f;
  w3[t] = wf;
}

// ---------------- f32 screening pass ----------------
__device__ __forceinline__ void load9(float v[9], const float* __restrict__ ib,
                                      const bool rok[3], const bool cok[3],
                                      const int roff[3]) {
#pragma unroll
  for (int ky = 0; ky < 3; ++ky)
#pragma unroll
    for (int kx = 0; kx < 3; ++kx)
      v[ky * 3 + kx] = (rok[ky] && cok[kx]) ? ib[roff[ky] + kx] : 0.0f;
}

// TLP-doubled screen (R9): grid 1110 = 2 channel-halves per pixel tile, each
// wave owns a 32-channel serial chain. Partials q=(r0+r1)+(r2+r3) -> qpart;
// k_fcomb adds halves + fb32. f64 path untouched; logits32 tree perturbation
// ~1e-4 relative is absorbed by the screen's 2-bin margin.
__global__ __launch_bounds__(256) void k_fast(
    const float* __restrict__ p0, const float* __restrict__ p1,
    const float* __restrict__ p2, const float* __restrict__ p3,
    const float* __restrict__ p4,
    const float4* __restrict__ w3, float* __restrict__ qpart) {
  __shared__ float4 w3s[1152];       // 18.4 KB: this block's 128 channels
  __shared__ float red[4][64][3];
  int tid = threadIdx.x, wv = tid >> 6, ln = tid & 63;
  int t = blockIdx.x >> 1, hf = blockIdx.x & 1;
  int cbase = hf * 128;
  for (int i = tid; i < 1152; i += 256) w3s[i] = w3[cbase * 9 + i];
  int L = 0;
  while (L < 4 && t >= LV_TILE0[L + 1]) ++L;
  const float* inL = (L == 0) ? p0 : (L == 1) ? p1 : (L == 2) ? p2 : (L == 3) ? p3 : p4;
  int H = LV_H[L], W = LV_W[L], HW = H * W, PIX = LV_PIX[L];
  int pix = (t - LV_TILE0[L]) * 64 + ln;
  if (pix >= PIX) pix = PIX - 1;           // clamp; k_fcomb skips invalid
  int h = pix / W, w = pix % W;
  bool rok[3], cok[3];
  int roff[3];
#pragma unroll
  for (int ky = 0; ky < 3; ++ky) {
    int iy = h + ky - 1;
    rok[ky] = (iy >= 0 && iy < H);
    roff[ky] = iy * W + w - 1;
  }
#pragma unroll
  for (int kx = 0; kx < 3; ++kx) {
    int ix = w + kx - 1;
    cok[kx] = (ix >= 0 && ix < W);
  }
  int lci0 = wv * 32;                      // LDS channel index within half
  const float* ibn = inL + (size_t)(cbase + lci0) * HW;
  float vn[9];
  load9(vn, ibn, rok, cok, roff);          // prefetch first channel
  __syncthreads();
  float a0 = 0.f, a1 = 0.f, a2 = 0.f;
#pragma unroll 1
  for (int c = 0; c < 32; ++c) {
    float vc[9];
#pragma unroll
    for (int q = 0; q < 9; ++q) vc[q] = vn[q];
    if (c < 31) {                          // uniform; prefetch next channel
      ibn += HW;
      load9(vn, ibn, rok, cok, roff);
    }
    const float4* wr = w3s + (lci0 + c) * 9;
#pragma unroll
    for (int t9 = 0; t9 < 9; ++t9) {
      float4 wt = wr[t9];                  // broadcast ds_read_b128
      float vv = vc[t9];
      a0 += vv * wt.x; a1 += vv * wt.y; a2 += vv * wt.z;
    }
  }
  red[wv][ln][0] = a0; red[wv][ln][1] = a1; red[wv][ln][2] = a2;
  __syncthreads();
  if (wv == 0) {
    float* o = qpart + ((size_t)(t * 2 + hf) * 64 + ln) * 3;
#pragma unroll
    for (int a = 0; a < 3; ++a)
      o[a] = (red[0][ln][a] + red[1][ln][a]) + (red[2][ln][a] + red[3][ln][a]);
  }
}

// combine channel-halves: f = (q0+q1)+fb32 -> logits32 + histogram
__global__ __launch_bounds__(256) void k_fcomb(
    const float* __restrict__ qpart, const float* __restrict__ fb32,
    float* __restrict__ logits32, uint32_t* __restrict__ hist) {
  int tid = threadIdx.x, ln = tid & 63;
  int t = blockIdx.x * 4 + (tid >> 6);
  if (t >= 555) return;
  int L = 0;
  while (L < 4 && t >= LV_TILE0[L + 1]) ++L;
  int PIX = LV_PIX[L];
  int pix = (t - LV_TILE0[L]) * 64 + ln;
  if (pix >= PIX) return;
  const float* q0 = qpart + ((size_t)(t * 2 + 0) * 64 + ln) * 3;
  const float* q1 = qpart + ((size_t)(t * 2 + 1) * 64 + ln) * 3;
  int gbase = LV_AOFF[L] + pix * 3;
#pragma unroll
  for (int a = 0; a < 3; ++a) {
    float f = (q0[a] + q1[a]) + fb32[a];
    logits32[gbase + a] = f;
    atomicAdd(&hist[sort32f(f) >> 16], 1u);
  }
}

// ---------------- edge finder (with 2-bin safety margin) ----------------
__global__ __launch_bounds__(1024) void k_edge(const uint32_t* __restrict__ hist,
                                               uint32_t* __restrict__ cnts) {
  __shared__ uint32_t cs[1024];
  __shared__ uint32_t g_grp, g_suf;
  int t = threadIdx.x, wv = t >> 6, ln = t & 63;
#pragma unroll 4
  for (int r = 0; r < 64; ++r) {
    int g = r * 16 + wv;
    uint32_t x = hist[g * 64 + ln];
#pragma unroll
    for (int off = 32; off > 0; off >>= 1) x += __shfl_down(x, off);
    if (ln == 0) cs[g] = x;
  }
  __syncthreads();
  for (int off = 1; off < 1024; off <<= 1) {
    uint32_t v = cs[t] + ((t + off < 1024) ? cs[t + off] : 0u);
    __syncthreads();
    cs[t] = v;
    __syncthreads();
  }
  uint32_t sufnext = (t < 1023) ? cs[t + 1] : 0u;
  if (cs[t] >= PRE_NMS && sufnext < PRE_NMS) {   // unique t
    g_grp = (uint32_t)t;
    g_suf = sufnext;
  }
  __syncthreads();
  if (t < 64) {   // wave 0: refine edge within the winning 64-bin group
    uint32_t grp = g_grp, suf = g_suf;
    uint32_t x = hist[grp * 64 + t];
    uint32_t S = x;
#pragma unroll
    for (int off = 1; off < 64; off <<= 1) {
      uint32_t y = __shfl_down(S, off);
      if (t + off < 64) S += y;
    }
    unsigned long long mask = __ballot(suf + S >= PRE_NMS);
    int hi = 63 - (int)__clzll(mask);
    if (t == hi) {
      uint32_t e = grp * 64 + (uint32_t)hi;
      cnts[1] = (e > 2) ? e - 2 : 0;     // -2 bin margin: f32 superset of f64 top-k
    }
  }
}

// ---------------- ordered pool compaction (f32 screen) ----------------
__global__ __launch_bounds__(256) void k_cnt(const float* __restrict__ logits32,
                                             const uint32_t* __restrict__ cnts,
                                             uint32_t* __restrict__ bcnt) {
  __shared__ uint32_t wc[4];
  int tid = threadIdx.x;
  int i = blockIdx.x * 256 + tid;
  uint32_t edge = cnts[1];
  bool pass = (i < N_ANCH) && ((sort32f(logits32[i]) >> 16) >= edge);
  unsigned long long m = __ballot(pass);
  if ((tid & 63) == 0) wc[tid >> 6] = (uint32_t)__popcll(m);
  __syncthreads();
  if (tid == 0) bcnt[blockIdx.x] = wc[0] + wc[1] + wc[2] + wc[3];
}

__global__ __launch_bounds__(256) void k_fill(const float* __restrict__ logits32,
                                              uint32_t* __restrict__ cnts,
                                              const uint32_t* __restrict__ bcnt,
                                              uint32_t* __restrict__ alist) {
  __shared__ uint32_t red[256];
  __shared__ uint32_t woff[4];
  int tid = threadIdx.x, wv = tid >> 6, ln = tid & 63;
  // exclusive prefix over preceding blocks (416 values, trivial)
  uint32_t s = 0;
  for (int k = tid; k < blockIdx.x; k += 256) s += bcnt[k];
  red[tid] = s;
  __syncthreads();
#pragma unroll
  for (int off = 128; off > 0; off >>= 1) {
    if (tid < off) red[tid] += red[tid + off];
    __syncthreads();
  }
  uint32_t base = red[0];
  int i = blockIdx.x * 256 + tid;
  uint32_t edge = cnts[1];
  bool pass = (i < N_ANCH) && ((sort32f(logits32[i]) >> 16) >= edge);
  unsigned long long m = __ballot(pass);
  if (ln == 0) woff[wv] = (uint32_t)__popcll(m);
  __syncthreads();
  uint32_t off_in_blk = 0;
  for (int k = 0; k < wv; ++k) off_in_blk += woff[k];
  if (pass) {
    uint32_t pos = base + off_in_blk + (uint32_t)__popcll(m & ((1ull << ln) - 1ull));
    if (pos < POOL_CAP) alist[pos] = (uint32_t)i;
  }
  if (blockIdx.x == ((N_ANCH + 255) / 256 - 1) && tid == 0)
    cnts[0] = base + woff[0] + woff[1] + woff[2] + woff[3];   // uncapped total
}

// ---------------- f64 refine: per-chunk partials ----------------
// Chunks 0..3 (64 serial channels each) are freely distributable; only the
// final left-assoc combine is order-fixed. 2 half-blocks per 64-slot group,
// 128 threads each, grid 256. Per-chunk FMA order (ci asc, tap asc) and LDS
// weight staging unchanged from R2.
__global__ __launch_bounds__(128) void k_refine(
    const float* __restrict__ p0, const float* __restrict__ p1,
    const float* __restrict__ p2, const float* __restrict__ p3,
    const float* __restrict__ p4,
    const double* __restrict__ w5,
    const uint32_t* __restrict__ alist, const uint32_t* __restrict__ cnts,
    double* __restrict__ ppart) {
  __shared__ int4 wlds[2][768];            // 12 KB per wave
  int tid = threadIdx.x, wv = tid >> 6, ln = tid & 63;
  int cnt = (int)cnts[0];
  if (cnt > POOL_CAP) cnt = POOL_CAP;
  int grp = blockIdx.x >> 1, half = blockIdx.x & 1;
  int base = grp * 64;
  if (base >= cnt) return;                 // uniform early-exit
  int slot = base + ln;
  if (slot >= cnt) slot = cnt - 1;         // dup tail (benign same-value writes)
  int gi = (int)alist[slot];
  int gpix = gi / 3, a = gi - gpix * 3;
  int L = 0;
  while (L < 4 && gpix >= GPOFF[L + 1]) ++L;
  int pix = gpix - GPOFF[L];
  const float* inL = (L == 0) ? p0 : (L == 1) ? p1 : (L == 2) ? p2 : (L == 3) ? p3 : p4;
  int H = LV_H[L], W = LV_W[L], HW = H * W;
  int h = pix / W, w = pix % W;
  bool rok[3], cok[3];
  int roff[3];
#pragma unroll
  for (int ky = 0; ky < 3; ++ky) {
    int iy = h + ky - 1;
    rok[ky] = (iy >= 0 && iy < H);
    roff[ky] = iy * W + w - 1;
  }
#pragma unroll
  for (int kx = 0; kx < 3; ++kx) {
    int ix = w + kx - 1;
    cok[kx] = (ix >= 0 && ix < W);
  }
  int chunk = half * 2 + wv;               // 0..3: 64-channel serial chunk
  int ci0 = chunk * 64;
  const char* wbc = (const char*)&wlds[wv][0];
  // prologue: stage weight chunk 0 (channels ci0 .. ci0+8)
  {
    const int4* gs = (const int4*)((const char*)w5 + (size_t)ci0 * 1536);
    int4 r[12];
#pragma unroll
    for (int i = 0; i < 12; ++i) r[i] = gs[i * 64 + ln];
#pragma unroll
    for (int i = 0; i < 12; ++i) wlds[wv][i * 64 + ln] = r[i];
  }
  double sc = 0.0, d0 = 0.0, d1 = 0.0, d2 = 0.0, d3 = 0.0;
  const float* ibn = inL + (size_t)ci0 * HW;
  float vn[9];
  load9(vn, ibn, rok, cok, roff);          // feature prefetch for channel 0
#pragma unroll 1
  for (int k = 0; k < 8; ++k) {
    int4 r[12];
    if (k < 7) {                           // issue next chunk's weight loads
      const int4* gs =
          (const int4*)((const char*)w5 + (size_t)(ci0 + (k + 1) * 8) * 1536);
#pragma unroll
      for (int i = 0; i < 12; ++i) r[i] = gs[i * 64 + ln];
    }
#pragma unroll 1
    for (int c2 = 0; c2 < 8; ++c2) {
      float vc[9];
#pragma unroll
      for (int q = 0; q < 9; ++q) vc[q] = vn[q];
      int lc = k * 8 + c2;
      if (lc < 63) {                       // uniform; prefetch next channel
        ibn += HW;
        load9(vn, ibn, rok, cok, roff);
      }
      const char* b2 = wbc + c2 * 1536 + a * 48;
#pragma unroll
      for (int t9 = 0; t9 < 9; ++t9) {
        double vd = (double)vc[t9];
        double2 w01 = *(const double2*)(b2 + t9 * 144);
        double2 w23 = *(const double2*)(b2 + t9 * 144 + 16);
        double  w4  = *(const double*)(b2 + t9 * 144 + 32);
        d0 += vd * w01.x; d1 += vd * w01.y;
        d2 += vd * w23.x; d3 += vd * w23.y;
        sc += vd * w4;
      }
    }
    if (k < 7) {                           // land next chunk in LDS
#pragma unroll
      for (int i = 0; i < 12; ++i) wlds[wv][i * 64 + ln] = r[i];
    }
  }
  double* o = ppart + ((size_t)slot * 4 + chunk) * 5;
  o[0] = sc; o[1] = d0; o[2] = d1; o[3] = d2; o[4] = d3;
}

// ---------------- combine partials: bit-exact ((c0+c1)+c2)+c3 ----------------
// Writes deltas over the (now dead) W5 region -- W5's last reader is k_refine.
__global__ __launch_bounds__(256) void k_comb(
    const uint32_t* __restrict__ alist, const uint32_t* __restrict__ cnts,
    const double* __restrict__ ppart, const double* __restrict__ fb,
    double* __restrict__ logits, double* __restrict__ deltas,
    uint64_t* __restrict__ pkey) {
  int e = blockIdx.x * 256 + threadIdx.x;
  int cnt = (int)cnts[0];
  if (cnt > POOL_CAP) cnt = POOL_CAP;
  if (blockIdx.x * 256 >= cnt) return;     // uniform early-exit
  if (e >= cnt) return;
  int gi = (int)alist[e];
  int a = gi - (gi / 3) * 3;
  const double* p = ppart + (size_t)e * 20;
  double f[5];
#pragma unroll
  for (int j = 0; j < 5; ++j)
    f[j] = ((p[0 + j] + p[5 + j]) + p[10 + j]) + p[15 + j];   // left-assoc
  int js = a, jd = 3 + 4 * a;
  double lg = f[0] + fb[js];
  logits[gi] = lg;
  deltas[gi * 4 + 0] = f[1] + fb[jd + 0];
  deltas[gi * 4 + 1] = f[2] + fb[jd + 1];
  deltas[gi * 4 + 2] = f[3] + fb[jd + 2];
  deltas[gi * 4 + 3] = f[4] + fb[jd + 3];
  // top-47 bits of sortable f64 logit; low 17 bits inverted index ->
  // rank-descending breaks score ties by ascending index (top_k semantics)
  pkey[e] = (sort64(lg) & ~0x1FFFFull) | (uint64_t)(0x1FFFFu - (uint32_t)gi);
}

// ---------------- 2D rank-by-counting: 32 i-tiles x 16 j-chunks ----------------
// rank32[e] += #{j in chunk : pkey[j] > pkey[e]}  (u32 atomics: exact, commutative)
__global__ __launch_bounds__(256) void k_rank_cnt(const uint32_t* __restrict__ cnts,
                                                  const uint64_t* __restrict__ pkey,
                                                  uint32_t* __restrict__ rank32) {
  __shared__ uint64_t lk[512];
  int t = threadIdx.x;
  int cnt = (int)cnts[0];
  if (cnt > POOL_CAP) cnt = POOL_CAP;
  int it = blockIdx.x >> 4, jc = blockIdx.x & 15;
  int e = it * 256 + t;
  int c0 = jc * 512;
  if (it * 256 >= cnt || c0 >= cnt) return;   // uniform early-exit
  int lim = cnt - c0; if (lim > 512) lim = 512;
  for (int i = t; i < 512; i += 256) lk[i] = (i < lim) ? pkey[c0 + i] : 0ull;
  __syncthreads();
  bool active = e < cnt;
  uint64_t mykey = active ? pkey[e] : ~0ull;   // ~0 counts nothing
  int r = 0;
#pragma unroll 8
  for (int j = 0; j < 512; ++j) r += (lk[j] > mykey) ? 1 : 0;
  if (active && r) atomicAdd(&rank32[e], (uint32_t)r);
}

// ---------------- scatter by rank + box decode ----------------
__global__ __launch_bounds__(256) void k_scatter(const uint32_t* __restrict__ cnts,
                                                 const uint64_t* __restrict__ pkey,
                                                 const uint32_t* __restrict__ rank32,
                                                 const double* __restrict__ logits,
                                                 const double* __restrict__ deltas,
                                                 const float* __restrict__ im_info,
                                                 double* __restrict__ ss,
                                                 double* __restrict__ sbx,
                                                 float4* __restrict__ bxf,
                                                 float* __restrict__ areaf) {
  int t = threadIdx.x;
  int cnt = (int)cnts[0];
  if (cnt > POOL_CAP) cnt = POOL_CAP;
  int e = blockIdx.x * 256 + t;
  if (blockIdx.x * 256 >= cnt) return;     // uniform
  if (e >= cnt) return;
  int rank = (int)rank32[e];
  if (rank >= PRE_NMS) return;
  uint64_t mykey = pkey[e];
  int gi = 0x1FFFF - (int)(mykey & 0x1FFFFull);
  int L = 0;
  while (L < 4 && gi >= LV_AOFF[L + 1]) ++L;
  int rel = gi - LV_AOFF[L];
  int pix = rel / 3, a = rel % 3;
  int W = LV_W[L];
  int h = pix / W, w = pix % W;
  double imW1 = (double)im_info[1] - 1.0;
  double imH1 = (double)im_info[0] - 1.0;
  double shx = (double)(w * LV_STRIDE[L]), shy = (double)(h * LV_STRIDE[L]);
  double ax1 = BASE_ANCH[L][a][0] + shx, ay1 = BASE_ANCH[L][a][1] + shy;
  double ax2 = BASE_ANCH[L][a][2] + shx, ay2 = BASE_ANCH[L][a][3] + shy;
  double dx = deltas[gi * 4 + 0], dy = deltas[gi * 4 + 1];
  double dw = deltas[gi * 4 + 2], dh = deltas[gi * 4 + 3];
  double wa = ax2 - ax1 + 1.0, ha = ay2 - ay1 + 1.0;
  double cx = ax1 + 0.5 * wa, cy = ay1 + 0.5 * ha;
  double pcx = dx * wa + cx, pcy = dy * ha + cy;
  double pw = exp(dw) * wa, ph = exp(dh) * ha;
  double x1 = fmin(fmax(pcx - 0.5 * pw, 0.0), imW1);
  double y1 = fmin(fmax(pcy - 0.5 * ph, 0.0), imH1);
  double x2 = fmin(fmax(pcx + 0.5 * pw, 0.0), imW1);
  double y2 = fmin(fmax(pcy + 0.5 * ph, 0.0), imH1);
  ss[rank] = 1.0 / (1.0 + exp(-logits[gi]));
  sbx[rank * 4 + 0] = x1; sbx[rank * 4 + 1] = y1;
  sbx[rank * 4 + 2] = x2; sbx[rank * 4 + 3] = y2;
  float4 bf;
  bf.x = (float)x1; bf.y = (float)y1; bf.z = (float)x2; bf.w = (float)y2;
  bxf[rank] = bf;
  areaf[rank] = (float)((x2 - x1 + 1.0) * (y2 - y1 + 1.0));
}

// ---------------- exact f64 IoU decision (reference semantics) ----------------
__device__ __forceinline__ bool iou_gt(const double* A, const double* B) {
  double areaA = (A[2] - A[0] + 1.0) * (A[3] - A[1] + 1.0);
  double areaB = (B[2] - B[0] + 1.0) * (B[3] - B[1] + 1.0);
  double xx1 = fmax(A[0], B[0]), yy1 = fmax(A[1], B[1]);
  double xx2 = fmin(A[2], B[2]), yy2 = fmin(A[3], B[3]);
  double iw = fmax(0.0, xx2 - xx1 + 1.0), ih = fmax(0.0, yy2 - yy1 + 1.0);
  double inter = iw * ih;
  return inter > 0.7 * (areaA + areaB - inter);
}

// ---------------- suppression matrix build (upper triangle) ----------------
// Blocks whose entire word range lies strictly below the diagonal block
// (ctile*4+3 < rtile) write only never-read Sup words -- k_scan touches
// Sup[r][w] solely at w >= r/64. ~48% of blocks early-exit (block-uniform).
__global__ __launch_bounds__(256) void k_build(const double* __restrict__ sbx,
                                               const float4* __restrict__ bxf,
                                               const float* __restrict__ areaf,
                                               uint64_t* __restrict__ Sup) {
  __shared__ float cbx[256][5];
  __shared__ float rbx[64][5];
  int blk = blockIdx.x;
  int rtile = blk / 24, ctile = blk % 24;   // 94 x 24
  if (ctile * 4 + 3 < rtile) return;        // uniform: all words unread
  int t = threadIdx.x, q = t >> 6, ln = t & 63;
  int r = rtile * 64 + ln;
  int w = ctile * 4 + q;                    // word 0..95
  {
    int c = ctile * 256 + t;
    float4 b;
    float ar;
    if (c < NMS_BLKS * 64) { b = bxf[c]; ar = areaf[c]; }
    else { b.x = b.y = b.z = b.w = 0.f; ar = 0.f; }
    cbx[t][0] = b.x; cbx[t][1] = b.y; cbx[t][2] = b.z; cbx[t][3] = b.w; cbx[t][4] = ar;
    if (t < 64) {
      int rr = rtile * 64 + t;
      float4 rb = bxf[rr];
      rbx[t][0] = rb.x; rbx[t][1] = rb.y; rbx[t][2] = rb.z; rbx[t][3] = rb.w;
      rbx[t][4] = areaf[rr];
    }
  }
  __syncthreads();
  uint64_t bits = 0ull;
  int j0 = w * 64;
  if (w < NMS_BLKS && j0 + 63 > r) {
    float ax1 = rbx[ln][0], ay1 = rbx[ln][1], ax2 = rbx[ln][2], ay2 = rbx[ln][3];
    float aar = rbx[ln][4];
#pragma unroll 4
    for (int jj = 0; jj < 64; ++jj) {
      int j = j0 + jj;
      if (j <= r) continue;
      int cl = q * 64 + jj;
      float iw = fminf(ax2, cbx[cl][2]) - fmaxf(ax1, cbx[cl][0]) + 1.f;
      float ih = fminf(ay2, cbx[cl][3]) - fmaxf(ay1, cbx[cl][1]) + 1.f;
      float inter = fmaxf(iw, 0.f) * fmaxf(ih, 0.f);
      float d = inter - 0.7f * (aar + cbx[cl][4] - inter);
      bool sup;
      if (d > 4.0f) sup = true;
      else if (d < -4.0f) sup = false;
      else sup = iou_gt(sbx + (size_t)r * 4, sbx + (size_t)j * 4);  // rare
      if (sup) bits |= 1ull << jj;
    }
  }
  Sup[(size_t)r * SUP_W + w] = bits;
}

// ---------------- single-barrier pipelined greedy NMS scan (scalar chain) ----
// R9 version: wave-uniform greedy chain on the scalar unit (s_ff1 ->
// readlane x2 -> s_andn2). Next-block ext fold = two extra readlanes per keep
// off the critical path. Waves 1-15 OR full remaining rows of phase b-1 keeps
// concurrently; one barrier per phase. R10's A/B showed the no-vmcnt-drain
// barrier + deeper fold REGRESSED; readlanes-per-keep on the serial chain is
// the currency -- keep the 4-readlane version.
__global__ __launch_bounds__(1024) void k_scan(const uint64_t* __restrict__ Sup,
                                               const double* __restrict__ ss,
                                               const double* __restrict__ sbx,
                                               float* __restrict__ out) {
  __shared__ uint16_t keep[POST_NMS];
  __shared__ uint32_t ext_arr[SUP_W][2];
  __shared__ int s_kcnt, s_done;
  __shared__ int s_pend[2][2];             // parity-double-buffered pend range
  int t = threadIdx.x, wv = t >> 6, ln = t & 63;
  for (int i = t; i < SUP_W * 2; i += 1024) ext_arr[i >> 1][i & 1] = 0u;
  if (t == 0) { s_kcnt = 0; s_done = 0; }
  if (t < 4) s_pend[t >> 1][t & 1] = 0;
  uint64_t diag = 0ull, nxt = 0ull;
  if (wv == 0) {                           // prefetch block-0 diag pair
    size_t r = (size_t)ln * SUP_W;
    diag = Sup[r + 0];
    nxt  = Sup[r + 1];
  }
  __syncthreads();
  for (int b = 0; b < NMS_BLKS; ++b) {
    if (wv == 0) {
      uint64_t myrow = diag & ~((2ull << ln) - 1ull);
      uint64_t mynxt = nxt;
      if (b + 1 < NMS_BLKS) {              // issue next-phase prefetch early
        size_t r = (size_t)((b + 1) * 64 + ln) * SUP_W;
        diag = Sup[r + (b + 1)];
        nxt  = Sup[r + (b + 2)];           // b+2 <= 95 < SUP_W
      }
      uint64_t ext = ((uint64_t)ext_arr[b][1] << 32) | ext_arr[b][0];
      int base = b * 64;
      if (base + 63 >= PRE_NMS) {
        int v = PRE_NMS - base;            // 48 for the tail block
        ext |= ~((1ull << v) - 1ull);
      }
      int K0 = s_kcnt;
      // scalarize: avail is wave-uniform; hoist to SGPRs so the greedy chain
      // runs on the scalar unit with readlane broadcasts (no ds_bpermute).
      uint64_t avail;
      {
        uint64_t a0 = ~ext;
        uint32_t alo = __builtin_amdgcn_readfirstlane((uint32_t)a0);
        uint32_t ahi = __builtin_amdgcn_readfirstlane((uint32_t)(a0 >> 32));
        avail = ((uint64_t)ahi << 32) | alo;
      }
      uint32_t mr_lo = (uint32_t)myrow, mr_hi = (uint32_t)(myrow >> 32);
      uint32_t mn_lo = (uint32_t)mynxt, mn_hi = (uint32_t)(mynxt >> 32);
      uint64_t kp = 0ull, extn = 0ull;
      int lim = POST_NMS - K0, nk = 0;
      while (avail && nk < lim) {
        int i2 = __ffsll((unsigned long long)avail) - 1;
        uint32_t rlo = (uint32_t)__builtin_amdgcn_readlane((int)mr_lo, i2);
        uint32_t rhi = (uint32_t)__builtin_amdgcn_readlane((int)mr_hi, i2);
        uint32_t qlo = (uint32_t)__builtin_amdgcn_readlane((int)mn_lo, i2);
        uint32_t qhi = (uint32_t)__builtin_amdgcn_readlane((int)mn_hi, i2);
        kp |= 1ull << i2;
        ++nk;
        extn |= ((uint64_t)qhi << 32) | qlo;
        avail &= ~(((uint64_t)rhi << 32) | rlo);
        avail &= ~(1ull << i2);
      }
      if ((kp >> ln) & 1ull) {
        int pos = K0 + __popcll(kp & ((1ull << ln) - 1ull));
        keep[pos] = (uint16_t)(base + ln);
      }
      if (ln == 0) {
        if ((uint32_t)extn)         atomicOr(&ext_arr[b + 1][0], (uint32_t)extn);
        if ((uint32_t)(extn >> 32)) atomicOr(&ext_arr[b + 1][1],
                                             (uint32_t)(extn >> 32));
        s_kcnt = K0 + nk;
        s_pend[(b + 1) & 1][0] = K0;       // pend range for next phase's ORers
        s_pend[(b + 1) & 1][1] = K0 + nk;
        if (K0 + nk >= POST_NMS || b + 1 >= NMS_BLKS) s_done = 1;
      }
    } else {
      // waves 1-15: full-row OR of phase b-1's keeps, words >= b+1 only
      // (word b was folded by wave 0 last phase; wave 0 reads word b now).
      int lo = s_pend[b & 1][0], hi = s_pend[b & 1][1];
      if (hi > lo) {
        int tt = t - 64;                   // 0..959
        int g = tt / 96, w = tt - g * 96;  // 10 row-groups x 96 words
        if (w >= b + 1) {
          uint64_t v = 0ull;
          for (int q = lo + g; q < hi; q += 10)
            v |= Sup[(size_t)keep[q] * SUP_W + w];
          if (v) {
            if ((uint32_t)v)         atomicOr(&ext_arr[w][0], (uint32_t)v);
            if ((uint32_t)(v >> 32)) atomicOr(&ext_arr[w][1], (uint32_t)(v >> 32));
          }
        }
      }
    }
    __syncthreads();
    if (s_done) break;                     // uniform: LDS value after barrier
  }
  __syncthreads();
  int KF = s_kcnt;
  for (int r = t; r < POST_NMS; r += 1024) {
    float* o = out + r * 6;
    if (r < KF) {
      int p = keep[r];
      o[0] = 0.f;
      o[1] = (float)sbx[p * 4 + 0];
      o[2] = (float)sbx[p * 4 + 1];
      o[3] = (float)sbx[p * 4 + 2];
      o[4] = (float)sbx[p * 4 + 3];
      o[5] = (float)ss[p];
    } else {
#pragma unroll
      for (int c = 0; c < 6; ++c) o[c] = 0.f;
    }
  }
}

// ---------------- host launch ----------------
extern "C" void kernel_launch(void* const* d_in, const int* in_sizes, int n_in,
                              void* d_out, int out_size, void* d_ws, size_t ws_size,
                              hipStream_t stream) {
  const float* p0 = (const float*)d_in[0];
  const float* p1 = (const float*)d_in[1];
  const float* p2 = (const float*)d_in[2];
  const float* p3 = (const float*)d_in[3];
  const float* p4 = (const float*)d_in[4];
  const float* im_info = (const float*)d_in[5];
  const float* cw = (const float*)d_in[6];
  const float* cb = (const float*)d_in[7];
  const float* sw = (const float*)d_in[8];
  const float* sb = (const float*)d_in[9];
  const float* bw = (const float*)d_in[10];
  const float* bb = (const float*)d_in[11];
  char* ws = (char*)d_ws;
  // ws layout (bytes):
  uint32_t* hist    = (uint32_t*)(ws + 0);         // 65536 u32 -> 262144
  uint32_t* cnts    = (uint32_t*)(ws + 262144);    // [0]=pool [1]=edge -> 262208
  double*   fb      = (double*)  (ws + 262208);    // 16 f64 -> 262336
  float*    fb32    = (float*)   (ws + 262336);    // 4 f32  -> 262352
  double*   logits  = (double*)  (ws + 262352);    // 106392 f64 -> 1113488
  double*   deltas  = (double*)  (ws + 1113488);   // 425568 f64 -> 4518032
  float*    logits32= (float*)   (ws + 4518032);   // 106392 f32 -> 4943600
  float4*   w3      = (float4*)  (ws + 4943600);   // 2304 float4 -> 4980464
  // (ws+4980464 .. 5275376: former Weff region, now unused)
  // Wpart transposed: [16 chunks][15 j][2304 t] f64 = 4,423,680 B
  double*   Wpart   = (double*)  (ws + 5275376);   // -> 9,699,056 (< 9,993,968)
  uint32_t* alist   = (uint32_t*)(ws + 9993968);   // 8192 u32 -> 10026736
  double*   ssort   = (double*)  (ws + 10026736);  // 6016 f64 -> 10074864
  double*   sbx     = (double*)  (ws + 10074864);  // 6016*4 f64 -> 10267376
  float4*   bxf     = (float4*)  (ws + 10267376);  // 6016 float4 -> 10363632
  float*    areaf   = (float*)   (ws + 10363632);  // 6016 f32 -> 10387696
  uint64_t* Sup     = (uint64_t*)(ws + 10387696);  // 6016*96 u64 -> 15007984
  uint64_t* pkey    = (uint64_t*)(ws + 15007984);  // 8192 u64 -> 15073520
  uint32_t* rank32  = (uint32_t*)(ws + 15073520);  // 8192 u32 -> 15106288
  uint32_t* bcnt    = hist;                        // reuse: hist dead after k_edge
  // W5 (256ch*192 f64 = 393216 B) lives in the deltas region: written by
  // k_weff_fin, last read by k_refine, then k_comb overwrites with deltas
  // (k_scatter reads only pool-gi deltas, all freshly written).
  double*   W5      = deltas;
  // ppart/qpart live inside the Wpart region -- Wpart is dead after
  // k_weff_fin; ppart written by k_refine, qpart by k_fast (both later).
  double*   ppart   = (double*)(ws + 5275376 + 524288);   // in Wpart region
  float*    qpart   = (float*) (ws + 5275376 + 2097152);  // in Wpart region
  float* out = (float*)d_out;

  // zeroing of hist+cnts+rank32 is folded into k_weff_part (first dispatch)
  k_weff_part<<<288, 256, 0, stream>>>(cw, sw, bw, Wpart, hist, rank32);
  k_weff_fin<<<10, 256, 0, stream>>>(Wpart, cb, sb, bb, sw, bw, W5, fb, w3, fb32);
  k_fast<<<1110, 256, 0, stream>>>(p0, p1, p2, p3, p4, w3, qpart);
  k_fcomb<<<139, 256, 0, stream>>>(qpart, fb32, logits32, hist);
  k_edge<<<1, 1024, 0, stream>>>(hist, cnts);
  k_cnt<<<416, 256, 0, stream>>>(logits32, cnts, bcnt);
  k_fill<<<416, 256, 0, stream>>>(logits32, cnts, bcnt, alist);
  k_refine<<<256, 128, 0, stream>>>(p0, p1, p2, p3, p4, W5, alist, cnts, ppart);
  k_comb<<<32, 256, 0, stream>>>(alist, cnts, ppart, fb, logits, deltas, pkey);
  k_rank_cnt<<<512, 256, 0, stream>>>(cnts, pkey, rank32);
  k_scatter<<<32, 256, 0, stream>>>(cnts, pkey, rank32, logits, deltas, im_info,
                                    ssort, sbx, bxf, areaf);
  k_build<<<94 * 24, 256, 0, stream>>>(sbx, bxf, areaf, Sup);
  k_scan<<<1, 1024, 0, stream>>>(Sup, ssort, sbx, out);
}